// Round 2
// baseline (2954.260 us; speedup 1.0000x reference)
//
#include <hip/hip_runtime.h>
#include <cstddef>
#include <cstdint>

#define DEV __device__ __forceinline__

namespace {

constexpr int kD = 512, kH = 8;
constexpr int kB = 32, kT = 1024, kNT = 77, kR = 4, kLR = 256;
constexpr int kRL = kR * kLR;            // 1024
constexpr int kN = kNT + kRL + kT;       // 2125
constexpr float kNEG = -1000000.0f;

DEV float wave_sum(float v) {
  #pragma unroll
  for (int s = 32; s; s >>= 1) v += __shfl_xor(v, s);
  return v;
}

// ---------------- LayerNorm (block per row) ----------------
template<int COLS>
__global__ __launch_bounds__(256) void ln_kernel(const float* __restrict__ in,
    const float* __restrict__ g, const float* __restrict__ be, float* __restrict__ out) {
  constexpr int PT = COLS / 256;
  int row = blockIdx.x;
  const float* p = in + (size_t)row * COLS;
  float* o = out + (size_t)row * COLS;
  float v[PT]; float s = 0.f, s2 = 0.f;
  #pragma unroll
  for (int i = 0; i < PT; i++) {
    v[i] = p[threadIdx.x + i * 256];
    s += v[i]; s2 += v[i] * v[i];
  }
  __shared__ float red[2][4];
  int lane = threadIdx.x & 63, w = threadIdx.x >> 6;
  s = wave_sum(s); s2 = wave_sum(s2);
  if (!lane) { red[0][w] = s; red[1][w] = s2; }
  __syncthreads();
  s = red[0][0] + red[0][1] + red[0][2] + red[0][3];
  s2 = red[1][0] + red[1][1] + red[1][2] + red[1][3];
  float mean = s / COLS;
  float var = s2 / COLS - mean * mean;
  float rstd = rsqrtf(var + 1e-5f);
  #pragma unroll
  for (int i = 0; i < PT; i++) {
    int c = threadIdx.x + i * 256;
    o[c] = (v[i] - mean) * rstd * g[c] + be[c];
  }
}

// ---------------- stats for the two retrieval LNs ----------------
__global__ __launch_bounds__(256) void rfk_stats(const float* __restrict__ mot,
    const float* __restrict__ txt, float* __restrict__ mA, float* __restrict__ rA,
    float* __restrict__ mV, float* __restrict__ rV) {
  int m = blockIdx.x;
  const float* pm = mot + (size_t)m * 512;
  const float* pt = txt + (size_t)(m >> 8) * 512;   // b*4+r = m/256
  float sv = 0.f, sv2 = 0.f, st = 0.f, st2 = 0.f;
  #pragma unroll
  for (int i = 0; i < 2; i++) {
    float a = pm[threadIdx.x + i * 256]; sv += a; sv2 += a * a;
    float b = pt[threadIdx.x + i * 256]; st += b; st2 += b * b;
  }
  __shared__ float red[4][4];
  int lane = threadIdx.x & 63, w = threadIdx.x >> 6;
  sv = wave_sum(sv); sv2 = wave_sum(sv2); st = wave_sum(st); st2 = wave_sum(st2);
  if (!lane) { red[0][w] = sv; red[1][w] = sv2; red[2][w] = st; red[3][w] = st2; }
  __syncthreads();
  if (threadIdx.x == 0) {
    float SV = 0, SV2 = 0, ST = 0, ST2 = 0;
    for (int i = 0; i < 4; i++) { SV += red[0][i]; SV2 += red[1][i]; ST += red[2][i]; ST2 += red[3][i]; }
    float SA = SV + ST, SA2 = SV2 + ST2;
    float ma = SA / 1024.f, va = SA2 / 1024.f - ma * ma;
    mA[m] = ma; rA[m] = rsqrtf(va + 1e-5f);
    float mv = SV / 512.f, vv = SV2 / 512.f - mv * mv;
    mV[m] = mv; rV[m] = rsqrtf(vv + 1e-5f);
  }
}

// ---------------- per-row mask arrays ----------------
__global__ __launch_bounds__(256) void rowmask_kernel(const int* __restrict__ ct,
    const float* __restrict__ src_mask, const float* __restrict__ re_mask,
    float* __restrict__ kaT, float* __restrict__ kaR, float* __restrict__ kaM,
    float* __restrict__ vmT, float* __restrict__ vmR, float* __restrict__ vmM,
    int nB) {
  int i = blockIdx.x * 256 + threadIdx.x;
  if (i < nB * kRL) {
    int b = i >> 10;
    int c = ct[b];
    float retr = (c / 10 > 0) ? 1.f : 0.f;
    float rm = re_mask[i];
    kaR[i] = (1.f - retr) * kNEG + (1.f - rm) * kNEG;
    vmR[i] = retr * rm;
    float sm = src_mask[i];
    kaM[i] = (1.f - sm) * kNEG;
    vmM[i] = sm;
  }
  if (i < nB * kNT) {
    int b = i / kNT;
    int c = ct[b];
    float text = (c % 10 > 0) ? 1.f : 0.f;
    kaT[i] = (1.f - text) * kNEG;
    vmT[i] = text;
  }
}

// ---------------- GEMM: C = A @ W^T + bias, with epilogue ----------------
struct PlainA {
  const float* A; int K;
  DEV float ld(int m, int k) const { return A[(size_t)m * K + k]; }
};
struct LNA {
  const float* A; const float* mean; const float* rstd;
  const float* g; const float* be; int K;
  DEV float ld(int m, int k) const {
    return (A[(size_t)m * K + k] - mean[m]) * rstd[m] * g[k] + be[k];
  }
};
struct RFKA {   // concat(re_motion[m], re_text[m/256]) then LN
  const float* mot; const float* txt; const float* mean; const float* rstd;
  const float* g; const float* be;
  DEV float ld(int m, int k) const {
    float v = (k < 512) ? mot[(size_t)m * 512 + k]
                        : txt[(size_t)(m >> 8) * 512 + (k - 512)];
    return (v - mean[m]) * rstd[m] * g[k] + be[k];
  }
};
struct SiluA {
  const float* A; int K;
  DEV float ld(int m, int k) const {
    float v = A[(size_t)m * K + k];
    return v / (1.f + __expf(-v));
  }
};

template<class AL>
__global__ __launch_bounds__(256) void gemm64(AL al, const float* __restrict__ W,
    const float* __restrict__ bias, float* __restrict__ C, int M, int K, int Dout,
    int m_per_b, int n_total, int out_off,
    const float* __restrict__ rowAdd, const float* __restrict__ rowMul,
    const float* __restrict__ addX) {
  __shared__ float As[16][68];
  __shared__ float Ws[16][68];
  int m0 = blockIdx.y * 64, n0 = blockIdx.x * 64;
  int tid = threadIdx.x;
  int tx = tid & 15, ty = tid >> 4;
  float acc[4][4] = {};
  int mm = tid >> 2, kk = (tid & 3) << 2;
  int ma = m0 + mm; if (ma >= M) ma = M - 1;
  int nn = tid >> 2;
  for (int k0 = 0; k0 < K; k0 += 16) {
    __syncthreads();
    float a0 = al.ld(ma, k0 + kk + 0);
    float a1 = al.ld(ma, k0 + kk + 1);
    float a2 = al.ld(ma, k0 + kk + 2);
    float a3 = al.ld(ma, k0 + kk + 3);
    As[kk + 0][mm] = a0; As[kk + 1][mm] = a1; As[kk + 2][mm] = a2; As[kk + 3][mm] = a3;
    const float4 wv = *reinterpret_cast<const float4*>(&W[(size_t)(n0 + nn) * K + k0 + kk]);
    Ws[kk + 0][nn] = wv.x; Ws[kk + 1][nn] = wv.y; Ws[kk + 2][nn] = wv.z; Ws[kk + 3][nn] = wv.w;
    __syncthreads();
    #pragma unroll
    for (int k = 0; k < 16; k++) {
      float4 av = *reinterpret_cast<const float4*>(&As[k][ty * 4]);
      float4 bv = *reinterpret_cast<const float4*>(&Ws[k][tx * 4]);
      float a[4] = {av.x, av.y, av.z, av.w};
      float b[4] = {bv.x, bv.y, bv.z, bv.w};
      #pragma unroll
      for (int i = 0; i < 4; i++)
        #pragma unroll
        for (int j = 0; j < 4; j++)
          acc[i][j] = fmaf(a[i], b[j], acc[i][j]);
    }
  }
  #pragma unroll
  for (int i = 0; i < 4; i++) {
    int m = m0 + ty * 4 + i;
    if (m >= M) continue;
    size_t orow = (size_t)(m / m_per_b) * n_total + out_off + (m % m_per_b);
    float ra = rowAdd ? rowAdd[m] : 0.f;
    float rm = rowMul ? rowMul[m] : 1.f;
    #pragma unroll
    for (int j = 0; j < 4; j++) {
      int n = n0 + tx * 4 + j;
      float c = (acc[i][j] + bias[n]) * rm + ra;
      if (addX) c += addX[(size_t)m * Dout + n];
      C[orow * Dout + n] = c;
    }
  }
}

// ---------------- column-softmax denominator for k (over N) ----------------
__global__ __launch_bounds__(256) void colsum_part(const float* __restrict__ kc,
    float* __restrict__ part) {
  int b = blockIdx.x >> 1;
  int d = ((blockIdx.x & 1) << 8) + threadIdx.x;
  int c = blockIdx.y;
  int nbeg = c * 266, nend = min(kN, nbeg + 266);
  const float* p = kc + (size_t)b * kN * 512 + d;
  float s = 0.f;
  for (int n = nbeg; n < nend; n++) s += __expf(p[(size_t)n * 512]);
  part[((size_t)b * 512 + d) * 8 + c] = s;
}
__global__ __launch_bounds__(256) void colsum_fin(const float* __restrict__ part,
    float* __restrict__ sinv) {
  int i = blockIdx.x * 256 + threadIdx.x;
  float s = 0.f;
  #pragma unroll
  for (int c = 0; c < 8; c++) s += part[(size_t)i * 8 + c];
  sinv[i] = 1.f / s;
}

// ---------------- attention = (softmax_N k)^T v  per (b,h): 64x64 ----------------
__global__ __launch_bounds__(256) void att_einsum(const float* __restrict__ kc,
    const float* __restrict__ vv, const float* __restrict__ sinv, float* __restrict__ att) {
  int bh = blockIdx.x; int b = bh >> 3, h = bh & 7;
  const float* kp = kc + (size_t)b * kN * 512 + h * 64;
  const float* vp = vv + (size_t)b * kN * 512 + h * 64;
  __shared__ float ks[32][64];
  __shared__ float vs[32][64];
  int tid = threadIdx.x;
  int td = tid >> 4, tl = tid & 15;
  float acc[4][4] = {};
  for (int n0 = 0; n0 < kN; n0 += 32) {
    __syncthreads();
    #pragma unroll
    for (int idx = tid; idx < 2048; idx += 256) {
      int dd = idx & 63, nn = idx >> 6;
      int n = n0 + nn;
      float kval = 0.f, vval = 0.f;
      if (n < kN) {
        kval = __expf(kp[(size_t)n * 512 + dd]);
        vval = vp[(size_t)n * 512 + dd];
      }
      ks[nn][dd] = kval; vs[nn][dd] = vval;
    }
    __syncthreads();
    #pragma unroll
    for (int nn = 0; nn < 32; nn++) {
      float4 kv = *reinterpret_cast<const float4*>(&ks[nn][td * 4]);
      float4 vl = *reinterpret_cast<const float4*>(&vs[nn][tl * 4]);
      float a[4] = {kv.x, kv.y, kv.z, kv.w};
      float c[4] = {vl.x, vl.y, vl.z, vl.w};
      #pragma unroll
      for (int i = 0; i < 4; i++)
        #pragma unroll
        for (int j = 0; j < 4; j++)
          acc[i][j] = fmaf(a[i], c[j], acc[i][j]);
    }
  }
  #pragma unroll
  for (int i = 0; i < 4; i++) {
    float si = sinv[b * 512 + h * 64 + td * 4 + i];
    #pragma unroll
    for (int j = 0; j < 4; j++)
      att[(size_t)bh * 4096 + (td * 4 + i) * 64 + tl * 4 + j] = acc[i][j] * si;
  }
}

// ---------------- y = (softmax_d q) @ att, q-softmax fused ----------------
__global__ __launch_bounds__(256) void y_einsum(const float* __restrict__ q,
    const float* __restrict__ att, float* __restrict__ y) {
  int bh = blockIdx.x; int b = bh >> 3, h = bh & 7;
  int t0 = blockIdx.y * 64;
  __shared__ float as_[64][64];
  __shared__ float qs[64][68];
  int tid = threadIdx.x;
  #pragma unroll
  for (int idx = tid; idx < 4096; idx += 256) {
    int l = idx & 63, dd = idx >> 6;
    as_[dd][l] = att[(size_t)bh * 4096 + idx];
  }
  #pragma unroll
  for (int idx = tid; idx < 4096; idx += 256) {
    int dd = idx & 63, tt = idx >> 6;
    qs[tt][dd] = __expf(q[(size_t)(b * 1024 + t0 + tt) * 512 + h * 64 + dd]);
  }
  __syncthreads();
  int t = tid >> 2, lb = (tid & 3) << 4;
  float rsum = 0.f;
  for (int dd = 0; dd < 64; dd++) rsum += qs[t][dd];
  float rinv = 1.f / rsum;
  float acc[16] = {};
  for (int dd = 0; dd < 64; dd++) {
    float qv = qs[t][dd];
    #pragma unroll
    for (int j = 0; j < 16; j++) acc[j] = fmaf(qv, as_[dd][lb + j], acc[j]);
  }
  float* yp = y + (size_t)(b * 1024 + t0 + t) * 512 + h * 64 + lb;
  #pragma unroll
  for (int j = 0; j < 16; j++) yp[j] = acc[j] * rinv;
}

// ---------------- LN(y)*(1+scale)+shift then SiLU ----------------
__global__ __launch_bounds__(256) void mod_kernel(const float* __restrict__ y,
    const float* __restrict__ ss, const float* __restrict__ g, const float* __restrict__ be,
    float* __restrict__ h) {
  int row = blockIdx.x; int b = row >> 10;
  const float* p = y + (size_t)row * 512;
  float* o = h + (size_t)row * 512;
  float v[2]; float s = 0.f, s2 = 0.f;
  #pragma unroll
  for (int i = 0; i < 2; i++) {
    v[i] = p[threadIdx.x + i * 256];
    s += v[i]; s2 += v[i] * v[i];
  }
  __shared__ float red[2][4];
  int lane = threadIdx.x & 63, w = threadIdx.x >> 6;
  s = wave_sum(s); s2 = wave_sum(s2);
  if (!lane) { red[0][w] = s; red[1][w] = s2; }
  __syncthreads();
  s = red[0][0] + red[0][1] + red[0][2] + red[0][3];
  s2 = red[1][0] + red[1][1] + red[1][2] + red[1][3];
  float mean = s / 512.f, var = s2 / 512.f - mean * mean;
  float rstd = rsqrtf(var + 1e-5f);
  #pragma unroll
  for (int i = 0; i < 2; i++) {
    int c = threadIdx.x + i * 256;
    float val = (v[i] - mean) * rstd * g[c] + be[c];
    val = val * (1.f + ss[b * 1024 + c]) + ss[b * 1024 + 512 + c];
    o[c] = val / (1.f + __expf(-val));
  }
}

}  // namespace

extern "C" void kernel_launch(void* const* d_in, const int* in_sizes, int n_in,
                              void* d_out, int out_size, void* d_ws, size_t ws_size,
                              hipStream_t stream) {
  const float* x        = (const float*)d_in[0];
  const float* xf       = (const float*)d_in[1];
  const float* emb      = (const float*)d_in[2];
  const float* src_mask = (const float*)d_in[3];
  const int*   cond     = (const int*)d_in[4];
  const float* re_motion= (const float*)d_in[5];
  const float* re_text  = (const float*)d_in[6];
  const float* re_mask  = (const float*)d_in[7];
  const float* norm_g = (const float*)d_in[8],  * norm_b = (const float*)d_in[9];
  const float* tnorm_g= (const float*)d_in[10], * tnorm_b= (const float*)d_in[11];
  const float* rn1_g  = (const float*)d_in[12], * rn1_b  = (const float*)d_in[13];
  const float* rn2_g  = (const float*)d_in[14], * rn2_b  = (const float*)d_in[15];
  const float* Wq  = (const float*)d_in[16], * bq  = (const float*)d_in[17];
  const float* Wkt = (const float*)d_in[18], * bkt = (const float*)d_in[19];
  const float* Wvt = (const float*)d_in[20], * bvt = (const float*)d_in[21];
  const float* Wkm = (const float*)d_in[22], * bkm = (const float*)d_in[23];
  const float* Wvm = (const float*)d_in[24], * bvm = (const float*)d_in[25];
  const float* Wkr = (const float*)d_in[26], * bkr = (const float*)d_in[27];
  const float* Wvr = (const float*)d_in[28], * bvr = (const float*)d_in[29];
  const float* emb_W = (const float*)d_in[30], * emb_b = (const float*)d_in[31];
  const float* snorm_g = (const float*)d_in[32], * snorm_b = (const float*)d_in[33];
  const float* out_W = (const float*)d_in[34], * out_b = (const float*)d_in[35];
  float* out = (float*)d_out;

  // ---- choose batch chunk so the workspace FITS in ws_size ----
  auto padql = [](size_t n) { return (n + 63) & ~size_t(63); };
  auto need_floats = [&](size_t CH) -> size_t {
    size_t f = 0;
    f += padql(CH * 1024 * 512);   // xn (reused as y)
    f += padql(CH * kNT * 256);    // xfn
    f += padql(CH * 1024 * 512);   // q (reused as h)
    f += padql(CH * kN * 512);     // kc
    f += padql(CH * kN * 512);     // vb
    f += padql(CH * 8 * 4096);     // att
    f += padql(CH * 1024);         // scale/shift
    f += 4 * padql(CH * 1024);     // mA,rA,mV,rV
    f += padql(CH * kNT) + 2 * padql(CH * 1024);   // kaT,kaR,kaM
    f += padql(CH * kNT) + 2 * padql(CH * 1024);   // vmT,vmR,vmM
    f += padql(CH * 512 * 8);      // part
    f += padql(CH * 512);          // sinv
    return f;
  };
  int CH = 32;
  while (CH > 1 && need_floats(CH) * 4 > ws_size) CH >>= 1;

  float* ws = (float*)d_ws;

  for (int b0 = 0; b0 < kB; b0 += CH) {
    size_t off = 0;
    auto alloc = [&](size_t n) { float* p = ws + off; off += padql(n); return p; };
    const size_t MRc = (size_t)CH * kT;     // rows of x in chunk
    const int MTc = CH * kNT;               // rows of xf in chunk

    float* xn  = alloc(MRc * 512);
    float* xfn = alloc((size_t)CH * kNT * 256);
    float* qb  = alloc(MRc * 512);
    float* kc  = alloc((size_t)CH * kN * 512);
    float* vb  = alloc((size_t)CH * kN * 512);
    float* attb= alloc((size_t)CH * 8 * 4096);
    float* ssb = alloc((size_t)CH * 1024);
    float* mA = alloc(MRc / 2); float* rA = alloc(MRc / 2);   // CH*1024 rows
    mA = mA; // (CH*1024 == MRc when kT==1024; RL==1024 too)
    // note: retrieval rows per chunk = CH*kRL = CH*1024
    float* rAx = rA; (void)rAx;
    float* mV = alloc((size_t)CH * kRL); float* rV = alloc((size_t)CH * kRL);
    float* kaT = alloc((size_t)CH * kNT); float* kaR = alloc((size_t)CH * kRL);
    float* kaM = alloc(MRc);
    float* vmT = alloc((size_t)CH * kNT); float* vmR = alloc((size_t)CH * kRL);
    float* vmM = alloc(MRc);
    float* part = alloc((size_t)CH * 512 * 8);
    float* sinv = alloc((size_t)CH * 512);
    float* yb = xn;
    float* hb = qb;

    // NOTE: mA/rA were sized MRc/2 above by mistake in bookkeeping; but
    // CH*kRL == CH*1024 == MRc/... ensure correct sizes:
    // (kRL==1024, kT==1024, so retrieval row count == MRc). Re-derive:
    // mA needs CH*kRL floats. MRc/2 == CH*512 < CH*1024 — WRONG. Fix by
    // allocating the difference right here (layout stays deterministic).
    // To keep it simple and safe, allocate fresh correctly-sized arrays:
    mA = alloc((size_t)CH * kRL); rA = alloc((size_t)CH * kRL);

    const float* x_c   = x + (size_t)b0 * kT * 512;
    const float* xf_c  = xf + (size_t)b0 * kNT * 256;
    const float* emb_c = emb + (size_t)b0 * 2048;
    const float* sm_c  = src_mask + (size_t)b0 * kT;
    const int*   ct_c  = cond + b0;
    const float* rm_c  = re_motion + (size_t)b0 * kRL * 512;
    const float* rt_c  = re_text + (size_t)b0 * kR * 512;
    const float* rmask_c = re_mask + (size_t)b0 * kRL;
    float* out_c = out + (size_t)b0 * kT * 512;

    // --- preprocessing ---
    ln_kernel<512><<<dim3((int)MRc), 256, 0, stream>>>(x_c, norm_g, norm_b, xn);
    ln_kernel<256><<<dim3(MTc), 256, 0, stream>>>(xf_c, tnorm_g, tnorm_b, xfn);
    rfk_stats<<<dim3(CH * kRL), 256, 0, stream>>>(rm_c, rt_c, mA, rA, mV, rV);
    rowmask_kernel<<<dim3(CH * 4), 256, 0, stream>>>(ct_c, sm_c, rmask_c,
                                                     kaT, kaR, kaM, vmT, vmR, vmM, CH);

    // --- projections ---
    gemm64<PlainA><<<dim3(8, CH * 16), 256, 0, stream>>>(PlainA{xn, 512}, Wq, bq, qb,
        (int)MRc, 512, 512, (int)MRc, 0, 0, nullptr, nullptr, nullptr);
    gemm64<PlainA><<<dim3(8, (MTc + 63) / 64), 256, 0, stream>>>(PlainA{xfn, 256}, Wkt, bkt, kc,
        MTc, 256, 512, kNT, kN, 0, kaT, nullptr, nullptr);
    gemm64<RFKA><<<dim3(8, CH * 16), 256, 0, stream>>>(
        RFKA{rm_c, rt_c, mA, rA, rn1_g, rn1_b}, Wkr, bkr, kc,
        CH * kRL, 1024, 512, kRL, kN, kNT, kaR, nullptr, nullptr);
    gemm64<PlainA><<<dim3(8, CH * 16), 256, 0, stream>>>(PlainA{xn, 512}, Wkm, bkm, kc,
        (int)MRc, 512, 512, kT, kN, kNT + kRL, kaM, nullptr, nullptr);
    gemm64<PlainA><<<dim3(8, (MTc + 63) / 64), 256, 0, stream>>>(PlainA{xfn, 256}, Wvt, bvt, vb,
        MTc, 256, 512, kNT, kN, 0, nullptr, vmT, nullptr);
    gemm64<LNA><<<dim3(8, CH * 16), 256, 0, stream>>>(
        LNA{rm_c, mV, rV, rn2_g, rn2_b, 512}, Wvr, bvr, vb,
        CH * kRL, 512, 512, kRL, kN, kNT, nullptr, vmR, nullptr);
    gemm64<PlainA><<<dim3(8, CH * 16), 256, 0, stream>>>(PlainA{xn, 512}, Wvm, bvm, vb,
        (int)MRc, 512, 512, kT, kN, kNT + kRL, nullptr, vmM, nullptr);
    gemm64<SiluA><<<dim3(16, 1), 256, 0, stream>>>(SiluA{emb_c, 2048}, emb_W, emb_b, ssb,
        CH, 2048, 1024, CH, 0, 0, nullptr, nullptr, nullptr);

    // --- attention (softmaxes folded in) ---
    colsum_part<<<dim3(CH * 2, 8), 256, 0, stream>>>(kc, part);
    colsum_fin<<<dim3(CH * 2), 256, 0, stream>>>(part, sinv);
    att_einsum<<<dim3(CH * 8), 256, 0, stream>>>(kc, vb, sinv, attb);
    y_einsum<<<dim3(CH * 8, 16), 256, 0, stream>>>(qb, attb, yb);

    // --- modulation + output projection + residual ---
    mod_kernel<<<dim3((int)MRc), 256, 0, stream>>>(yb, ssb, snorm_g, snorm_b, hb);
    gemm64<PlainA><<<dim3(8, CH * 16), 256, 0, stream>>>(PlainA{hb, 512}, out_W, out_b, out_c,
        (int)MRc, 512, 512, (int)MRc, 0, 0, nullptr, nullptr, x_c);
  }
}

// Round 3
// 1525.672 us; speedup vs baseline: 1.9364x; 1.9364x over previous
//
#include <hip/hip_runtime.h>
#include <cstddef>
#include <cstdint>

#define DEV __device__ __forceinline__

namespace {

constexpr int kH = 8;
constexpr int kB = 32, kT = 1024, kNT = 77, kR = 4, kLR = 256;
constexpr int kRL = kR * kLR;            // 1024
constexpr int kN = kNT + kRL + kT;       // 2125
constexpr float kNEG = -1000000.0f;

typedef __bf16 bf16x8 __attribute__((ext_vector_type(8)));
typedef float f32x4 __attribute__((ext_vector_type(4)));

DEV unsigned short f2bf(float f) {
  unsigned int u = __float_as_uint(f);
  u += 0x7fffu + ((u >> 16) & 1u);
  return (unsigned short)(u >> 16);
}
DEV float bf2f(unsigned short h) { return __uint_as_float(((unsigned int)h) << 16); }

DEV float wave_sum(float v) {
  #pragma unroll
  for (int s = 32; s; s >>= 1) v += __shfl_xor(v, s);
  return v;
}

// ---------------- LayerNorm -> bf16 ----------------
template<int COLS>
__global__ __launch_bounds__(256) void ln_bf16(const float* __restrict__ in,
    const float* __restrict__ g, const float* __restrict__ be,
    unsigned short* __restrict__ out) {
  constexpr int PT = COLS / 256;
  int row = blockIdx.x;
  const float* p = in + (size_t)row * COLS;
  unsigned short* o = out + (size_t)row * COLS;
  float v[PT]; float s = 0.f, s2 = 0.f;
  #pragma unroll
  for (int i = 0; i < PT; i++) {
    v[i] = p[threadIdx.x + i * 256];
    s += v[i]; s2 += v[i] * v[i];
  }
  __shared__ float red[2][4];
  int lane = threadIdx.x & 63, w = threadIdx.x >> 6;
  s = wave_sum(s); s2 = wave_sum(s2);
  if (!lane) { red[0][w] = s; red[1][w] = s2; }
  __syncthreads();
  s = red[0][0] + red[0][1] + red[0][2] + red[0][3];
  s2 = red[1][0] + red[1][1] + red[1][2] + red[1][3];
  float mean = s / COLS;
  float var = s2 / COLS - mean * mean;
  float rstd = rsqrtf(var + 1e-5f);
  #pragma unroll
  for (int i = 0; i < PT; i++) {
    int c = threadIdx.x + i * 256;
    o[c] = f2bf((v[i] - mean) * rstd * g[c] + be[c]);
  }
}

// ---------------- retrieval LNs fused: stats + normalize -> bf16 ----------------
__global__ __launch_bounds__(256) void rfk_norm(const float* __restrict__ mot,
    const float* __restrict__ txt,
    const float* __restrict__ g1, const float* __restrict__ b1,
    const float* __restrict__ g2, const float* __restrict__ b2,
    unsigned short* __restrict__ rfk, unsigned short* __restrict__ rfv) {
  int m = blockIdx.x;                       // chunk-local retrieval row
  const float* pm = mot + (size_t)m * 512;
  const float* pt = txt + (size_t)(m >> 8) * 512;   // (b*4+r) = m/256
  float v[2], t[2];
  float sv = 0.f, sv2 = 0.f, st = 0.f, st2 = 0.f;
  #pragma unroll
  for (int i = 0; i < 2; i++) {
    v[i] = pm[threadIdx.x + i * 256]; sv += v[i]; sv2 += v[i] * v[i];
    t[i] = pt[threadIdx.x + i * 256]; st += t[i]; st2 += t[i] * t[i];
  }
  __shared__ float red[4][4];
  int lane = threadIdx.x & 63, w = threadIdx.x >> 6;
  sv = wave_sum(sv); sv2 = wave_sum(sv2); st = wave_sum(st); st2 = wave_sum(st2);
  if (!lane) { red[0][w] = sv; red[1][w] = sv2; red[2][w] = st; red[3][w] = st2; }
  __syncthreads();
  float SV = red[0][0] + red[0][1] + red[0][2] + red[0][3];
  float SV2 = red[1][0] + red[1][1] + red[1][2] + red[1][3];
  float ST = red[2][0] + red[2][1] + red[2][2] + red[2][3];
  float ST2 = red[3][0] + red[3][1] + red[3][2] + red[3][3];
  float SA = SV + ST, SA2 = SV2 + ST2;
  float ma = SA / 1024.f, va = SA2 / 1024.f - ma * ma;
  float ra_ = rsqrtf(va + 1e-5f);
  float mv = SV / 512.f, vv = SV2 / 512.f - mv * mv;
  float rv_ = rsqrtf(vv + 1e-5f);
  #pragma unroll
  for (int i = 0; i < 2; i++) {
    int c = threadIdx.x + i * 256;
    rfk[(size_t)m * 1024 + c]       = f2bf((v[i] - ma) * ra_ * g1[c] + b1[c]);
    rfk[(size_t)m * 1024 + 512 + c] = f2bf((t[i] - ma) * ra_ * g1[512 + c] + b1[512 + c]);
    rfv[(size_t)m * 512 + c]        = f2bf((v[i] - mv) * rv_ * g2[c] + b2[c]);
  }
}

// ---------------- per-row mask arrays ----------------
__global__ __launch_bounds__(256) void rowmask_kernel(const int* __restrict__ ct,
    const float* __restrict__ src_mask, const float* __restrict__ re_mask,
    float* __restrict__ kaT, float* __restrict__ kaR, float* __restrict__ kaM,
    float* __restrict__ vmT, float* __restrict__ vmR, float* __restrict__ vmM,
    int nB) {
  int i = blockIdx.x * 256 + threadIdx.x;
  if (i < nB * kRL) {
    int b = i >> 10;
    int c = ct[b];
    float retr = (c / 10 > 0) ? 1.f : 0.f;
    float rm = re_mask[i];
    kaR[i] = (1.f - retr) * kNEG + (1.f - rm) * kNEG;
    vmR[i] = retr * rm;
    float sm = src_mask[i];
    kaM[i] = (1.f - sm) * kNEG;
    vmM[i] = sm;
  }
  if (i < nB * kNT) {
    int b = i / kNT;
    int c = ct[b];
    float text = (c % 10 > 0) ? 1.f : 0.f;
    kaT[i] = (1.f - text) * kNEG;
    vmT[i] = text;
  }
}

// ---------------- weight cast f32 -> bf16 ----------------
__global__ __launch_bounds__(256) void castw(const float* __restrict__ s,
    unsigned short* __restrict__ d, int n) {
  int i = (blockIdx.x * 256 + threadIdx.x) * 4;
  if (i < n) {
    float4 v = *reinterpret_cast<const float4*>(s + i);
    ushort4 o;
    o.x = f2bf(v.x); o.y = f2bf(v.y); o.z = f2bf(v.z); o.w = f2bf(v.w);
    *reinterpret_cast<ushort4*>(d + i) = o;
  }
}

// ---------------- MFMA GEMM: C = A @ W^T (+bias, masks, residual) ----------------
// A: [M][K] bf16, W: [512][K] bf16, N fixed = 512. 128x128 tile, BK=32, 4 waves.
template<int OUTBF>
__global__ __launch_bounds__(256) void gemm_mfma(
    const unsigned short* __restrict__ A, const unsigned short* __restrict__ W,
    const float* __restrict__ bias, void* __restrict__ Cout,
    int M, int K, int m_per_b, int n_total, int out_off,
    const float* __restrict__ rowAdd, const float* __restrict__ rowMul,
    const float* __restrict__ addX) {
  __shared__ unsigned short As[128 * 32];
  __shared__ unsigned short Bs[128 * 32];
  const int tid = threadIdx.x;
  const int lane = tid & 63;
  const int wv = tid >> 6;
  const int wr = (wv >> 1) * 64;   // wave row offset in tile
  const int wc = (wv & 1) * 64;    // wave col offset in tile
  const int m0 = blockIdx.y * 128;
  const int n0 = blockIdx.x * 128;

  // staging: 512 16B-chunks per tile, 2 per thread; swizzle c ^= (r>>1)&3
  const unsigned short* srcA[2]; const unsigned short* srcB[2];
  unsigned short* dstA[2]; unsigned short* dstB[2];
  #pragma unroll
  for (int i = 0; i < 2; i++) {
    int lin = i * 256 + tid;
    int r = lin >> 2, cl = lin & 3;
    int cs = cl ^ ((r >> 1) & 3);
    int ra = m0 + r; if (ra > M - 1) ra = M - 1;
    srcA[i] = A + (size_t)ra * K + cs * 8;
    dstA[i] = &As[lin * 8];
    srcB[i] = W + (size_t)(n0 + r) * K + cs * 8;
    dstB[i] = &Bs[lin * 8];
  }
  // fragment LDS element-offsets (row*32 + chunk*8), same swizzle
  int offA[4], offB[4];
  #pragma unroll
  for (int i = 0; i < 4; i++) {
    int r = wr + i * 16 + (lane & 15);
    int c = (lane >> 4) ^ ((r >> 1) & 3);
    offA[i] = r * 32 + c * 8;
    int rb = wc + i * 16 + (lane & 15);
    int cb = (lane >> 4) ^ ((rb >> 1) & 3);
    offB[i] = rb * 32 + cb * 8;
  }

  f32x4 acc[4][4] = {};

  for (int k0 = 0; k0 < K; k0 += 32) {
    #pragma unroll
    for (int i = 0; i < 2; i++) {
      __builtin_amdgcn_global_load_lds(
          (const __attribute__((address_space(1))) void*)(srcA[i] + k0),
          (__attribute__((address_space(3))) void*)dstA[i], 16, 0, 0);
      __builtin_amdgcn_global_load_lds(
          (const __attribute__((address_space(1))) void*)(srcB[i] + k0),
          (__attribute__((address_space(3))) void*)dstB[i], 16, 0, 0);
    }
    asm volatile("s_waitcnt vmcnt(0)" ::: "memory");
    __syncthreads();
    bf16x8 af[4], bf[4];
    #pragma unroll
    for (int i = 0; i < 4; i++) {
      af[i] = *reinterpret_cast<const bf16x8*>(&As[offA[i]]);
      bf[i] = *reinterpret_cast<const bf16x8*>(&Bs[offB[i]]);
    }
    #pragma unroll
    for (int i = 0; i < 4; i++)
      #pragma unroll
      for (int j = 0; j < 4; j++)
        acc[i][j] = __builtin_amdgcn_mfma_f32_16x16x32_bf16(af[i], bf[j], acc[i][j], 0, 0, 0);
    __syncthreads();
  }

  // epilogue: C/D layout col = lane&15, row = (lane>>4)*4 + reg
  const int colb = n0 + wc + (lane & 15);
  const int rowb = m0 + wr + ((lane >> 4) << 2);
  #pragma unroll
  for (int i = 0; i < 4; i++) {
    #pragma unroll
    for (int r = 0; r < 4; r++) {
      int row = rowb + i * 16 + r;
      if (row >= M) continue;
      size_t orow = (size_t)(row / m_per_b) * n_total + out_off + (row % m_per_b);
      float ra = rowAdd ? rowAdd[row] : 0.f;
      float rm = rowMul ? rowMul[row] : 1.f;
      #pragma unroll
      for (int j = 0; j < 4; j++) {
        int col = colb + j * 16;
        float v = (acc[i][j][r] + bias[col] + ra) * rm;
        if (OUTBF) {
          ((unsigned short*)Cout)[orow * 512 + col] = f2bf(v);
        } else {
          if (addX) v += addX[(size_t)row * 512 + col];
          ((float*)Cout)[orow * 512 + col] = v;
        }
      }
    }
  }
}

// ---------------- f32 GEMM (kept for the tiny emb projection, M=CH) ----------------
struct SiluA {
  const float* A; int K;
  DEV float ld(int m, int k) const {
    float v = A[(size_t)m * K + k];
    return v / (1.f + __expf(-v));
  }
};

template<class AL>
__global__ __launch_bounds__(256) void gemm64(AL al, const float* __restrict__ W,
    const float* __restrict__ bias, float* __restrict__ C, int M, int K, int Dout,
    int m_per_b, int n_total, int out_off) {
  __shared__ float As[16][68];
  __shared__ float Ws[16][68];
  int m0 = blockIdx.y * 64, n0 = blockIdx.x * 64;
  int tid = threadIdx.x;
  int tx = tid & 15, ty = tid >> 4;
  float acc[4][4] = {};
  int mm = tid >> 2, kk = (tid & 3) << 2;
  int ma = m0 + mm; if (ma >= M) ma = M - 1;
  int nn = tid >> 2;
  for (int k0 = 0; k0 < K; k0 += 16) {
    __syncthreads();
    float a0 = al.ld(ma, k0 + kk + 0);
    float a1 = al.ld(ma, k0 + kk + 1);
    float a2 = al.ld(ma, k0 + kk + 2);
    float a3 = al.ld(ma, k0 + kk + 3);
    As[kk + 0][mm] = a0; As[kk + 1][mm] = a1; As[kk + 2][mm] = a2; As[kk + 3][mm] = a3;
    const float4 wv = *reinterpret_cast<const float4*>(&W[(size_t)(n0 + nn) * K + k0 + kk]);
    Ws[kk + 0][nn] = wv.x; Ws[kk + 1][nn] = wv.y; Ws[kk + 2][nn] = wv.z; Ws[kk + 3][nn] = wv.w;
    __syncthreads();
    #pragma unroll
    for (int k = 0; k < 16; k++) {
      float4 av = *reinterpret_cast<const float4*>(&As[k][ty * 4]);
      float4 bv = *reinterpret_cast<const float4*>(&Ws[k][tx * 4]);
      float a[4] = {av.x, av.y, av.z, av.w};
      float b[4] = {bv.x, bv.y, bv.z, bv.w};
      #pragma unroll
      for (int i = 0; i < 4; i++)
        #pragma unroll
        for (int j = 0; j < 4; j++)
          acc[i][j] = fmaf(a[i], b[j], acc[i][j]);
    }
  }
  #pragma unroll
  for (int i = 0; i < 4; i++) {
    int m = m0 + ty * 4 + i;
    if (m >= M) continue;
    size_t orow = (size_t)(m / m_per_b) * n_total + out_off + (m % m_per_b);
    #pragma unroll
    for (int j = 0; j < 4; j++) {
      int n = n0 + tx * 4 + j;
      C[orow * Dout + n] = acc[i][j] + bias[n];
    }
  }
}

// ---------------- column-softmax denominator for k (over N) ----------------
__global__ __launch_bounds__(256) void colsum_part(const unsigned short* __restrict__ kc,
    float* __restrict__ part) {
  int b = blockIdx.x >> 1;
  int d = ((blockIdx.x & 1) << 8) + threadIdx.x;
  int c = blockIdx.y;
  int nbeg = c * 266, nend = min(kN, nbeg + 266);
  const unsigned short* p = kc + (size_t)b * kN * 512 + d;
  float s = 0.f;
  for (int n = nbeg; n < nend; n++) s += __expf(bf2f(p[(size_t)n * 512]));
  part[((size_t)b * 512 + d) * 8 + c] = s;
}
__global__ __launch_bounds__(256) void colsum_fin(const float* __restrict__ part,
    float* __restrict__ sinv) {
  int i = blockIdx.x * 256 + threadIdx.x;
  float s = 0.f;
  #pragma unroll
  for (int c = 0; c < 8; c++) s += part[(size_t)i * 8 + c];
  sinv[i] = 1.f / s;
}

// ---------------- attention = (softmax_N k)^T v  per (b,h): 64x64 ----------------
__global__ __launch_bounds__(256) void att_einsum(const unsigned short* __restrict__ kc,
    const unsigned short* __restrict__ vv, const float* __restrict__ sinv,
    float* __restrict__ att) {
  int bh = blockIdx.x; int b = bh >> 3, h = bh & 7;
  const unsigned short* kp = kc + (size_t)b * kN * 512 + h * 64;
  const unsigned short* vp = vv + (size_t)b * kN * 512 + h * 64;
  __shared__ float ks[32][64];
  __shared__ float vs[32][64];
  int tid = threadIdx.x;
  int td = tid >> 4, tl = tid & 15;
  float acc[4][4] = {};
  for (int n0 = 0; n0 < kN; n0 += 32) {
    __syncthreads();
    #pragma unroll
    for (int idx = tid; idx < 2048; idx += 256) {
      int dd = idx & 63, nn = idx >> 6;
      int n = n0 + nn;
      float kval = 0.f, vval = 0.f;
      if (n < kN) {
        kval = __expf(bf2f(kp[(size_t)n * 512 + dd]));
        vval = bf2f(vp[(size_t)n * 512 + dd]);
      }
      ks[nn][dd] = kval; vs[nn][dd] = vval;
    }
    __syncthreads();
    #pragma unroll
    for (int nn = 0; nn < 32; nn++) {
      float4 kv = *reinterpret_cast<const float4*>(&ks[nn][td * 4]);
      float4 vl = *reinterpret_cast<const float4*>(&vs[nn][tl * 4]);
      float a[4] = {kv.x, kv.y, kv.z, kv.w};
      float c[4] = {vl.x, vl.y, vl.z, vl.w};
      #pragma unroll
      for (int i = 0; i < 4; i++)
        #pragma unroll
        for (int j = 0; j < 4; j++)
          acc[i][j] = fmaf(a[i], c[j], acc[i][j]);
    }
  }
  #pragma unroll
  for (int i = 0; i < 4; i++) {
    float si = sinv[b * 512 + h * 64 + td * 4 + i];
    #pragma unroll
    for (int j = 0; j < 4; j++)
      att[(size_t)bh * 4096 + (td * 4 + i) * 64 + tl * 4 + j] = acc[i][j] * si;
  }
}

// ---------------- y = (softmax_d q) @ att ----------------
__global__ __launch_bounds__(256) void y_einsum(const unsigned short* __restrict__ q,
    const float* __restrict__ att, float* __restrict__ y) {
  int bh = blockIdx.x; int b = bh >> 3, h = bh & 7;
  int t0 = blockIdx.y * 64;
  __shared__ float as_[64][64];
  __shared__ float qs[64][68];
  int tid = threadIdx.x;
  #pragma unroll
  for (int idx = tid; idx < 4096; idx += 256) {
    int l = idx & 63, dd = idx >> 6;
    as_[dd][l] = att[(size_t)bh * 4096 + idx];
  }
  #pragma unroll
  for (int idx = tid; idx < 4096; idx += 256) {
    int dd = idx & 63, tt = idx >> 6;
    qs[tt][dd] = __expf(bf2f(q[(size_t)(b * 1024 + t0 + tt) * 512 + h * 64 + dd]));
  }
  __syncthreads();
  int t = tid >> 2, lb = (tid & 3) << 4;
  float rsum = 0.f;
  for (int dd = 0; dd < 64; dd++) rsum += qs[t][dd];
  float rinv = 1.f / rsum;
  float acc[16] = {};
  for (int dd = 0; dd < 64; dd++) {
    float qv = qs[t][dd];
    #pragma unroll
    for (int j = 0; j < 16; j++) acc[j] = fmaf(qv, as_[dd][lb + j], acc[j]);
  }
  float* yp = y + (size_t)(b * 1024 + t0 + t) * 512 + h * 64 + lb;
  #pragma unroll
  for (int j = 0; j < 16; j++) yp[j] = acc[j] * rinv;
}

// ---------------- LN(y)*(1+scale)+shift then SiLU -> bf16 ----------------
__global__ __launch_bounds__(256) void mod_kernel(const float* __restrict__ y,
    const float* __restrict__ ss, const float* __restrict__ g, const float* __restrict__ be,
    unsigned short* __restrict__ h) {
  int row = blockIdx.x; int b = row >> 10;
  const float* p = y + (size_t)row * 512;
  unsigned short* o = h + (size_t)row * 512;
  float v[2]; float s = 0.f, s2 = 0.f;
  #pragma unroll
  for (int i = 0; i < 2; i++) {
    v[i] = p[threadIdx.x + i * 256];
    s += v[i]; s2 += v[i] * v[i];
  }
  __shared__ float red[2][4];
  int lane = threadIdx.x & 63, w = threadIdx.x >> 6;
  s = wave_sum(s); s2 = wave_sum(s2);
  if (!lane) { red[0][w] = s; red[1][w] = s2; }
  __syncthreads();
  s = red[0][0] + red[0][1] + red[0][2] + red[0][3];
  s2 = red[1][0] + red[1][1] + red[1][2] + red[1][3];
  float mean = s / 512.f, var = s2 / 512.f - mean * mean;
  float rstd = rsqrtf(var + 1e-5f);
  #pragma unroll
  for (int i = 0; i < 2; i++) {
    int c = threadIdx.x + i * 256;
    float val = (v[i] - mean) * rstd * g[c] + be[c];
    val = val * (1.f + ss[b * 1024 + c]) + ss[b * 1024 + 512 + c];
    o[c] = f2bf(val / (1.f + __expf(-val)));
  }
}

}  // namespace

extern "C" void kernel_launch(void* const* d_in, const int* in_sizes, int n_in,
                              void* d_out, int out_size, void* d_ws, size_t ws_size,
                              hipStream_t stream) {
  const float* x        = (const float*)d_in[0];
  const float* xf       = (const float*)d_in[1];
  const float* emb      = (const float*)d_in[2];
  const float* src_mask = (const float*)d_in[3];
  const int*   cond     = (const int*)d_in[4];
  const float* re_motion= (const float*)d_in[5];
  const float* re_text  = (const float*)d_in[6];
  const float* re_mask  = (const float*)d_in[7];
  const float* norm_g = (const float*)d_in[8],  * norm_b = (const float*)d_in[9];
  const float* tnorm_g= (const float*)d_in[10], * tnorm_b= (const float*)d_in[11];
  const float* rn1_g  = (const float*)d_in[12], * rn1_b  = (const float*)d_in[13];
  const float* rn2_g  = (const float*)d_in[14], * rn2_b  = (const float*)d_in[15];
  const float* Wq  = (const float*)d_in[16], * bq  = (const float*)d_in[17];
  const float* Wkt = (const float*)d_in[18], * bkt = (const float*)d_in[19];
  const float* Wvt = (const float*)d_in[20], * bvt = (const float*)d_in[21];
  const float* Wkm = (const float*)d_in[22], * bkm = (const float*)d_in[23];
  const float* Wvm = (const float*)d_in[24], * bvm = (const float*)d_in[25];
  const float* Wkr = (const float*)d_in[26], * bkr = (const float*)d_in[27];
  const float* Wvr = (const float*)d_in[28], * bvr = (const float*)d_in[29];
  const float* emb_W = (const float*)d_in[30], * emb_b = (const float*)d_in[31];
  const float* snorm_g = (const float*)d_in[32], * snorm_b = (const float*)d_in[33];
  const float* out_W = (const float*)d_in[34], * out_b = (const float*)d_in[35];
  float* out = (float*)d_out;

  char* base = (char*)d_ws;
  size_t off = 0;
  auto ab = [&](size_t nb) { char* p = base + off; off = (off + nb + 255) & ~(size_t)255; return p; };

  // persistent bf16 weights
  unsigned short* wq_bf  = (unsigned short*)ab(512 * 512 * 2);
  unsigned short* wkt_bf = (unsigned short*)ab(512 * 256 * 2);
  unsigned short* wvt_bf = (unsigned short*)ab(512 * 256 * 2);
  unsigned short* wkm_bf = (unsigned short*)ab(512 * 512 * 2);
  unsigned short* wvm_bf = (unsigned short*)ab(512 * 512 * 2);
  unsigned short* wkr_bf = (unsigned short*)ab(512 * 1024 * 2);
  unsigned short* wvr_bf = (unsigned short*)ab(512 * 512 * 2);
  unsigned short* wout_bf= (unsigned short*)ab(512 * 512 * 2);
  const size_t fixed_off = off;

  auto pad = [](size_t n) { return (n + 255) & ~(size_t)255; };
  auto chunk_bytes = [&](size_t CH) -> size_t {
    size_t s = 0;
    s += pad(CH * 1024 * 512 * 2);        // xn_bf (reused as h_bf)
    s += pad(CH * kNT * 256 * 2);         // xfn_bf
    s += pad(CH * 1024 * 1024 * 2);       // rfk_bf (reused as yb f32)
    s += pad(CH * 1024 * 512 * 2);        // rfv_bf
    s += pad(CH * 1024 * 512 * 2);        // qb_bf
    s += pad((size_t)CH * kN * 512 * 2);  // kc_bf
    s += pad((size_t)CH * kN * 512 * 2);  // vb_bf
    s += pad(CH * 8 * 4096 * 4);          // attb
    s += pad(CH * 1024 * 4);              // ssb
    s += 2 * pad(CH * kNT * 4) + 4 * pad(CH * 1024 * 4);  // masks
    s += pad(CH * 512 * 8 * 4) + pad(CH * 512 * 4);        // part, sinv
    return s;
  };
  int CH = 32;
  while (CH > 1 && fixed_off + chunk_bytes(CH) > ws_size) CH >>= 1;

  // cast weights once
  auto cl = [&](const float* s, unsigned short* d, int n) {
    castw<<<dim3((n / 4 + 255) / 256), 256, 0, stream>>>(s, d, n);
  };
  cl(Wq,  wq_bf,  512 * 512);
  cl(Wkt, wkt_bf, 512 * 256);
  cl(Wvt, wvt_bf, 512 * 256);
  cl(Wkm, wkm_bf, 512 * 512);
  cl(Wvm, wvm_bf, 512 * 512);
  cl(Wkr, wkr_bf, 512 * 1024);
  cl(Wvr, wvr_bf, 512 * 512);
  cl(out_W, wout_bf, 512 * 512);

  for (int b0 = 0; b0 < kB; b0 += CH) {
    off = fixed_off;
    const int MRc = CH * 1024;
    const int MTc = CH * kNT;

    unsigned short* xn_bf  = (unsigned short*)ab((size_t)MRc * 512 * 2);
    unsigned short* xfn_bf = (unsigned short*)ab((size_t)MTc * 256 * 2);
    unsigned short* rfk_bf = (unsigned short*)ab((size_t)MRc * 1024 * 2);
    unsigned short* rfv_bf = (unsigned short*)ab((size_t)MRc * 512 * 2);
    unsigned short* qb_bf  = (unsigned short*)ab((size_t)MRc * 512 * 2);
    unsigned short* kc_bf  = (unsigned short*)ab((size_t)CH * kN * 512 * 2);
    unsigned short* vb_bf  = (unsigned short*)ab((size_t)CH * kN * 512 * 2);
    float* attb = (float*)ab((size_t)CH * 8 * 4096 * 4);
    float* ssb  = (float*)ab((size_t)CH * 1024 * 4);
    float* kaT = (float*)ab((size_t)CH * kNT * 4);
    float* vmT = (float*)ab((size_t)CH * kNT * 4);
    float* kaR = (float*)ab((size_t)CH * 1024 * 4);
    float* kaM = (float*)ab((size_t)CH * 1024 * 4);
    float* vmR = (float*)ab((size_t)CH * 1024 * 4);
    float* vmM = (float*)ab((size_t)CH * 1024 * 4);
    float* part = (float*)ab((size_t)CH * 512 * 8 * 4);
    float* sinv = (float*)ab((size_t)CH * 512 * 4);
    float* yb = (float*)rfk_bf;              // rfk dead after Wkr GEMM
    unsigned short* h_bf = xn_bf;            // xn dead after Wvm GEMM

    const float* x_c   = x + (size_t)b0 * kT * 512;
    const float* xf_c  = xf + (size_t)b0 * kNT * 256;
    const float* emb_c = emb + (size_t)b0 * 2048;
    const float* sm_c  = src_mask + (size_t)b0 * kT;
    const int*   ct_c  = cond + b0;
    const float* rm_c  = re_motion + (size_t)b0 * kRL * 512;
    const float* rt_c  = re_text + (size_t)b0 * kR * 512;
    const float* rmask_c = re_mask + (size_t)b0 * kRL;
    float* out_c = out + (size_t)b0 * kT * 512;

    // --- preprocessing ---
    ln_bf16<512><<<dim3(MRc), 256, 0, stream>>>(x_c, norm_g, norm_b, xn_bf);
    ln_bf16<256><<<dim3(MTc), 256, 0, stream>>>(xf_c, tnorm_g, tnorm_b, xfn_bf);
    rfk_norm<<<dim3(MRc), 256, 0, stream>>>(rm_c, rt_c, rn1_g, rn1_b, rn2_g, rn2_b,
                                            rfk_bf, rfv_bf);
    rowmask_kernel<<<dim3(CH * 4), 256, 0, stream>>>(ct_c, sm_c, rmask_c,
                                                     kaT, kaR, kaM, vmT, vmR, vmM, CH);

    // --- projections (bf16 MFMA) ---
    gemm_mfma<1><<<dim3(4, CH * 8), 256, 0, stream>>>(xn_bf, wq_bf, bq, qb_bf,
        MRc, 512, MRc, 0, 0, nullptr, nullptr, nullptr);
    gemm_mfma<1><<<dim3(4, (MTc + 127) / 128), 256, 0, stream>>>(xfn_bf, wkt_bf, bkt, kc_bf,
        MTc, 256, kNT, kN, 0, kaT, nullptr, nullptr);
    gemm_mfma<1><<<dim3(4, CH * 8), 256, 0, stream>>>(rfk_bf, wkr_bf, bkr, kc_bf,
        MRc, 1024, kRL, kN, kNT, kaR, nullptr, nullptr);
    gemm_mfma<1><<<dim3(4, CH * 8), 256, 0, stream>>>(xn_bf, wkm_bf, bkm, kc_bf,
        MRc, 512, kT, kN, kNT + kRL, kaM, nullptr, nullptr);
    gemm_mfma<1><<<dim3(4, (MTc + 127) / 128), 256, 0, stream>>>(xfn_bf, wvt_bf, bvt, vb_bf,
        MTc, 256, kNT, kN, 0, nullptr, vmT, nullptr);
    gemm_mfma<1><<<dim3(4, CH * 8), 256, 0, stream>>>(rfv_bf, wvr_bf, bvr, vb_bf,
        MRc, 512, kRL, kN, kNT, nullptr, vmR, nullptr);
    gemm_mfma<1><<<dim3(4, CH * 8), 256, 0, stream>>>(xn_bf, wvm_bf, bvm, vb_bf,
        MRc, 512, kT, kN, kNT + kRL, nullptr, vmM, nullptr);
    gemm64<SiluA><<<dim3(16, 1), 256, 0, stream>>>(SiluA{emb_c, 2048}, emb_W, emb_b, ssb,
        CH, 2048, 1024, CH, 0, 0);

    // --- attention (softmaxes folded in) ---
    colsum_part<<<dim3(CH * 2, 8), 256, 0, stream>>>(kc_bf, part);
    colsum_fin<<<dim3(CH * 2), 256, 0, stream>>>(part, sinv);
    att_einsum<<<dim3(CH * 8), 256, 0, stream>>>(kc_bf, vb_bf, sinv, attb);
    y_einsum<<<dim3(CH * 8, 16), 256, 0, stream>>>(qb_bf, attb, yb);

    // --- modulation + output projection + residual ---
    mod_kernel<<<dim3(MRc), 256, 0, stream>>>(yb, ssb, snorm_g, snorm_b, h_bf);
    gemm_mfma<0><<<dim3(4, CH * 8), 256, 0, stream>>>(h_bf, wout_bf, out_b, out_c,
        MRc, 512, MRc, 0, 0, nullptr, nullptr, x_c);
  }
}

// Round 4
// 1028.659 us; speedup vs baseline: 2.8720x; 1.4832x over previous
//
#include <hip/hip_runtime.h>
#include <cstddef>
#include <cstdint>

#define DEV __device__ __forceinline__

namespace {

constexpr int kH = 8;
constexpr int kB = 32, kT = 1024, kNT = 77, kR = 4, kLR = 256;
constexpr int kRL = kR * kLR;            // 1024
constexpr int kN = kNT + kRL + kT;       // 2125
constexpr float kNEG = -1000000.0f;
constexpr int kNS = 8;                   // N-slices for attention reduction
constexpr int kSL = 266;                 // ceil(2125/8)

typedef __bf16 bf16x8 __attribute__((ext_vector_type(8)));
typedef float f32x4 __attribute__((ext_vector_type(4)));

DEV unsigned short f2bf(float f) {
  unsigned int u = __float_as_uint(f);
  u += 0x7fffu + ((u >> 16) & 1u);
  return (unsigned short)(u >> 16);
}
DEV float bf2f(unsigned short h) { return __uint_as_float(((unsigned int)h) << 16); }

DEV float wave_sum(float v) {
  #pragma unroll
  for (int s = 32; s; s >>= 1) v += __shfl_xor(v, s);
  return v;
}

// ---------------- LayerNorm -> bf16 ----------------
template<int COLS>
__global__ __launch_bounds__(256) void ln_bf16(const float* __restrict__ in,
    const float* __restrict__ g, const float* __restrict__ be,
    unsigned short* __restrict__ out) {
  constexpr int PT = COLS / 256;
  int row = blockIdx.x;
  const float* p = in + (size_t)row * COLS;
  unsigned short* o = out + (size_t)row * COLS;
  float v[PT]; float s = 0.f, s2 = 0.f;
  #pragma unroll
  for (int i = 0; i < PT; i++) {
    v[i] = p[threadIdx.x + i * 256];
    s += v[i]; s2 += v[i] * v[i];
  }
  __shared__ float red[2][4];
  int lane = threadIdx.x & 63, w = threadIdx.x >> 6;
  s = wave_sum(s); s2 = wave_sum(s2);
  if (!lane) { red[0][w] = s; red[1][w] = s2; }
  __syncthreads();
  s = red[0][0] + red[0][1] + red[0][2] + red[0][3];
  s2 = red[1][0] + red[1][1] + red[1][2] + red[1][3];
  float mean = s / COLS;
  float var = s2 / COLS - mean * mean;
  float rstd = rsqrtf(var + 1e-5f);
  #pragma unroll
  for (int i = 0; i < PT; i++) {
    int c = threadIdx.x + i * 256;
    o[c] = f2bf((v[i] - mean) * rstd * g[c] + be[c]);
  }
}

// ---------------- retrieval LNs fused: stats + normalize -> bf16 ----------------
__global__ __launch_bounds__(256) void rfk_norm(const float* __restrict__ mot,
    const float* __restrict__ txt,
    const float* __restrict__ g1, const float* __restrict__ b1,
    const float* __restrict__ g2, const float* __restrict__ b2,
    unsigned short* __restrict__ rfk, unsigned short* __restrict__ rfv) {
  int m = blockIdx.x;                       // chunk-local retrieval row
  const float* pm = mot + (size_t)m * 512;
  const float* pt = txt + (size_t)(m >> 8) * 512;   // (b*4+r) = m/256
  float v[2], t[2];
  float sv = 0.f, sv2 = 0.f, st = 0.f, st2 = 0.f;
  #pragma unroll
  for (int i = 0; i < 2; i++) {
    v[i] = pm[threadIdx.x + i * 256]; sv += v[i]; sv2 += v[i] * v[i];
    t[i] = pt[threadIdx.x + i * 256]; st += t[i]; st2 += t[i] * t[i];
  }
  __shared__ float red[4][4];
  int lane = threadIdx.x & 63, w = threadIdx.x >> 6;
  sv = wave_sum(sv); sv2 = wave_sum(sv2); st = wave_sum(st); st2 = wave_sum(st2);
  if (!lane) { red[0][w] = sv; red[1][w] = sv2; red[2][w] = st; red[3][w] = st2; }
  __syncthreads();
  float SV = red[0][0] + red[0][1] + red[0][2] + red[0][3];
  float SV2 = red[1][0] + red[1][1] + red[1][2] + red[1][3];
  float ST = red[2][0] + red[2][1] + red[2][2] + red[2][3];
  float ST2 = red[3][0] + red[3][1] + red[3][2] + red[3][3];
  float SA = SV + ST, SA2 = SV2 + ST2;
  float ma = SA / 1024.f, va = SA2 / 1024.f - ma * ma;
  float ra_ = rsqrtf(va + 1e-5f);
  float mv = SV / 512.f, vv = SV2 / 512.f - mv * mv;
  float rv_ = rsqrtf(vv + 1e-5f);
  #pragma unroll
  for (int i = 0; i < 2; i++) {
    int c = threadIdx.x + i * 256;
    rfk[(size_t)m * 1024 + c]       = f2bf((v[i] - ma) * ra_ * g1[c] + b1[c]);
    rfk[(size_t)m * 1024 + 512 + c] = f2bf((t[i] - ma) * ra_ * g1[512 + c] + b1[512 + c]);
    rfv[(size_t)m * 512 + c]        = f2bf((v[i] - mv) * rv_ * g2[c] + b2[c]);
  }
}

// ---------------- per-row mask arrays ----------------
__global__ __launch_bounds__(256) void rowmask_kernel(const int* __restrict__ ct,
    const float* __restrict__ src_mask, const float* __restrict__ re_mask,
    float* __restrict__ kaT, float* __restrict__ kaR, float* __restrict__ kaM,
    float* __restrict__ vmT, float* __restrict__ vmR, float* __restrict__ vmM,
    int nB) {
  int i = blockIdx.x * 256 + threadIdx.x;
  if (i < nB * kRL) {
    int b = i >> 10;
    int c = ct[b];
    float retr = (c / 10 > 0) ? 1.f : 0.f;
    float rm = re_mask[i];
    kaR[i] = (1.f - retr) * kNEG + (1.f - rm) * kNEG;
    vmR[i] = retr * rm;
    float sm = src_mask[i];
    kaM[i] = (1.f - sm) * kNEG;
    vmM[i] = sm;
  }
  if (i < nB * kNT) {
    int b = i / kNT;
    int c = ct[b];
    float text = (c % 10 > 0) ? 1.f : 0.f;
    kaT[i] = (1.f - text) * kNEG;
    vmT[i] = text;
  }
}

// ---------------- weight cast f32 -> bf16 ----------------
__global__ __launch_bounds__(256) void castw(const float* __restrict__ s,
    unsigned short* __restrict__ d, int n) {
  int i = (blockIdx.x * 256 + threadIdx.x) * 4;
  if (i < n) {
    float4 v = *reinterpret_cast<const float4*>(s + i);
    ushort4 o;
    o.x = f2bf(v.x); o.y = f2bf(v.y); o.z = f2bf(v.z); o.w = f2bf(v.w);
    *reinterpret_cast<ushort4*>(d + i) = o;
  }
}

// ---------------- MFMA GEMM: C = A @ W^T (+bias, masks, residual) ----------------
// OUTMODE: 0 = f32 (+optional addX residual), 1 = bf16, 2 = bf16(exp(.))
template<int OUTMODE>
__global__ __launch_bounds__(256) void gemm_mfma(
    const unsigned short* __restrict__ A, const unsigned short* __restrict__ W,
    const float* __restrict__ bias, void* __restrict__ Cout,
    int M, int K, int m_per_b, int n_total, int out_off,
    const float* __restrict__ rowAdd, const float* __restrict__ rowMul,
    const float* __restrict__ addX) {
  __shared__ unsigned short As[128 * 32];
  __shared__ unsigned short Bs[128 * 32];
  const int tid = threadIdx.x;
  const int lane = tid & 63;
  const int wv = tid >> 6;
  const int wr = (wv >> 1) * 64;
  const int wc = (wv & 1) * 64;
  const int m0 = blockIdx.y * 128;
  const int n0 = blockIdx.x * 128;

  const unsigned short* srcA[2]; const unsigned short* srcB[2];
  unsigned short* dstA[2]; unsigned short* dstB[2];
  #pragma unroll
  for (int i = 0; i < 2; i++) {
    int lin = i * 256 + tid;
    int r = lin >> 2, cl = lin & 3;
    int cs = cl ^ ((r >> 1) & 3);
    int ra = m0 + r; if (ra > M - 1) ra = M - 1;
    srcA[i] = A + (size_t)ra * K + cs * 8;
    dstA[i] = &As[lin * 8];
    srcB[i] = W + (size_t)(n0 + r) * K + cs * 8;
    dstB[i] = &Bs[lin * 8];
  }
  int offA[4], offB[4];
  #pragma unroll
  for (int i = 0; i < 4; i++) {
    int r = wr + i * 16 + (lane & 15);
    int c = (lane >> 4) ^ ((r >> 1) & 3);
    offA[i] = r * 32 + c * 8;
    int rb = wc + i * 16 + (lane & 15);
    int cb = (lane >> 4) ^ ((rb >> 1) & 3);
    offB[i] = rb * 32 + cb * 8;
  }

  f32x4 acc[4][4] = {};

  for (int k0 = 0; k0 < K; k0 += 32) {
    #pragma unroll
    for (int i = 0; i < 2; i++) {
      __builtin_amdgcn_global_load_lds(
          (const __attribute__((address_space(1))) void*)(srcA[i] + k0),
          (__attribute__((address_space(3))) void*)dstA[i], 16, 0, 0);
      __builtin_amdgcn_global_load_lds(
          (const __attribute__((address_space(1))) void*)(srcB[i] + k0),
          (__attribute__((address_space(3))) void*)dstB[i], 16, 0, 0);
    }
    asm volatile("s_waitcnt vmcnt(0)" ::: "memory");
    __syncthreads();
    bf16x8 af[4], bf[4];
    #pragma unroll
    for (int i = 0; i < 4; i++) {
      af[i] = *reinterpret_cast<const bf16x8*>(&As[offA[i]]);
      bf[i] = *reinterpret_cast<const bf16x8*>(&Bs[offB[i]]);
    }
    #pragma unroll
    for (int i = 0; i < 4; i++)
      #pragma unroll
      for (int j = 0; j < 4; j++)
        acc[i][j] = __builtin_amdgcn_mfma_f32_16x16x32_bf16(af[i], bf[j], acc[i][j], 0, 0, 0);
    __syncthreads();
  }

  const int colb = n0 + wc + (lane & 15);
  const int rowb = m0 + wr + ((lane >> 4) << 2);
  #pragma unroll
  for (int i = 0; i < 4; i++) {
    #pragma unroll
    for (int r = 0; r < 4; r++) {
      int row = rowb + i * 16 + r;
      if (row >= M) continue;
      size_t orow = (size_t)(row / m_per_b) * n_total + out_off + (row % m_per_b);
      float ra = rowAdd ? rowAdd[row] : 0.f;
      float rm = rowMul ? rowMul[row] : 1.f;
      #pragma unroll
      for (int j = 0; j < 4; j++) {
        int col = colb + j * 16;
        float v = (acc[i][j][r] + bias[col] + ra) * rm;
        if (OUTMODE == 2) {
          ((unsigned short*)Cout)[orow * 512 + col] = f2bf(__expf(v));
        } else if (OUTMODE == 1) {
          ((unsigned short*)Cout)[orow * 512 + col] = f2bf(v);
        } else {
          if (addX) v += addX[(size_t)row * 512 + col];
          ((float*)Cout)[orow * 512 + col] = v;
        }
      }
    }
  }
}

// ---------------- f32 GEMM (tiny emb projection, M=CH) ----------------
struct SiluA {
  const float* A; int K;
  DEV float ld(int m, int k) const {
    float v = A[(size_t)m * K + k];
    return v / (1.f + __expf(-v));
  }
};

template<class AL>
__global__ __launch_bounds__(256) void gemm64(AL al, const float* __restrict__ W,
    const float* __restrict__ bias, float* __restrict__ C, int M, int K, int Dout,
    int m_per_b, int n_total, int out_off) {
  __shared__ float As[16][68];
  __shared__ float Ws[16][68];
  int m0 = blockIdx.y * 64, n0 = blockIdx.x * 64;
  int tid = threadIdx.x;
  int tx = tid & 15, ty = tid >> 4;
  float acc[4][4] = {};
  int mm = tid >> 2, kk = (tid & 3) << 2;
  int ma = m0 + mm; if (ma >= M) ma = M - 1;
  int nn = tid >> 2;
  for (int k0 = 0; k0 < K; k0 += 16) {
    __syncthreads();
    float a0 = al.ld(ma, k0 + kk + 0);
    float a1 = al.ld(ma, k0 + kk + 1);
    float a2 = al.ld(ma, k0 + kk + 2);
    float a3 = al.ld(ma, k0 + kk + 3);
    As[kk + 0][mm] = a0; As[kk + 1][mm] = a1; As[kk + 2][mm] = a2; As[kk + 3][mm] = a3;
    const float4 wv = *reinterpret_cast<const float4*>(&W[(size_t)(n0 + nn) * K + k0 + kk]);
    Ws[kk + 0][nn] = wv.x; Ws[kk + 1][nn] = wv.y; Ws[kk + 2][nn] = wv.z; Ws[kk + 3][nn] = wv.w;
    __syncthreads();
    #pragma unroll
    for (int k = 0; k < 16; k++) {
      float4 av = *reinterpret_cast<const float4*>(&As[k][ty * 4]);
      float4 bv = *reinterpret_cast<const float4*>(&Ws[k][tx * 4]);
      float a[4] = {av.x, av.y, av.z, av.w};
      float b[4] = {bv.x, bv.y, bv.z, bv.w};
      #pragma unroll
      for (int i = 0; i < 4; i++)
        #pragma unroll
        for (int j = 0; j < 4; j++)
          acc[i][j] = fmaf(a[i], b[j], acc[i][j]);
    }
  }
  #pragma unroll
  for (int i = 0; i < 4; i++) {
    int m = m0 + ty * 4 + i;
    if (m >= M) continue;
    size_t orow = (size_t)(m / m_per_b) * n_total + out_off + (m % m_per_b);
    #pragma unroll
    for (int j = 0; j < 4; j++) {
      int n = n0 + tx * 4 + j;
      C[orow * Dout + n] = acc[i][j] + bias[n];
    }
  }
}

// ---------------- coalesced column-sum of E over N (partial per slice) ----------------
__global__ __launch_bounds__(256) void colsumE(const unsigned short* __restrict__ E,
    float* __restrict__ part) {
  int b = blockIdx.x, s = blockIdx.y;
  int nbeg = s * kSL, nend = min(kN, nbeg + kSL);
  int grp = threadIdx.x >> 6, lane = threadIdx.x & 63;
  const unsigned short* base = E + (size_t)b * kN * 512 + lane * 8;
  float acc[8] = {};
  for (int n = nbeg + grp; n < nend; n += 4) {
    const unsigned short* p = base + (size_t)n * 512;
    ushort4 u0 = *reinterpret_cast<const ushort4*>(p);
    ushort4 u1 = *reinterpret_cast<const ushort4*>(p + 4);
    acc[0] += bf2f(u0.x); acc[1] += bf2f(u0.y); acc[2] += bf2f(u0.z); acc[3] += bf2f(u0.w);
    acc[4] += bf2f(u1.x); acc[5] += bf2f(u1.y); acc[6] += bf2f(u1.z); acc[7] += bf2f(u1.w);
  }
  __shared__ float sacc[4][512];
  #pragma unroll
  for (int j = 0; j < 8; j++) sacc[grp][lane * 8 + j] = acc[j];
  __syncthreads();
  for (int c = threadIdx.x; c < 512; c += 256) {
    part[((size_t)b * kNS + s) * 512 + c] =
        sacc[0][c] + sacc[1][c] + sacc[2][c] + sacc[3][c];
  }
}
__global__ __launch_bounds__(256) void colsum_fin(const float* __restrict__ part,
    float* __restrict__ sinv) {
  int i = blockIdx.x * 256 + threadIdx.x;   // CH*512 total
  int b = i >> 9, d = i & 511;
  float s = 0.f;
  #pragma unroll
  for (int c = 0; c < kNS; c++) s += part[((size_t)b * kNS + c) * 512 + d];
  sinv[i] = 1.f / s;
}

// ---------------- attention partials: P[bh][s] = E_slice^T V_slice (64x64) ----------------
__global__ __launch_bounds__(256) void attp_kernel(const unsigned short* __restrict__ E,
    const unsigned short* __restrict__ V, float* __restrict__ part) {
  int bh = blockIdx.x; int b = bh >> 3, h = bh & 7;
  int s = blockIdx.y;
  int nbeg = s * kSL, nend = min(kN, nbeg + kSL);
  const unsigned short* kp = E + (size_t)b * kN * 512 + h * 64;
  const unsigned short* vp = V + (size_t)b * kN * 512 + h * 64;
  __shared__ float ks[32][68];
  __shared__ float vs[32][68];
  int tid = threadIdx.x;
  int td = tid >> 4, tl = tid & 15;
  int snn = tid >> 3, sc0 = (tid & 7) * 8;
  float acc[4][4] = {};
  for (int n0 = nbeg; n0 < nend; n0 += 32) {
    __syncthreads();
    int n = n0 + snn;
    float kv[8] = {}, vv[8] = {};
    if (n < nend) {
      const unsigned short* pk = kp + (size_t)n * 512 + sc0;
      const unsigned short* pv = vp + (size_t)n * 512 + sc0;
      ushort4 a0 = *reinterpret_cast<const ushort4*>(pk);
      ushort4 a1 = *reinterpret_cast<const ushort4*>(pk + 4);
      ushort4 b0 = *reinterpret_cast<const ushort4*>(pv);
      ushort4 b1 = *reinterpret_cast<const ushort4*>(pv + 4);
      kv[0] = bf2f(a0.x); kv[1] = bf2f(a0.y); kv[2] = bf2f(a0.z); kv[3] = bf2f(a0.w);
      kv[4] = bf2f(a1.x); kv[5] = bf2f(a1.y); kv[6] = bf2f(a1.z); kv[7] = bf2f(a1.w);
      vv[0] = bf2f(b0.x); vv[1] = bf2f(b0.y); vv[2] = bf2f(b0.z); vv[3] = bf2f(b0.w);
      vv[4] = bf2f(b1.x); vv[5] = bf2f(b1.y); vv[6] = bf2f(b1.z); vv[7] = bf2f(b1.w);
    }
    #pragma unroll
    for (int j = 0; j < 8; j++) { ks[snn][sc0 + j] = kv[j]; vs[snn][sc0 + j] = vv[j]; }
    __syncthreads();
    #pragma unroll
    for (int nn = 0; nn < 32; nn++) {
      float4 kq = *reinterpret_cast<const float4*>(&ks[nn][td * 4]);
      float4 vl = *reinterpret_cast<const float4*>(&vs[nn][tl * 4]);
      float a[4] = {kq.x, kq.y, kq.z, kq.w};
      float c[4] = {vl.x, vl.y, vl.z, vl.w};
      #pragma unroll
      for (int i = 0; i < 4; i++)
        #pragma unroll
        for (int j = 0; j < 4; j++)
          acc[i][j] = fmaf(a[i], c[j], acc[i][j]);
    }
  }
  float* op = part + ((size_t)bh * kNS + s) * 4096;
  #pragma unroll
  for (int i = 0; i < 4; i++)
    #pragma unroll
    for (int j = 0; j < 4; j++)
      op[(td * 4 + i) * 64 + tl * 4 + j] = acc[i][j];
}

// ---------------- combine attention partials * sinv ----------------
__global__ __launch_bounds__(256) void attc_kernel(const float* __restrict__ part,
    const float* __restrict__ sinv, float* __restrict__ att) {
  int bh = blockIdx.x; int b = bh >> 3, h = bh & 7;
  for (int i = threadIdx.x; i < 4096; i += 256) {
    float s = 0.f;
    #pragma unroll
    for (int c = 0; c < kNS; c++) s += part[((size_t)bh * kNS + c) * 4096 + i];
    att[(size_t)bh * 4096 + i] = s * sinv[b * 512 + h * 64 + (i >> 6)];
  }
}

// ---------------- y = (softmax_d expq) @ att  (expq pre-exponentiated) ----------------
__global__ __launch_bounds__(256) void y_einsum(const unsigned short* __restrict__ q,
    const float* __restrict__ att, float* __restrict__ y) {
  int bh = blockIdx.x; int b = bh >> 3, h = bh & 7;
  int t0 = blockIdx.y * 64;
  __shared__ float as_[64][64];
  __shared__ float qs[64][68];
  int tid = threadIdx.x;
  #pragma unroll
  for (int idx = tid; idx < 4096; idx += 256) {
    int l = idx & 63, dd = idx >> 6;
    as_[dd][l] = att[(size_t)bh * 4096 + idx];
  }
  #pragma unroll
  for (int idx = tid; idx < 4096; idx += 256) {
    int dd = idx & 63, tt = idx >> 6;
    qs[tt][dd] = bf2f(q[(size_t)(b * 1024 + t0 + tt) * 512 + h * 64 + dd]);
  }
  __syncthreads();
  int t = tid >> 2, lb = (tid & 3) << 4;
  float rsum = 0.f;
  for (int dd = 0; dd < 64; dd++) rsum += qs[t][dd];
  float rinv = 1.f / rsum;
  float acc[16] = {};
  for (int dd = 0; dd < 64; dd++) {
    float qv = qs[t][dd];
    #pragma unroll
    for (int j = 0; j < 16; j++) acc[j] = fmaf(qv, as_[dd][lb + j], acc[j]);
  }
  float* yp = y + (size_t)(b * 1024 + t0 + t) * 512 + h * 64 + lb;
  #pragma unroll
  for (int j = 0; j < 16; j++) yp[j] = acc[j] * rinv;
}

// ---------------- LN(y)*(1+scale)+shift then SiLU -> bf16 ----------------
__global__ __launch_bounds__(256) void mod_kernel(const float* __restrict__ y,
    const float* __restrict__ ss, const float* __restrict__ g, const float* __restrict__ be,
    unsigned short* __restrict__ h) {
  int row = blockIdx.x; int b = row >> 10;
  const float* p = y + (size_t)row * 512;
  unsigned short* o = h + (size_t)row * 512;
  float v[2]; float s = 0.f, s2 = 0.f;
  #pragma unroll
  for (int i = 0; i < 2; i++) {
    v[i] = p[threadIdx.x + i * 256];
    s += v[i]; s2 += v[i] * v[i];
  }
  __shared__ float red[2][4];
  int lane = threadIdx.x & 63, w = threadIdx.x >> 6;
  s = wave_sum(s); s2 = wave_sum(s2);
  if (!lane) { red[0][w] = s; red[1][w] = s2; }
  __syncthreads();
  s = red[0][0] + red[0][1] + red[0][2] + red[0][3];
  s2 = red[1][0] + red[1][1] + red[1][2] + red[1][3];
  float mean = s / 512.f, var = s2 / 512.f - mean * mean;
  float rstd = rsqrtf(var + 1e-5f);
  #pragma unroll
  for (int i = 0; i < 2; i++) {
    int c = threadIdx.x + i * 256;
    float val = (v[i] - mean) * rstd * g[c] + be[c];
    val = val * (1.f + ss[b * 1024 + c]) + ss[b * 1024 + 512 + c];
    o[c] = f2bf(val / (1.f + __expf(-val)));
  }
}

}  // namespace

extern "C" void kernel_launch(void* const* d_in, const int* in_sizes, int n_in,
                              void* d_out, int out_size, void* d_ws, size_t ws_size,
                              hipStream_t stream) {
  const float* x        = (const float*)d_in[0];
  const float* xf       = (const float*)d_in[1];
  const float* emb      = (const float*)d_in[2];
  const float* src_mask = (const float*)d_in[3];
  const int*   cond     = (const int*)d_in[4];
  const float* re_motion= (const float*)d_in[5];
  const float* re_text  = (const float*)d_in[6];
  const float* re_mask  = (const float*)d_in[7];
  const float* norm_g = (const float*)d_in[8],  * norm_b = (const float*)d_in[9];
  const float* tnorm_g= (const float*)d_in[10], * tnorm_b= (const float*)d_in[11];
  const float* rn1_g  = (const float*)d_in[12], * rn1_b  = (const float*)d_in[13];
  const float* rn2_g  = (const float*)d_in[14], * rn2_b  = (const float*)d_in[15];
  const float* Wq  = (const float*)d_in[16], * bq  = (const float*)d_in[17];
  const float* Wkt = (const float*)d_in[18], * bkt = (const float*)d_in[19];
  const float* Wvt = (const float*)d_in[20], * bvt = (const float*)d_in[21];
  const float* Wkm = (const float*)d_in[22], * bkm = (const float*)d_in[23];
  const float* Wvm = (const float*)d_in[24], * bvm = (const float*)d_in[25];
  const float* Wkr = (const float*)d_in[26], * bkr = (const float*)d_in[27];
  const float* Wvr = (const float*)d_in[28], * bvr = (const float*)d_in[29];
  const float* emb_W = (const float*)d_in[30], * emb_b = (const float*)d_in[31];
  const float* snorm_g = (const float*)d_in[32], * snorm_b = (const float*)d_in[33];
  const float* out_W = (const float*)d_in[34], * out_b = (const float*)d_in[35];
  float* out = (float*)d_out;

  char* base = (char*)d_ws;
  size_t off = 0;
  auto ab = [&](size_t nb) { char* p = base + off; off = (off + nb + 255) & ~(size_t)255; return p; };

  // persistent bf16 weights
  unsigned short* wq_bf  = (unsigned short*)ab(512 * 512 * 2);
  unsigned short* wkt_bf = (unsigned short*)ab(512 * 256 * 2);
  unsigned short* wvt_bf = (unsigned short*)ab(512 * 256 * 2);
  unsigned short* wkm_bf = (unsigned short*)ab(512 * 512 * 2);
  unsigned short* wvm_bf = (unsigned short*)ab(512 * 512 * 2);
  unsigned short* wkr_bf = (unsigned short*)ab(512 * 1024 * 2);
  unsigned short* wvr_bf = (unsigned short*)ab(512 * 512 * 2);
  unsigned short* wout_bf= (unsigned short*)ab(512 * 512 * 2);
  const size_t fixed_off = off;

  auto pad = [](size_t n) { return (n + 255) & ~(size_t)255; };
  auto chunk_bytes = [&](size_t CH) -> size_t {
    size_t s = 0;
    s += pad(CH * 1024 * 512 * 2);        // xn_bf (reused as h_bf)
    s += pad(CH * kNT * 256 * 2);         // xfn_bf
    s += pad(CH * 1024 * 1024 * 2);       // rfk_bf (reused as yb f32)
    s += pad(CH * 1024 * 512 * 2);        // rfv_bf
    s += pad(CH * 1024 * 512 * 2);        // qb_bf
    s += pad((size_t)CH * kN * 512 * 2);  // kc_bf (E)
    s += pad((size_t)CH * kN * 512 * 2);  // vb_bf
    s += pad(CH * 8 * 4096 * 4);          // attb
    s += pad(CH * 8 * (size_t)kNS * 4096 * 4);  // attp partials
    s += pad(CH * 1024 * 4);              // ssb
    s += 2 * pad(CH * kNT * 4) + 4 * pad(CH * 1024 * 4);  // masks
    s += pad(CH * kNS * 512 * 4) + pad(CH * 512 * 4);     // partE, sinv
    return s;
  };
  int CH = 32;
  while (CH > 1 && fixed_off + chunk_bytes(CH) > ws_size) CH >>= 1;

  auto cl = [&](const float* s, unsigned short* d, int n) {
    castw<<<dim3((n / 4 + 255) / 256), 256, 0, stream>>>(s, d, n);
  };
  cl(Wq,  wq_bf,  512 * 512);
  cl(Wkt, wkt_bf, 512 * 256);
  cl(Wvt, wvt_bf, 512 * 256);
  cl(Wkm, wkm_bf, 512 * 512);
  cl(Wvm, wvm_bf, 512 * 512);
  cl(Wkr, wkr_bf, 512 * 1024);
  cl(Wvr, wvr_bf, 512 * 512);
  cl(out_W, wout_bf, 512 * 512);

  for (int b0 = 0; b0 < kB; b0 += CH) {
    off = fixed_off;
    const int MRc = CH * 1024;
    const int MTc = CH * kNT;

    unsigned short* xn_bf  = (unsigned short*)ab((size_t)MRc * 512 * 2);
    unsigned short* xfn_bf = (unsigned short*)ab((size_t)MTc * 256 * 2);
    unsigned short* rfk_bf = (unsigned short*)ab((size_t)MRc * 1024 * 2);
    unsigned short* rfv_bf = (unsigned short*)ab((size_t)MRc * 512 * 2);
    unsigned short* qb_bf  = (unsigned short*)ab((size_t)MRc * 512 * 2);
    unsigned short* kc_bf  = (unsigned short*)ab((size_t)CH * kN * 512 * 2);
    unsigned short* vb_bf  = (unsigned short*)ab((size_t)CH * kN * 512 * 2);
    float* attb = (float*)ab((size_t)CH * 8 * 4096 * 4);
    float* attp = (float*)ab((size_t)CH * 8 * kNS * 4096 * 4);
    float* ssb  = (float*)ab((size_t)CH * 1024 * 4);
    float* kaT = (float*)ab((size_t)CH * kNT * 4);
    float* vmT = (float*)ab((size_t)CH * kNT * 4);
    float* kaR = (float*)ab((size_t)CH * 1024 * 4);
    float* kaM = (float*)ab((size_t)CH * 1024 * 4);
    float* vmR = (float*)ab((size_t)CH * 1024 * 4);
    float* vmM = (float*)ab((size_t)CH * 1024 * 4);
    float* partE = (float*)ab((size_t)CH * kNS * 512 * 4);
    float* sinv = (float*)ab((size_t)CH * 512 * 4);
    float* yb = (float*)rfk_bf;              // rfk dead after Wkr GEMM
    unsigned short* h_bf = xn_bf;            // xn dead after Wvm GEMM

    const float* x_c   = x + (size_t)b0 * kT * 512;
    const float* xf_c  = xf + (size_t)b0 * kNT * 256;
    const float* emb_c = emb + (size_t)b0 * 2048;
    const float* sm_c  = src_mask + (size_t)b0 * kT;
    const int*   ct_c  = cond + b0;
    const float* rm_c  = re_motion + (size_t)b0 * kRL * 512;
    const float* rt_c  = re_text + (size_t)b0 * kR * 512;
    const float* rmask_c = re_mask + (size_t)b0 * kRL;
    float* out_c = out + (size_t)b0 * kT * 512;

    // --- preprocessing ---
    ln_bf16<512><<<dim3(MRc), 256, 0, stream>>>(x_c, norm_g, norm_b, xn_bf);
    ln_bf16<256><<<dim3(MTc), 256, 0, stream>>>(xf_c, tnorm_g, tnorm_b, xfn_bf);
    rfk_norm<<<dim3(MRc), 256, 0, stream>>>(rm_c, rt_c, rn1_g, rn1_b, rn2_g, rn2_b,
                                            rfk_bf, rfv_bf);
    rowmask_kernel<<<dim3(CH * 4), 256, 0, stream>>>(ct_c, sm_c, rmask_c,
                                                     kaT, kaR, kaM, vmT, vmR, vmM, CH);

    // --- projections (bf16 MFMA); k-GEMMs and q-GEMM write exp() ---
    gemm_mfma<2><<<dim3(4, CH * 8), 256, 0, stream>>>(xn_bf, wq_bf, bq, qb_bf,
        MRc, 512, MRc, 0, 0, nullptr, nullptr, nullptr);
    gemm_mfma<2><<<dim3(4, (MTc + 127) / 128), 256, 0, stream>>>(xfn_bf, wkt_bf, bkt, kc_bf,
        MTc, 256, kNT, kN, 0, kaT, nullptr, nullptr);
    gemm_mfma<2><<<dim3(4, CH * 8), 256, 0, stream>>>(rfk_bf, wkr_bf, bkr, kc_bf,
        MRc, 1024, kRL, kN, kNT, kaR, nullptr, nullptr);
    gemm_mfma<2><<<dim3(4, CH * 8), 256, 0, stream>>>(xn_bf, wkm_bf, bkm, kc_bf,
        MRc, 512, kT, kN, kNT + kRL, kaM, nullptr, nullptr);
    gemm_mfma<1><<<dim3(4, (MTc + 127) / 128), 256, 0, stream>>>(xfn_bf, wvt_bf, bvt, vb_bf,
        MTc, 256, kNT, kN, 0, nullptr, vmT, nullptr);
    gemm_mfma<1><<<dim3(4, CH * 8), 256, 0, stream>>>(rfv_bf, wvr_bf, bvr, vb_bf,
        MRc, 512, kRL, kN, kNT, nullptr, vmR, nullptr);
    gemm_mfma<1><<<dim3(4, CH * 8), 256, 0, stream>>>(xn_bf, wvm_bf, bvm, vb_bf,
        MRc, 512, kT, kN, kNT + kRL, nullptr, vmM, nullptr);
    gemm64<SiluA><<<dim3(16, 1), 256, 0, stream>>>(SiluA{emb_c, 2048}, emb_W, emb_b, ssb,
        CH, 2048, 1024, CH, 0, 0);

    // --- attention (E = exp(k) already materialized) ---
    colsumE<<<dim3(CH, kNS), 256, 0, stream>>>(kc_bf, partE);
    colsum_fin<<<dim3(CH * 2), 256, 0, stream>>>(partE, sinv);
    attp_kernel<<<dim3(CH * 8, kNS), 256, 0, stream>>>(kc_bf, vb_bf, attp);
    attc_kernel<<<dim3(CH * 8), 256, 0, stream>>>(attp, sinv, attb);
    y_einsum<<<dim3(CH * 8, 16), 256, 0, stream>>>(qb_bf, attb, yb);

    // --- modulation + output projection + residual ---
    mod_kernel<<<dim3(MRc), 256, 0, stream>>>(yb, ssb, snorm_g, snorm_b, h_bf);
    gemm_mfma<0><<<dim3(4, CH * 8), 256, 0, stream>>>(h_bf, wout_bf, out_b, out_c,
        MRc, 512, MRc, 0, 0, nullptr, nullptr, x_c);
  }
}

// Round 5
// 824.911 us; speedup vs baseline: 3.5813x; 1.2470x over previous
//
#include <hip/hip_runtime.h>
#include <cstddef>
#include <cstdint>

#define DEV __device__ __forceinline__

namespace {

constexpr int kH = 8;
constexpr int kB = 32, kT = 1024, kNT = 77, kR = 4, kLR = 256;
constexpr int kRL = kR * kLR;            // 1024
constexpr int kN = kNT + kRL + kT;       // 2125
constexpr float kNEG = -1000000.0f;
constexpr int kNS = 8;                   // N-slices for attention reduction
constexpr int kSL = 266;                 // ceil(2125/8)

typedef __bf16 bf16x8 __attribute__((ext_vector_type(8)));
typedef float f32x4 __attribute__((ext_vector_type(4)));

DEV unsigned short f2bf(float f) {
  unsigned int u = __float_as_uint(f);
  u += 0x7fffu + ((u >> 16) & 1u);
  return (unsigned short)(u >> 16);
}
DEV float bf2f(unsigned short h) { return __uint_as_float(((unsigned int)h) << 16); }

DEV float wave_sum(float v) {
  #pragma unroll
  for (int s = 32; s; s >>= 1) v += __shfl_xor(v, s);
  return v;
}

// ---------------- LayerNorm -> bf16 ----------------
template<int COLS>
__global__ __launch_bounds__(256) void ln_bf16(const float* __restrict__ in,
    const float* __restrict__ g, const float* __restrict__ be,
    unsigned short* __restrict__ out) {
  constexpr int PT = COLS / 256;
  int row = blockIdx.x;
  const float* p = in + (size_t)row * COLS;
  unsigned short* o = out + (size_t)row * COLS;
  float v[PT]; float s = 0.f, s2 = 0.f;
  #pragma unroll
  for (int i = 0; i < PT; i++) {
    v[i] = p[threadIdx.x + i * 256];
    s += v[i]; s2 += v[i] * v[i];
  }
  __shared__ float red[2][4];
  int lane = threadIdx.x & 63, w = threadIdx.x >> 6;
  s = wave_sum(s); s2 = wave_sum(s2);
  if (!lane) { red[0][w] = s; red[1][w] = s2; }
  __syncthreads();
  s = red[0][0] + red[0][1] + red[0][2] + red[0][3];
  s2 = red[1][0] + red[1][1] + red[1][2] + red[1][3];
  float mean = s / COLS;
  float var = s2 / COLS - mean * mean;
  float rstd = rsqrtf(var + 1e-5f);
  #pragma unroll
  for (int i = 0; i < PT; i++) {
    int c = threadIdx.x + i * 256;
    o[c] = f2bf((v[i] - mean) * rstd * g[c] + be[c]);
  }
}

// ---------------- retrieval LNs fused: stats + normalize -> bf16 ----------------
__global__ __launch_bounds__(256) void rfk_norm(const float* __restrict__ mot,
    const float* __restrict__ txt,
    const float* __restrict__ g1, const float* __restrict__ b1,
    const float* __restrict__ g2, const float* __restrict__ b2,
    unsigned short* __restrict__ rfk, unsigned short* __restrict__ rfv) {
  int m = blockIdx.x;                       // chunk-local retrieval row
  const float* pm = mot + (size_t)m * 512;
  const float* pt = txt + (size_t)(m >> 8) * 512;   // (b*4+r) = m/256
  float v[2], t[2];
  float sv = 0.f, sv2 = 0.f, st = 0.f, st2 = 0.f;
  #pragma unroll
  for (int i = 0; i < 2; i++) {
    v[i] = pm[threadIdx.x + i * 256]; sv += v[i]; sv2 += v[i] * v[i];
    t[i] = pt[threadIdx.x + i * 256]; st += t[i]; st2 += t[i] * t[i];
  }
  __shared__ float red[4][4];
  int lane = threadIdx.x & 63, w = threadIdx.x >> 6;
  sv = wave_sum(sv); sv2 = wave_sum(sv2); st = wave_sum(st); st2 = wave_sum(st2);
  if (!lane) { red[0][w] = sv; red[1][w] = sv2; red[2][w] = st; red[3][w] = st2; }
  __syncthreads();
  float SV = red[0][0] + red[0][1] + red[0][2] + red[0][3];
  float SV2 = red[1][0] + red[1][1] + red[1][2] + red[1][3];
  float ST = red[2][0] + red[2][1] + red[2][2] + red[2][3];
  float ST2 = red[3][0] + red[3][1] + red[3][2] + red[3][3];
  float SA = SV + ST, SA2 = SV2 + ST2;
  float ma = SA / 1024.f, va = SA2 / 1024.f - ma * ma;
  float ra_ = rsqrtf(va + 1e-5f);
  float mv = SV / 512.f, vv = SV2 / 512.f - mv * mv;
  float rv_ = rsqrtf(vv + 1e-5f);
  #pragma unroll
  for (int i = 0; i < 2; i++) {
    int c = threadIdx.x + i * 256;
    rfk[(size_t)m * 1024 + c]       = f2bf((v[i] - ma) * ra_ * g1[c] + b1[c]);
    rfk[(size_t)m * 1024 + 512 + c] = f2bf((t[i] - ma) * ra_ * g1[512 + c] + b1[512 + c]);
    rfv[(size_t)m * 512 + c]        = f2bf((v[i] - mv) * rv_ * g2[c] + b2[c]);
  }
}

// ---------------- per-row mask arrays (full batch) ----------------
__global__ __launch_bounds__(256) void rowmask_kernel(const int* __restrict__ ct,
    const float* __restrict__ src_mask, const float* __restrict__ re_mask,
    float* __restrict__ kaT, float* __restrict__ kaR, float* __restrict__ kaM,
    float* __restrict__ vmT, float* __restrict__ vmR, float* __restrict__ vmM,
    int nB) {
  int i = blockIdx.x * 256 + threadIdx.x;
  if (i < nB * kRL) {
    int b = i >> 10;
    int c = ct[b];
    float retr = (c / 10 > 0) ? 1.f : 0.f;
    float rm = re_mask[i];
    kaR[i] = (1.f - retr) * kNEG + (1.f - rm) * kNEG;
    vmR[i] = retr * rm;
    float sm = src_mask[i];
    kaM[i] = (1.f - sm) * kNEG;
    vmM[i] = sm;
  }
  if (i < nB * kNT) {
    int b = i / kNT;
    int c = ct[b];
    float text = (c % 10 > 0) ? 1.f : 0.f;
    kaT[i] = (1.f - text) * kNEG;
    vmT[i] = text;
  }
}

// ---------------- weight cast f32 -> bf16 ----------------
__global__ __launch_bounds__(256) void castw(const float* __restrict__ s,
    unsigned short* __restrict__ d, int n) {
  int i = (blockIdx.x * 256 + threadIdx.x) * 4;
  if (i < n) {
    float4 v = *reinterpret_cast<const float4*>(s + i);
    ushort4 o;
    o.x = f2bf(v.x); o.y = f2bf(v.y); o.z = f2bf(v.z); o.w = f2bf(v.w);
    *reinterpret_cast<ushort4*>(d + i) = o;
  }
}

// ---------------- silu(emb) precompute (f32) ----------------
__global__ __launch_bounds__(256) void silu_emb(const float* __restrict__ emb,
    float* __restrict__ semb) {
  int i = (blockIdx.x * 256 + threadIdx.x) * 4;
  float4 v = *reinterpret_cast<const float4*>(emb + i);
  float4 o;
  o.x = v.x / (1.f + __expf(-v.x));
  o.y = v.y / (1.f + __expf(-v.y));
  o.z = v.z / (1.f + __expf(-v.z));
  o.w = v.w / (1.f + __expf(-v.w));
  *reinterpret_cast<float4*>(semb + i) = o;
}

// ---------------- emb GEMV: ss[32][1024] = semb[32][2048] @ W[1024][2048]^T + b ----------------
__global__ __launch_bounds__(256) void emb_gemv(const float* __restrict__ semb,
    const float* __restrict__ W, const float* __restrict__ bias,
    float* __restrict__ ss) {
  int n = blockIdx.x * 4 + (threadIdx.x >> 6);   // 256 blocks -> 1024 cols
  int lane = threadIdx.x & 63;
  float acc[32];
  #pragma unroll
  for (int m = 0; m < 32; m++) acc[m] = 0.f;
  for (int i = 0; i < 8; i++) {
    int k = (i * 64 + lane) * 4;
    float4 wv = *reinterpret_cast<const float4*>(&W[(size_t)n * 2048 + k]);
    #pragma unroll
    for (int m = 0; m < 32; m++) {
      float4 sv = *reinterpret_cast<const float4*>(&semb[(size_t)m * 2048 + k]);
      acc[m] = fmaf(sv.x, wv.x, fmaf(sv.y, wv.y, fmaf(sv.z, wv.z, fmaf(sv.w, wv.w, acc[m]))));
    }
  }
  #pragma unroll
  for (int m = 0; m < 32; m++) {
    float s = wave_sum(acc[m]);
    if (lane == 0) ss[(size_t)m * 1024 + n] = s + bias[n];
  }
}

// ---------------- MFMA GEMM: C = A @ W^T (+bias, masks, residual) ----------------
// OUTMODE: 0 = f32 (+optional addX residual), 1 = bf16, 2 = bf16(exp(.))
template<int OUTMODE>
__global__ __launch_bounds__(256) void gemm_mfma(
    const unsigned short* __restrict__ A, const unsigned short* __restrict__ W,
    const float* __restrict__ bias, void* __restrict__ Cout,
    int M, int K, int m_per_b, int n_total, int out_off,
    const float* __restrict__ rowAdd, const float* __restrict__ rowMul,
    const float* __restrict__ addX) {
  __shared__ unsigned short As[128 * 32];
  __shared__ unsigned short Bs[128 * 32];
  const int tid = threadIdx.x;
  const int lane = tid & 63;
  const int wv = tid >> 6;
  const int wr = (wv >> 1) * 64;
  const int wc = (wv & 1) * 64;
  const int m0 = blockIdx.y * 128;
  const int n0 = blockIdx.x * 128;

  const unsigned short* srcA[2]; const unsigned short* srcB[2];
  unsigned short* dstA[2]; unsigned short* dstB[2];
  #pragma unroll
  for (int i = 0; i < 2; i++) {
    int lin = i * 256 + tid;
    int r = lin >> 2, cl = lin & 3;
    int cs = cl ^ ((r >> 1) & 3);
    int ra = m0 + r; if (ra > M - 1) ra = M - 1;
    srcA[i] = A + (size_t)ra * K + cs * 8;
    dstA[i] = &As[lin * 8];
    srcB[i] = W + (size_t)(n0 + r) * K + cs * 8;
    dstB[i] = &Bs[lin * 8];
  }
  int offA[4], offB[4];
  #pragma unroll
  for (int i = 0; i < 4; i++) {
    int r = wr + i * 16 + (lane & 15);
    int c = (lane >> 4) ^ ((r >> 1) & 3);
    offA[i] = r * 32 + c * 8;
    int rb = wc + i * 16 + (lane & 15);
    int cb = (lane >> 4) ^ ((rb >> 1) & 3);
    offB[i] = rb * 32 + cb * 8;
  }

  f32x4 acc[4][4] = {};

  for (int k0 = 0; k0 < K; k0 += 32) {
    #pragma unroll
    for (int i = 0; i < 2; i++) {
      __builtin_amdgcn_global_load_lds(
          (const __attribute__((address_space(1))) void*)(srcA[i] + k0),
          (__attribute__((address_space(3))) void*)dstA[i], 16, 0, 0);
      __builtin_amdgcn_global_load_lds(
          (const __attribute__((address_space(1))) void*)(srcB[i] + k0),
          (__attribute__((address_space(3))) void*)dstB[i], 16, 0, 0);
    }
    asm volatile("s_waitcnt vmcnt(0)" ::: "memory");
    __syncthreads();
    bf16x8 af[4], bf[4];
    #pragma unroll
    for (int i = 0; i < 4; i++) {
      af[i] = *reinterpret_cast<const bf16x8*>(&As[offA[i]]);
      bf[i] = *reinterpret_cast<const bf16x8*>(&Bs[offB[i]]);
    }
    #pragma unroll
    for (int i = 0; i < 4; i++)
      #pragma unroll
      for (int j = 0; j < 4; j++)
        acc[i][j] = __builtin_amdgcn_mfma_f32_16x16x32_bf16(af[i], bf[j], acc[i][j], 0, 0, 0);
    __syncthreads();
  }

  const int colb = n0 + wc + (lane & 15);
  const int rowb = m0 + wr + ((lane >> 4) << 2);
  #pragma unroll
  for (int i = 0; i < 4; i++) {
    #pragma unroll
    for (int r = 0; r < 4; r++) {
      int row = rowb + i * 16 + r;
      if (row >= M) continue;
      size_t orow = (size_t)(row / m_per_b) * n_total + out_off + (row % m_per_b);
      float ra = rowAdd ? rowAdd[row] : 0.f;
      float rm = rowMul ? rowMul[row] : 1.f;
      #pragma unroll
      for (int j = 0; j < 4; j++) {
        int col = colb + j * 16;
        float v = (acc[i][j][r] + bias[col] + ra) * rm;
        if (OUTMODE == 2) {
          ((unsigned short*)Cout)[orow * 512 + col] = f2bf(__expf(v));
        } else if (OUTMODE == 1) {
          ((unsigned short*)Cout)[orow * 512 + col] = f2bf(v);
        } else {
          if (addX) v += addX[(size_t)row * 512 + col];
          ((float*)Cout)[orow * 512 + col] = v;
        }
      }
    }
  }
}

// ---------------- coalesced column-sum of E over N (partial per slice) ----------------
__global__ __launch_bounds__(256) void colsumE(const unsigned short* __restrict__ E,
    float* __restrict__ part) {
  int b = blockIdx.x, s = blockIdx.y;
  int nbeg = s * kSL, nend = min(kN, nbeg + kSL);
  int grp = threadIdx.x >> 6, lane = threadIdx.x & 63;
  const unsigned short* base = E + (size_t)b * kN * 512 + lane * 8;
  float acc[8] = {};
  for (int n = nbeg + grp; n < nend; n += 4) {
    const unsigned short* p = base + (size_t)n * 512;
    ushort4 u0 = *reinterpret_cast<const ushort4*>(p);
    ushort4 u1 = *reinterpret_cast<const ushort4*>(p + 4);
    acc[0] += bf2f(u0.x); acc[1] += bf2f(u0.y); acc[2] += bf2f(u0.z); acc[3] += bf2f(u0.w);
    acc[4] += bf2f(u1.x); acc[5] += bf2f(u1.y); acc[6] += bf2f(u1.z); acc[7] += bf2f(u1.w);
  }
  __shared__ float sacc[4][512];
  #pragma unroll
  for (int j = 0; j < 8; j++) sacc[grp][lane * 8 + j] = acc[j];
  __syncthreads();
  for (int c = threadIdx.x; c < 512; c += 256) {
    part[((size_t)b * kNS + s) * 512 + c] =
        sacc[0][c] + sacc[1][c] + sacc[2][c] + sacc[3][c];
  }
}
__global__ __launch_bounds__(256) void colsum_fin(const float* __restrict__ part,
    float* __restrict__ sinv) {
  int i = blockIdx.x * 256 + threadIdx.x;   // CH*512 total
  int b = i >> 9, d = i & 511;
  float s = 0.f;
  #pragma unroll
  for (int c = 0; c < kNS; c++) s += part[((size_t)b * kNS + c) * 512 + d];
  sinv[i] = 1.f / s;
}

// ---------------- attention partials: P[bh][s] = E_slice^T V_slice (64x64) ----------------
__global__ __launch_bounds__(256) void attp_kernel(const unsigned short* __restrict__ E,
    const unsigned short* __restrict__ V, float* __restrict__ part) {
  int bh = blockIdx.x; int b = bh >> 3, h = bh & 7;
  int s = blockIdx.y;
  int nbeg = s * kSL, nend = min(kN, nbeg + kSL);
  const unsigned short* kp = E + (size_t)b * kN * 512 + h * 64;
  const unsigned short* vp = V + (size_t)b * kN * 512 + h * 64;
  __shared__ float ks[32][68];
  __shared__ float vs[32][68];
  int tid = threadIdx.x;
  int td = tid >> 4, tl = tid & 15;
  int snn = tid >> 3, sc0 = (tid & 7) * 8;
  float acc[4][4] = {};
  for (int n0 = nbeg; n0 < nend; n0 += 32) {
    __syncthreads();
    int n = n0 + snn;
    float kv[8] = {}, vv[8] = {};
    if (n < nend) {
      const unsigned short* pk = kp + (size_t)n * 512 + sc0;
      const unsigned short* pv = vp + (size_t)n * 512 + sc0;
      ushort4 a0 = *reinterpret_cast<const ushort4*>(pk);
      ushort4 a1 = *reinterpret_cast<const ushort4*>(pk + 4);
      ushort4 b0 = *reinterpret_cast<const ushort4*>(pv);
      ushort4 b1 = *reinterpret_cast<const ushort4*>(pv + 4);
      kv[0] = bf2f(a0.x); kv[1] = bf2f(a0.y); kv[2] = bf2f(a0.z); kv[3] = bf2f(a0.w);
      kv[4] = bf2f(a1.x); kv[5] = bf2f(a1.y); kv[6] = bf2f(a1.z); kv[7] = bf2f(a1.w);
      vv[0] = bf2f(b0.x); vv[1] = bf2f(b0.y); vv[2] = bf2f(b0.z); vv[3] = bf2f(b0.w);
      vv[4] = bf2f(b1.x); vv[5] = bf2f(b1.y); vv[6] = bf2f(b1.z); vv[7] = bf2f(b1.w);
    }
    #pragma unroll
    for (int j = 0; j < 8; j++) { ks[snn][sc0 + j] = kv[j]; vs[snn][sc0 + j] = vv[j]; }
    __syncthreads();
    #pragma unroll
    for (int nn = 0; nn < 32; nn++) {
      float4 kq = *reinterpret_cast<const float4*>(&ks[nn][td * 4]);
      float4 vl = *reinterpret_cast<const float4*>(&vs[nn][tl * 4]);
      float a[4] = {kq.x, kq.y, kq.z, kq.w};
      float c[4] = {vl.x, vl.y, vl.z, vl.w};
      #pragma unroll
      for (int i = 0; i < 4; i++)
        #pragma unroll
        for (int j = 0; j < 4; j++)
          acc[i][j] = fmaf(a[i], c[j], acc[i][j]);
    }
  }
  float* op = part + ((size_t)bh * kNS + s) * 4096;
  #pragma unroll
  for (int i = 0; i < 4; i++)
    #pragma unroll
    for (int j = 0; j < 4; j++)
      op[(td * 4 + i) * 64 + tl * 4 + j] = acc[i][j];
}

// ---------------- combine attention partials * sinv ----------------
__global__ __launch_bounds__(256) void attc_kernel(const float* __restrict__ part,
    const float* __restrict__ sinv, float* __restrict__ att) {
  int bh = blockIdx.x; int b = bh >> 3, h = bh & 7;
  for (int i = threadIdx.x; i < 4096; i += 256) {
    float s = 0.f;
    #pragma unroll
    for (int c = 0; c < kNS; c++) s += part[((size_t)bh * kNS + c) * 4096 + i];
    att[(size_t)bh * 4096 + i] = s * sinv[b * 512 + h * 64 + (i >> 6)];
  }
}

// ---------------- y = (softmax_d expq) @ att  (expq pre-exponentiated) ----------------
__global__ __launch_bounds__(256) void y_einsum(const unsigned short* __restrict__ q,
    const float* __restrict__ att, float* __restrict__ y) {
  int bh = blockIdx.x; int b = bh >> 3, h = bh & 7;
  int t0 = blockIdx.y * 64;
  __shared__ float as_[64][64];
  __shared__ float qs[64][68];
  int tid = threadIdx.x;
  #pragma unroll
  for (int idx = tid; idx < 4096; idx += 256) {
    int l = idx & 63, dd = idx >> 6;
    as_[dd][l] = att[(size_t)bh * 4096 + idx];
  }
  #pragma unroll
  for (int idx = tid; idx < 4096; idx += 256) {
    int dd = idx & 63, tt = idx >> 6;
    qs[tt][dd] = bf2f(q[(size_t)(b * 1024 + t0 + tt) * 512 + h * 64 + dd]);
  }
  __syncthreads();
  int t = tid >> 2, lb = (tid & 3) << 4;
  float rsum = 0.f;
  for (int dd = 0; dd < 64; dd++) rsum += qs[t][dd];
  float rinv = 1.f / rsum;
  float acc[16] = {};
  for (int dd = 0; dd < 64; dd++) {
    float qv = qs[t][dd];
    #pragma unroll
    for (int j = 0; j < 16; j++) acc[j] = fmaf(qv, as_[dd][lb + j], acc[j]);
  }
  float* yp = y + (size_t)(b * 1024 + t0 + t) * 512 + h * 64 + lb;
  #pragma unroll
  for (int j = 0; j < 16; j++) yp[j] = acc[j] * rinv;
}

// ---------------- LN(y)*(1+scale)+shift then SiLU -> bf16 ----------------
__global__ __launch_bounds__(256) void mod_kernel(const float* __restrict__ y,
    const float* __restrict__ ss, const float* __restrict__ g, const float* __restrict__ be,
    unsigned short* __restrict__ h) {
  int row = blockIdx.x; int b = row >> 10;
  const float* p = y + (size_t)row * 512;
  unsigned short* o = h + (size_t)row * 512;
  float v[2]; float s = 0.f, s2 = 0.f;
  #pragma unroll
  for (int i = 0; i < 2; i++) {
    v[i] = p[threadIdx.x + i * 256];
    s += v[i]; s2 += v[i] * v[i];
  }
  __shared__ float red[2][4];
  int lane = threadIdx.x & 63, w = threadIdx.x >> 6;
  s = wave_sum(s); s2 = wave_sum(s2);
  if (!lane) { red[0][w] = s; red[1][w] = s2; }
  __syncthreads();
  s = red[0][0] + red[0][1] + red[0][2] + red[0][3];
  s2 = red[1][0] + red[1][1] + red[1][2] + red[1][3];
  float mean = s / 512.f, var = s2 / 512.f - mean * mean;
  float rstd = rsqrtf(var + 1e-5f);
  #pragma unroll
  for (int i = 0; i < 2; i++) {
    int c = threadIdx.x + i * 256;
    float val = (v[i] - mean) * rstd * g[c] + be[c];
    val = val * (1.f + ss[b * 1024 + c]) + ss[b * 1024 + 512 + c];
    o[c] = f2bf(val / (1.f + __expf(-val)));
  }
}

}  // namespace

extern "C" void kernel_launch(void* const* d_in, const int* in_sizes, int n_in,
                              void* d_out, int out_size, void* d_ws, size_t ws_size,
                              hipStream_t stream) {
  const float* x        = (const float*)d_in[0];
  const float* xf       = (const float*)d_in[1];
  const float* emb      = (const float*)d_in[2];
  const float* src_mask = (const float*)d_in[3];
  const int*   cond     = (const int*)d_in[4];
  const float* re_motion= (const float*)d_in[5];
  const float* re_text  = (const float*)d_in[6];
  const float* re_mask  = (const float*)d_in[7];
  const float* norm_g = (const float*)d_in[8],  * norm_b = (const float*)d_in[9];
  const float* tnorm_g= (const float*)d_in[10], * tnorm_b= (const float*)d_in[11];
  const float* rn1_g  = (const float*)d_in[12], * rn1_b  = (const float*)d_in[13];
  const float* rn2_g  = (const float*)d_in[14], * rn2_b  = (const float*)d_in[15];
  const float* Wq  = (const float*)d_in[16], * bq  = (const float*)d_in[17];
  const float* Wkt = (const float*)d_in[18], * bkt = (const float*)d_in[19];
  const float* Wvt = (const float*)d_in[20], * bvt = (const float*)d_in[21];
  const float* Wkm = (const float*)d_in[22], * bkm = (const float*)d_in[23];
  const float* Wvm = (const float*)d_in[24], * bvm = (const float*)d_in[25];
  const float* Wkr = (const float*)d_in[26], * bkr = (const float*)d_in[27];
  const float* Wvr = (const float*)d_in[28], * bvr = (const float*)d_in[29];
  const float* emb_W = (const float*)d_in[30], * emb_b = (const float*)d_in[31];
  const float* snorm_g = (const float*)d_in[32], * snorm_b = (const float*)d_in[33];
  const float* out_W = (const float*)d_in[34], * out_b = (const float*)d_in[35];
  float* out = (float*)d_out;

  char* base = (char*)d_ws;
  size_t off = 0;
  auto ab = [&](size_t nb) { char* p = base + off; off = (off + nb + 255) & ~(size_t)255; return p; };

  // ---- persistent region: bf16 weights + full-batch small buffers ----
  unsigned short* wq_bf  = (unsigned short*)ab(512 * 512 * 2);
  unsigned short* wkt_bf = (unsigned short*)ab(512 * 256 * 2);
  unsigned short* wvt_bf = (unsigned short*)ab(512 * 256 * 2);
  unsigned short* wkm_bf = (unsigned short*)ab(512 * 512 * 2);
  unsigned short* wvm_bf = (unsigned short*)ab(512 * 512 * 2);
  unsigned short* wkr_bf = (unsigned short*)ab(512 * 1024 * 2);
  unsigned short* wvr_bf = (unsigned short*)ab(512 * 512 * 2);
  unsigned short* wout_bf= (unsigned short*)ab(512 * 512 * 2);
  float* semb_f   = (float*)ab((size_t)kB * 2048 * 4);
  float* ssb_full = (float*)ab((size_t)kB * 1024 * 4);
  float* kaT_full = (float*)ab((size_t)kB * kNT * 4);
  float* vmT_full = (float*)ab((size_t)kB * kNT * 4);
  float* kaR_full = (float*)ab((size_t)kB * kRL * 4);
  float* kaM_full = (float*)ab((size_t)kB * kT * 4);
  float* vmR_full = (float*)ab((size_t)kB * kRL * 4);
  float* vmM_full = (float*)ab((size_t)kB * kT * 4);
  const size_t fixed_off = off;

  auto pad = [](size_t n) { return (n + 255) & ~(size_t)255; };
  auto chunk_bytes = [&](size_t CH) -> size_t {
    size_t s = 0;
    s += pad(CH * 1024 * 512 * 2);        // xn_bf (reused as h_bf)
    s += pad(CH * kNT * 256 * 2);         // xfn_bf
    s += pad(CH * 1024 * 1024 * 2);       // rfk_bf (reused as yb f32)
    s += pad(CH * 1024 * 512 * 2);        // rfv_bf
    s += pad(CH * 1024 * 512 * 2);        // qb_bf
    s += pad((size_t)CH * kN * 512 * 2);  // kc_bf (E)
    s += pad((size_t)CH * kN * 512 * 2);  // vb_bf
    s += pad(CH * 8 * 4096 * 4);          // attb
    s += pad(CH * 8 * (size_t)kNS * 4096 * 4);  // attp partials
    s += pad(CH * kNS * 512 * 4) + pad(CH * 512 * 4);     // partE, sinv
    return s;
  };
  int CH = 32;
  while (CH > 1 && fixed_off + chunk_bytes(CH) > ws_size) CH >>= 1;

  // ---- once-per-call work (full batch) ----
  auto cl = [&](const float* s, unsigned short* d, int n) {
    castw<<<dim3((n / 4 + 255) / 256), 256, 0, stream>>>(s, d, n);
  };
  cl(Wq,  wq_bf,  512 * 512);
  cl(Wkt, wkt_bf, 512 * 256);
  cl(Wvt, wvt_bf, 512 * 256);
  cl(Wkm, wkm_bf, 512 * 512);
  cl(Wvm, wvm_bf, 512 * 512);
  cl(Wkr, wkr_bf, 512 * 1024);
  cl(Wvr, wvr_bf, 512 * 512);
  cl(out_W, wout_bf, 512 * 512);

  rowmask_kernel<<<dim3(kB * 4), 256, 0, stream>>>(cond, src_mask, re_mask,
      kaT_full, kaR_full, kaM_full, vmT_full, vmR_full, vmM_full, kB);
  silu_emb<<<dim3(kB * 2048 / 1024), 256, 0, stream>>>(emb, semb_f);
  emb_gemv<<<dim3(256), 256, 0, stream>>>(semb_f, emb_W, emb_b, ssb_full);

  for (int b0 = 0; b0 < kB; b0 += CH) {
    off = fixed_off;
    const int MRc = CH * 1024;
    const int MTc = CH * kNT;

    unsigned short* xn_bf  = (unsigned short*)ab((size_t)MRc * 512 * 2);
    unsigned short* xfn_bf = (unsigned short*)ab((size_t)MTc * 256 * 2);
    unsigned short* rfk_bf = (unsigned short*)ab((size_t)MRc * 1024 * 2);
    unsigned short* rfv_bf = (unsigned short*)ab((size_t)MRc * 512 * 2);
    unsigned short* qb_bf  = (unsigned short*)ab((size_t)MRc * 512 * 2);
    unsigned short* kc_bf  = (unsigned short*)ab((size_t)CH * kN * 512 * 2);
    unsigned short* vb_bf  = (unsigned short*)ab((size_t)CH * kN * 512 * 2);
    float* attb = (float*)ab((size_t)CH * 8 * 4096 * 4);
    float* attp = (float*)ab((size_t)CH * 8 * kNS * 4096 * 4);
    float* partE = (float*)ab((size_t)CH * kNS * 512 * 4);
    float* sinv = (float*)ab((size_t)CH * 512 * 4);
    float* yb = (float*)rfk_bf;              // rfk dead after Wkr GEMM
    unsigned short* h_bf = xn_bf;            // xn dead after Wvm GEMM

    const float* x_c   = x + (size_t)b0 * kT * 512;
    const float* xf_c  = xf + (size_t)b0 * kNT * 256;
    const float* sm_c  = src_mask + (size_t)b0 * kT;
    const float* rm_c  = re_motion + (size_t)b0 * kRL * 512;
    const float* rt_c  = re_text + (size_t)b0 * kR * 512;
    float* out_c = out + (size_t)b0 * kT * 512;
    (void)sm_c;

    // --- preprocessing ---
    ln_bf16<512><<<dim3(MRc), 256, 0, stream>>>(x_c, norm_g, norm_b, xn_bf);
    ln_bf16<256><<<dim3(MTc), 256, 0, stream>>>(xf_c, tnorm_g, tnorm_b, xfn_bf);
    rfk_norm<<<dim3(MRc), 256, 0, stream>>>(rm_c, rt_c, rn1_g, rn1_b, rn2_g, rn2_b,
                                            rfk_bf, rfv_bf);

    // --- projections (bf16 MFMA); k-GEMMs and q-GEMM write exp() ---
    gemm_mfma<2><<<dim3(4, CH * 8), 256, 0, stream>>>(xn_bf, wq_bf, bq, qb_bf,
        MRc, 512, MRc, 0, 0, nullptr, nullptr, nullptr);
    gemm_mfma<2><<<dim3(4, (MTc + 127) / 128), 256, 0, stream>>>(xfn_bf, wkt_bf, bkt, kc_bf,
        MTc, 256, kNT, kN, 0, kaT_full + (size_t)b0 * kNT, nullptr, nullptr);
    gemm_mfma<2><<<dim3(4, CH * 8), 256, 0, stream>>>(rfk_bf, wkr_bf, bkr, kc_bf,
        MRc, 1024, kRL, kN, kNT, kaR_full + (size_t)b0 * kRL, nullptr, nullptr);
    gemm_mfma<2><<<dim3(4, CH * 8), 256, 0, stream>>>(xn_bf, wkm_bf, bkm, kc_bf,
        MRc, 512, kT, kN, kNT + kRL, kaM_full + (size_t)b0 * kT, nullptr, nullptr);
    gemm_mfma<1><<<dim3(4, (MTc + 127) / 128), 256, 0, stream>>>(xfn_bf, wvt_bf, bvt, vb_bf,
        MTc, 256, kNT, kN, 0, nullptr, vmT_full + (size_t)b0 * kNT, nullptr);
    gemm_mfma<1><<<dim3(4, CH * 8), 256, 0, stream>>>(rfv_bf, wvr_bf, bvr, vb_bf,
        MRc, 512, kRL, kN, kNT, nullptr, vmR_full + (size_t)b0 * kRL, nullptr);
    gemm_mfma<1><<<dim3(4, CH * 8), 256, 0, stream>>>(xn_bf, wvm_bf, bvm, vb_bf,
        MRc, 512, kT, kN, kNT + kRL, nullptr, vmM_full + (size_t)b0 * kT, nullptr);

    // --- attention (E = exp(k) already materialized) ---
    colsumE<<<dim3(CH, kNS), 256, 0, stream>>>(kc_bf, partE);
    colsum_fin<<<dim3(CH * 2), 256, 0, stream>>>(partE, sinv);
    attp_kernel<<<dim3(CH * 8, kNS), 256, 0, stream>>>(kc_bf, vb_bf, attp);
    attc_kernel<<<dim3(CH * 8), 256, 0, stream>>>(attp, sinv, attb);
    y_einsum<<<dim3(CH * 8, 16), 256, 0, stream>>>(qb_bf, attb, yb);

    // --- modulation + output projection + residual ---
    mod_kernel<<<dim3(MRc), 256, 0, stream>>>(yb, ssb_full + (size_t)b0 * 1024,
                                              snorm_g, snorm_b, h_bf);
    gemm_mfma<0><<<dim3(4, CH * 8), 256, 0, stream>>>(h_bf, wout_bf, out_b, out_c,
        MRc, 512, MRc, 0, 0, nullptr, nullptr, x_c);
  }
}

// Round 6
// 775.072 us; speedup vs baseline: 3.8116x; 1.0643x over previous
//
#include <hip/hip_runtime.h>
#include <cstddef>
#include <cstdint>

#define DEV __device__ __forceinline__

namespace {

constexpr int kH = 8;
constexpr int kB = 32, kT = 1024, kNT = 77, kR = 4, kLR = 256;
constexpr int kRL = kR * kLR;            // 1024
constexpr int kN = kNT + kRL + kT;       // 2125
constexpr float kNEG = -1000000.0f;
constexpr int kNS = 8;                   // N-slices for attention reduction
constexpr int kSL = 266;                 // ceil(2125/8)
constexpr int kLDSW = 136;               // padded epilogue stage width

typedef __bf16 bf16x8 __attribute__((ext_vector_type(8)));
typedef float f32x4 __attribute__((ext_vector_type(4)));

DEV unsigned short f2bf(float f) {
  unsigned int u = __float_as_uint(f);
  u += 0x7fffu + ((u >> 16) & 1u);
  return (unsigned short)(u >> 16);
}
DEV float bf2f(unsigned short h) { return __uint_as_float(((unsigned int)h) << 16); }

DEV float wave_sum(float v) {
  #pragma unroll
  for (int s = 32; s; s >>= 1) v += __shfl_xor(v, s);
  return v;
}

// ---------------- LayerNorm -> bf16 ----------------
template<int COLS>
__global__ __launch_bounds__(256) void ln_bf16(const float* __restrict__ in,
    const float* __restrict__ g, const float* __restrict__ be,
    unsigned short* __restrict__ out) {
  constexpr int PT = COLS / 256;
  int row = blockIdx.x;
  const float* p = in + (size_t)row * COLS;
  unsigned short* o = out + (size_t)row * COLS;
  float v[PT]; float s = 0.f, s2 = 0.f;
  #pragma unroll
  for (int i = 0; i < PT; i++) {
    v[i] = p[threadIdx.x + i * 256];
    s += v[i]; s2 += v[i] * v[i];
  }
  __shared__ float red[2][4];
  int lane = threadIdx.x & 63, w = threadIdx.x >> 6;
  s = wave_sum(s); s2 = wave_sum(s2);
  if (!lane) { red[0][w] = s; red[1][w] = s2; }
  __syncthreads();
  s = red[0][0] + red[0][1] + red[0][2] + red[0][3];
  s2 = red[1][0] + red[1][1] + red[1][2] + red[1][3];
  float mean = s / COLS;
  float var = s2 / COLS - mean * mean;
  float rstd = rsqrtf(var + 1e-5f);
  #pragma unroll
  for (int i = 0; i < PT; i++) {
    int c = threadIdx.x + i * 256;
    o[c] = f2bf((v[i] - mean) * rstd * g[c] + be[c]);
  }
}

// ---------------- retrieval LNs fused: stats + normalize -> bf16 ----------------
__global__ __launch_bounds__(256) void rfk_norm(const float* __restrict__ mot,
    const float* __restrict__ txt,
    const float* __restrict__ g1, const float* __restrict__ b1,
    const float* __restrict__ g2, const float* __restrict__ b2,
    unsigned short* __restrict__ rfk, unsigned short* __restrict__ rfv) {
  int m = blockIdx.x;                       // chunk-local retrieval row
  const float* pm = mot + (size_t)m * 512;
  const float* pt = txt + (size_t)(m >> 8) * 512;   // (b*4+r) = m/256
  float v[2], t[2];
  float sv = 0.f, sv2 = 0.f, st = 0.f, st2 = 0.f;
  #pragma unroll
  for (int i = 0; i < 2; i++) {
    v[i] = pm[threadIdx.x + i * 256]; sv += v[i]; sv2 += v[i] * v[i];
    t[i] = pt[threadIdx.x + i * 256]; st += t[i]; st2 += t[i] * t[i];
  }
  __shared__ float red[4][4];
  int lane = threadIdx.x & 63, w = threadIdx.x >> 6;
  sv = wave_sum(sv); sv2 = wave_sum(sv2); st = wave_sum(st); st2 = wave_sum(st2);
  if (!lane) { red[0][w] = sv; red[1][w] = sv2; red[2][w] = st; red[3][w] = st2; }
  __syncthreads();
  float SV = red[0][0] + red[0][1] + red[0][2] + red[0][3];
  float SV2 = red[1][0] + red[1][1] + red[1][2] + red[1][3];
  float ST = red[2][0] + red[2][1] + red[2][2] + red[2][3];
  float ST2 = red[3][0] + red[3][1] + red[3][2] + red[3][3];
  float SA = SV + ST, SA2 = SV2 + ST2;
  float ma = SA / 1024.f, va = SA2 / 1024.f - ma * ma;
  float ra_ = rsqrtf(va + 1e-5f);
  float mv = SV / 512.f, vv = SV2 / 512.f - mv * mv;
  float rv_ = rsqrtf(vv + 1e-5f);
  #pragma unroll
  for (int i = 0; i < 2; i++) {
    int c = threadIdx.x + i * 256;
    rfk[(size_t)m * 1024 + c]       = f2bf((v[i] - ma) * ra_ * g1[c] + b1[c]);
    rfk[(size_t)m * 1024 + 512 + c] = f2bf((t[i] - ma) * ra_ * g1[512 + c] + b1[512 + c]);
    rfv[(size_t)m * 512 + c]        = f2bf((v[i] - mv) * rv_ * g2[c] + b2[c]);
  }
}

// ---------------- per-row mask arrays (full batch) ----------------
__global__ __launch_bounds__(256) void rowmask_kernel(const int* __restrict__ ct,
    const float* __restrict__ src_mask, const float* __restrict__ re_mask,
    float* __restrict__ kaT, float* __restrict__ kaR, float* __restrict__ kaM,
    float* __restrict__ vmT, float* __restrict__ vmR, float* __restrict__ vmM,
    int nB) {
  int i = blockIdx.x * 256 + threadIdx.x;
  if (i < nB * kRL) {
    int b = i >> 10;
    int c = ct[b];
    float retr = (c / 10 > 0) ? 1.f : 0.f;
    float rm = re_mask[i];
    kaR[i] = (1.f - retr) * kNEG + (1.f - rm) * kNEG;
    vmR[i] = retr * rm;
    float sm = src_mask[i];
    kaM[i] = (1.f - sm) * kNEG;
    vmM[i] = sm;
  }
  if (i < nB * kNT) {
    int b = i / kNT;
    int c = ct[b];
    float text = (c % 10 > 0) ? 1.f : 0.f;
    kaT[i] = (1.f - text) * kNEG;
    vmT[i] = text;
  }
}

// ---------------- weight cast f32 -> bf16 ----------------
__global__ __launch_bounds__(256) void castw(const float* __restrict__ s,
    unsigned short* __restrict__ d, int n) {
  int i = (blockIdx.x * 256 + threadIdx.x) * 4;
  if (i < n) {
    float4 v = *reinterpret_cast<const float4*>(s + i);
    ushort4 o;
    o.x = f2bf(v.x); o.y = f2bf(v.y); o.z = f2bf(v.z); o.w = f2bf(v.w);
    *reinterpret_cast<ushort4*>(d + i) = o;
  }
}

// ---------------- silu(emb) precompute (f32) ----------------
__global__ __launch_bounds__(256) void silu_emb(const float* __restrict__ emb,
    float* __restrict__ semb) {
  int i = (blockIdx.x * 256 + threadIdx.x) * 4;
  float4 v = *reinterpret_cast<const float4*>(emb + i);
  float4 o;
  o.x = v.x / (1.f + __expf(-v.x));
  o.y = v.y / (1.f + __expf(-v.y));
  o.z = v.z / (1.f + __expf(-v.z));
  o.w = v.w / (1.f + __expf(-v.w));
  *reinterpret_cast<float4*>(semb + i) = o;
}

// ---------------- emb GEMV: ss[32][1024] = semb[32][2048] @ W[1024][2048]^T + b ----------------
__global__ __launch_bounds__(256) void emb_gemv(const float* __restrict__ semb,
    const float* __restrict__ W, const float* __restrict__ bias,
    float* __restrict__ ss) {
  int n = blockIdx.x * 4 + (threadIdx.x >> 6);   // 256 blocks -> 1024 cols
  int lane = threadIdx.x & 63;
  float acc[32];
  #pragma unroll
  for (int m = 0; m < 32; m++) acc[m] = 0.f;
  for (int i = 0; i < 8; i++) {
    int k = (i * 64 + lane) * 4;
    float4 wv = *reinterpret_cast<const float4*>(&W[(size_t)n * 2048 + k]);
    #pragma unroll
    for (int m = 0; m < 32; m++) {
      float4 sv = *reinterpret_cast<const float4*>(&semb[(size_t)m * 2048 + k]);
      acc[m] = fmaf(sv.x, wv.x, fmaf(sv.y, wv.y, fmaf(sv.z, wv.z, fmaf(sv.w, wv.w, acc[m]))));
    }
  }
  #pragma unroll
  for (int m = 0; m < 32; m++) {
    float s = wave_sum(acc[m]);
    if (lane == 0) ss[(size_t)m * 1024 + n] = s + bias[n];
  }
}

// ---------------- MFMA GEMM: C = A @ W^T (+bias, masks, residual) ----------------
// OUTMODE: 0 = f32 (+optional addX residual), 1 = bf16, 2 = bf16(exp(.))
// Epilogue is LDS-staged for coalesced 16B stores.
template<int OUTMODE>
__global__ __launch_bounds__(256) void gemm_mfma(
    const unsigned short* __restrict__ A, const unsigned short* __restrict__ W,
    const float* __restrict__ bias, void* __restrict__ Cout,
    int M, int K, int m_per_b, int n_total, int out_off,
    const float* __restrict__ rowAdd, const float* __restrict__ rowMul,
    const float* __restrict__ addX) {
  __shared__ __align__(16) char smem[34816];   // union: As+Bs (16KB) | out stage (34KB)
  unsigned short* As = (unsigned short*)smem;          // 128*32
  unsigned short* Bs = As + 4096;                      // 128*32
  const int tid = threadIdx.x;
  const int lane = tid & 63;
  const int wv = tid >> 6;
  const int wr = (wv >> 1) * 64;
  const int wc = (wv & 1) * 64;
  const int m0 = blockIdx.y * 128;
  const int n0 = blockIdx.x * 128;

  const unsigned short* srcA[2]; const unsigned short* srcB[2];
  unsigned short* dstA[2]; unsigned short* dstB[2];
  #pragma unroll
  for (int i = 0; i < 2; i++) {
    int lin = i * 256 + tid;
    int r = lin >> 2, cl = lin & 3;
    int cs = cl ^ ((r >> 1) & 3);
    int ra = m0 + r; if (ra > M - 1) ra = M - 1;
    srcA[i] = A + (size_t)ra * K + cs * 8;
    dstA[i] = &As[lin * 8];
    srcB[i] = W + (size_t)(n0 + r) * K + cs * 8;
    dstB[i] = &Bs[lin * 8];
  }
  int offA[4], offB[4];
  #pragma unroll
  for (int i = 0; i < 4; i++) {
    int r = wr + i * 16 + (lane & 15);
    int c = (lane >> 4) ^ ((r >> 1) & 3);
    offA[i] = r * 32 + c * 8;
    int rb = wc + i * 16 + (lane & 15);
    int cb = (lane >> 4) ^ ((rb >> 1) & 3);
    offB[i] = rb * 32 + cb * 8;
  }

  f32x4 acc[4][4] = {};

  for (int k0 = 0; k0 < K; k0 += 32) {
    #pragma unroll
    for (int i = 0; i < 2; i++) {
      __builtin_amdgcn_global_load_lds(
          (const __attribute__((address_space(1))) void*)(srcA[i] + k0),
          (__attribute__((address_space(3))) void*)dstA[i], 16, 0, 0);
      __builtin_amdgcn_global_load_lds(
          (const __attribute__((address_space(1))) void*)(srcB[i] + k0),
          (__attribute__((address_space(3))) void*)dstB[i], 16, 0, 0);
    }
    asm volatile("s_waitcnt vmcnt(0)" ::: "memory");
    __syncthreads();
    bf16x8 af[4], bf[4];
    #pragma unroll
    for (int i = 0; i < 4; i++) {
      af[i] = *reinterpret_cast<const bf16x8*>(&As[offA[i]]);
      bf[i] = *reinterpret_cast<const bf16x8*>(&Bs[offB[i]]);
    }
    #pragma unroll
    for (int i = 0; i < 4; i++)
      #pragma unroll
      for (int j = 0; j < 4; j++)
        acc[i][j] = __builtin_amdgcn_mfma_f32_16x16x32_bf16(af[i], bf[j], acc[i][j], 0, 0, 0);
    __syncthreads();
  }

  const int r4 = (lane >> 4) << 2;
  if (OUTMODE != 0) {
    // ---- bf16 epilogue: stage full 128x128 tile in LDS, coalesced 16B writes ----
    unsigned short* S = (unsigned short*)smem;        // [128][kLDSW]
    #pragma unroll
    for (int i = 0; i < 4; i++) {
      #pragma unroll
      for (int r = 0; r < 4; r++) {
        int row_t = wr + i * 16 + r4 + r;
        int rowg = m0 + row_t; if (rowg > M - 1) rowg = M - 1;
        float ra = rowAdd ? rowAdd[rowg] : 0.f;
        float rm = rowMul ? rowMul[rowg] : 1.f;
        #pragma unroll
        for (int j = 0; j < 4; j++) {
          int col_t = wc + j * 16 + (lane & 15);
          float v = (acc[i][j][r] + bias[n0 + col_t] + ra) * rm;
          if (OUTMODE == 2) v = __expf(v);
          S[row_t * kLDSW + col_t] = f2bf(v);
        }
      }
    }
    __syncthreads();
    #pragma unroll
    for (int it = 0; it < 8; it++) {
      int slot = it * 256 + tid;        // 2048 slots = 128 rows x 16 chunks
      int row_t = slot >> 4;
      int cs = (slot & 15) * 8;
      int row = m0 + row_t;
      if (row < M) {
        size_t orow = (size_t)(row / m_per_b) * n_total + out_off + (row % m_per_b);
        ulonglong2 d = *reinterpret_cast<const ulonglong2*>(&S[row_t * kLDSW + cs]);
        *reinterpret_cast<ulonglong2*>((unsigned short*)Cout + orow * 512 + n0 + cs) = d;
      }
    }
  } else {
    // ---- f32 epilogue: two 64-row passes, coalesced float4 writes (+residual) ----
    float* Sf = (float*)smem;                         // [64][kLDSW]
    #pragma unroll
    for (int p = 0; p < 2; p++) {
      __syncthreads();
      #pragma unroll
      for (int i2 = 0; i2 < 2; i2++) {
        int i = p * 2 + i2;
        #pragma unroll
        for (int r = 0; r < 4; r++) {
          int row_t = wr + i * 16 + r4 + r;
          int srow = (row_t & 31) + ((row_t >> 6) << 5);
          int rowg = m0 + row_t; if (rowg > M - 1) rowg = M - 1;
          float ra = rowAdd ? rowAdd[rowg] : 0.f;
          float rm = rowMul ? rowMul[rowg] : 1.f;
          #pragma unroll
          for (int j = 0; j < 4; j++) {
            int col_t = wc + j * 16 + (lane & 15);
            Sf[srow * kLDSW + col_t] = (acc[i][j][r] + bias[n0 + col_t] + ra) * rm;
          }
        }
      }
      __syncthreads();
      #pragma unroll
      for (int it = 0; it < 8; it++) {
        int slot = it * 256 + tid;      // 2048 slots = 64 rows x 32 float4
        int srow = slot >> 5;
        int c4 = (slot & 31) * 4;
        int row_t = (srow & 31) + p * 32 + ((srow >> 5) << 6);
        int row = m0 + row_t;
        if (row < M) {
          size_t orow = (size_t)(row / m_per_b) * n_total + out_off + (row % m_per_b);
          float4 v = *reinterpret_cast<const float4*>(&Sf[srow * kLDSW + c4]);
          if (addX) {
            float4 xv = *reinterpret_cast<const float4*>(&addX[(size_t)row * 512 + n0 + c4]);
            v.x += xv.x; v.y += xv.y; v.z += xv.z; v.w += xv.w;
          }
          *reinterpret_cast<float4*>((float*)Cout + orow * 512 + n0 + c4) = v;
        }
      }
    }
  }
}

// ---------------- coalesced column-sum of E over N (partial per slice) ----------------
__global__ __launch_bounds__(256) void colsumE(const unsigned short* __restrict__ E,
    float* __restrict__ part) {
  int b = blockIdx.x, s = blockIdx.y;
  int nbeg = s * kSL, nend = min(kN, nbeg + kSL);
  int grp = threadIdx.x >> 6, lane = threadIdx.x & 63;
  const unsigned short* base = E + (size_t)b * kN * 512 + lane * 8;
  float acc[8] = {};
  for (int n = nbeg + grp; n < nend; n += 4) {
    const unsigned short* p = base + (size_t)n * 512;
    ushort4 u0 = *reinterpret_cast<const ushort4*>(p);
    ushort4 u1 = *reinterpret_cast<const ushort4*>(p + 4);
    acc[0] += bf2f(u0.x); acc[1] += bf2f(u0.y); acc[2] += bf2f(u0.z); acc[3] += bf2f(u0.w);
    acc[4] += bf2f(u1.x); acc[5] += bf2f(u1.y); acc[6] += bf2f(u1.z); acc[7] += bf2f(u1.w);
  }
  __shared__ float sacc[4][512];
  #pragma unroll
  for (int j = 0; j < 8; j++) sacc[grp][lane * 8 + j] = acc[j];
  __syncthreads();
  for (int c = threadIdx.x; c < 512; c += 256) {
    part[((size_t)b * kNS + s) * 512 + c] =
        sacc[0][c] + sacc[1][c] + sacc[2][c] + sacc[3][c];
  }
}
__global__ __launch_bounds__(256) void colsum_fin(const float* __restrict__ part,
    float* __restrict__ sinv) {
  int i = blockIdx.x * 256 + threadIdx.x;   // CH*512 total
  int b = i >> 9, d = i & 511;
  float s = 0.f;
  #pragma unroll
  for (int c = 0; c < kNS; c++) s += part[((size_t)b * kNS + c) * 512 + d];
  sinv[i] = 1.f / s;
}

// ---------------- attention partials: P[bh][s] = E_slice^T V_slice (64x64) ----------------
__global__ __launch_bounds__(256) void attp_kernel(const unsigned short* __restrict__ E,
    const unsigned short* __restrict__ V, float* __restrict__ part) {
  int bh = blockIdx.x; int b = bh >> 3, h = bh & 7;
  int s = blockIdx.y;
  int nbeg = s * kSL, nend = min(kN, nbeg + kSL);
  const unsigned short* kp = E + (size_t)b * kN * 512 + h * 64;
  const unsigned short* vp = V + (size_t)b * kN * 512 + h * 64;
  __shared__ float ks[32][68];
  __shared__ float vs[32][68];
  int tid = threadIdx.x;
  int td = tid >> 4, tl = tid & 15;
  int snn = tid >> 3, sc0 = (tid & 7) * 8;
  float acc[4][4] = {};
  for (int n0 = nbeg; n0 < nend; n0 += 32) {
    __syncthreads();
    int n = n0 + snn;
    float kv[8] = {}, vv[8] = {};
    if (n < nend) {
      const unsigned short* pk = kp + (size_t)n * 512 + sc0;
      const unsigned short* pv = vp + (size_t)n * 512 + sc0;
      ushort4 a0 = *reinterpret_cast<const ushort4*>(pk);
      ushort4 a1 = *reinterpret_cast<const ushort4*>(pk + 4);
      ushort4 b0 = *reinterpret_cast<const ushort4*>(pv);
      ushort4 b1 = *reinterpret_cast<const ushort4*>(pv + 4);
      kv[0] = bf2f(a0.x); kv[1] = bf2f(a0.y); kv[2] = bf2f(a0.z); kv[3] = bf2f(a0.w);
      kv[4] = bf2f(a1.x); kv[5] = bf2f(a1.y); kv[6] = bf2f(a1.z); kv[7] = bf2f(a1.w);
      vv[0] = bf2f(b0.x); vv[1] = bf2f(b0.y); vv[2] = bf2f(b0.z); vv[3] = bf2f(b0.w);
      vv[4] = bf2f(b1.x); vv[5] = bf2f(b1.y); vv[6] = bf2f(b1.z); vv[7] = bf2f(b1.w);
    }
    #pragma unroll
    for (int j = 0; j < 8; j++) { ks[snn][sc0 + j] = kv[j]; vs[snn][sc0 + j] = vv[j]; }
    __syncthreads();
    #pragma unroll
    for (int nn = 0; nn < 32; nn++) {
      float4 kq = *reinterpret_cast<const float4*>(&ks[nn][td * 4]);
      float4 vl = *reinterpret_cast<const float4*>(&vs[nn][tl * 4]);
      float a[4] = {kq.x, kq.y, kq.z, kq.w};
      float c[4] = {vl.x, vl.y, vl.z, vl.w};
      #pragma unroll
      for (int i = 0; i < 4; i++)
        #pragma unroll
        for (int j = 0; j < 4; j++)
          acc[i][j] = fmaf(a[i], c[j], acc[i][j]);
    }
  }
  float* op = part + ((size_t)bh * kNS + s) * 4096;
  #pragma unroll
  for (int i = 0; i < 4; i++)
    #pragma unroll
    for (int j = 0; j < 4; j++)
      op[(td * 4 + i) * 64 + tl * 4 + j] = acc[i][j];
}

// ---------------- combine attention partials * sinv ----------------
__global__ __launch_bounds__(256) void attc_kernel(const float* __restrict__ part,
    const float* __restrict__ sinv, float* __restrict__ att) {
  int bh = blockIdx.x; int b = bh >> 3, h = bh & 7;
  for (int i = threadIdx.x; i < 4096; i += 256) {
    float s = 0.f;
    #pragma unroll
    for (int c = 0; c < kNS; c++) s += part[((size_t)bh * kNS + c) * 4096 + i];
    att[(size_t)bh * 4096 + i] = s * sinv[b * 512 + h * 64 + (i >> 6)];
  }
}

// ---------------- y = (softmax_d expq) @ att  (expq pre-exponentiated) ----------------
__global__ __launch_bounds__(256) void y_einsum(const unsigned short* __restrict__ q,
    const float* __restrict__ att, float* __restrict__ y) {
  int bh = blockIdx.x; int b = bh >> 3, h = bh & 7;
  int t0 = blockIdx.y * 64;
  __shared__ float as_[64][64];
  __shared__ float qs[64][68];
  int tid = threadIdx.x;
  #pragma unroll
  for (int idx = tid; idx < 4096; idx += 256) {
    int l = idx & 63, dd = idx >> 6;
    as_[dd][l] = att[(size_t)bh * 4096 + idx];
  }
  #pragma unroll
  for (int idx = tid; idx < 4096; idx += 256) {
    int dd = idx & 63, tt = idx >> 6;
    qs[tt][dd] = bf2f(q[(size_t)(b * 1024 + t0 + tt) * 512 + h * 64 + dd]);
  }
  __syncthreads();
  int t = tid >> 2, lb = (tid & 3) << 4;
  float rsum = 0.f;
  for (int dd = 0; dd < 64; dd++) rsum += qs[t][dd];
  float rinv = 1.f / rsum;
  float acc[16] = {};
  for (int dd = 0; dd < 64; dd++) {
    float qv = qs[t][dd];
    #pragma unroll
    for (int j = 0; j < 16; j++) acc[j] = fmaf(qv, as_[dd][lb + j], acc[j]);
  }
  float* yp = y + (size_t)(b * 1024 + t0 + t) * 512 + h * 64 + lb;
  #pragma unroll
  for (int j = 0; j < 16; j++) yp[j] = acc[j] * rinv;
}

// ---------------- LN(y)*(1+scale)+shift then SiLU -> bf16 ----------------
__global__ __launch_bounds__(256) void mod_kernel(const float* __restrict__ y,
    const float* __restrict__ ss, const float* __restrict__ g, const float* __restrict__ be,
    unsigned short* __restrict__ h) {
  int row = blockIdx.x; int b = row >> 10;
  const float* p = y + (size_t)row * 512;
  unsigned short* o = h + (size_t)row * 512;
  float v[2]; float s = 0.f, s2 = 0.f;
  #pragma unroll
  for (int i = 0; i < 2; i++) {
    v[i] = p[threadIdx.x + i * 256];
    s += v[i]; s2 += v[i] * v[i];
  }
  __shared__ float red[2][4];
  int lane = threadIdx.x & 63, w = threadIdx.x >> 6;
  s = wave_sum(s); s2 = wave_sum(s2);
  if (!lane) { red[0][w] = s; red[1][w] = s2; }
  __syncthreads();
  s = red[0][0] + red[0][1] + red[0][2] + red[0][3];
  s2 = red[1][0] + red[1][1] + red[1][2] + red[1][3];
  float mean = s / 512.f, var = s2 / 512.f - mean * mean;
  float rstd = rsqrtf(var + 1e-5f);
  #pragma unroll
  for (int i = 0; i < 2; i++) {
    int c = threadIdx.x + i * 256;
    float val = (v[i] - mean) * rstd * g[c] + be[c];
    val = val * (1.f + ss[b * 1024 + c]) + ss[b * 1024 + 512 + c];
    o[c] = f2bf(val / (1.f + __expf(-val)));
  }
}

}  // namespace

extern "C" void kernel_launch(void* const* d_in, const int* in_sizes, int n_in,
                              void* d_out, int out_size, void* d_ws, size_t ws_size,
                              hipStream_t stream) {
  const float* x        = (const float*)d_in[0];
  const float* xf       = (const float*)d_in[1];
  const float* emb      = (const float*)d_in[2];
  const float* src_mask = (const float*)d_in[3];
  const int*   cond     = (const int*)d_in[4];
  const float* re_motion= (const float*)d_in[5];
  const float* re_text  = (const float*)d_in[6];
  const float* re_mask  = (const float*)d_in[7];
  const float* norm_g = (const float*)d_in[8],  * norm_b = (const float*)d_in[9];
  const float* tnorm_g= (const float*)d_in[10], * tnorm_b= (const float*)d_in[11];
  const float* rn1_g  = (const float*)d_in[12], * rn1_b  = (const float*)d_in[13];
  const float* rn2_g  = (const float*)d_in[14], * rn2_b  = (const float*)d_in[15];
  const float* Wq  = (const float*)d_in[16], * bq  = (const float*)d_in[17];
  const float* Wkt = (const float*)d_in[18], * bkt = (const float*)d_in[19];
  const float* Wvt = (const float*)d_in[20], * bvt = (const float*)d_in[21];
  const float* Wkm = (const float*)d_in[22], * bkm = (const float*)d_in[23];
  const float* Wvm = (const float*)d_in[24], * bvm = (const float*)d_in[25];
  const float* Wkr = (const float*)d_in[26], * bkr = (const float*)d_in[27];
  const float* Wvr = (const float*)d_in[28], * bvr = (const float*)d_in[29];
  const float* emb_W = (const float*)d_in[30], * emb_b = (const float*)d_in[31];
  const float* snorm_g = (const float*)d_in[32], * snorm_b = (const float*)d_in[33];
  const float* out_W = (const float*)d_in[34], * out_b = (const float*)d_in[35];
  float* out = (float*)d_out;

  char* base = (char*)d_ws;
  size_t off = 0;
  auto ab = [&](size_t nb) { char* p = base + off; off = (off + nb + 255) & ~(size_t)255; return p; };

  // ---- persistent region: bf16 weights + full-batch small buffers ----
  unsigned short* wq_bf  = (unsigned short*)ab(512 * 512 * 2);
  unsigned short* wkt_bf = (unsigned short*)ab(512 * 256 * 2);
  unsigned short* wvt_bf = (unsigned short*)ab(512 * 256 * 2);
  unsigned short* wkm_bf = (unsigned short*)ab(512 * 512 * 2);
  unsigned short* wvm_bf = (unsigned short*)ab(512 * 512 * 2);
  unsigned short* wkr_bf = (unsigned short*)ab(512 * 1024 * 2);
  unsigned short* wvr_bf = (unsigned short*)ab(512 * 512 * 2);
  unsigned short* wout_bf= (unsigned short*)ab(512 * 512 * 2);
  float* semb_f   = (float*)ab((size_t)kB * 2048 * 4);
  float* ssb_full = (float*)ab((size_t)kB * 1024 * 4);
  float* kaT_full = (float*)ab((size_t)kB * kNT * 4);
  float* vmT_full = (float*)ab((size_t)kB * kNT * 4);
  float* kaR_full = (float*)ab((size_t)kB * kRL * 4);
  float* kaM_full = (float*)ab((size_t)kB * kT * 4);
  float* vmR_full = (float*)ab((size_t)kB * kRL * 4);
  float* vmM_full = (float*)ab((size_t)kB * kT * 4);
  const size_t fixed_off = off;

  auto pad = [](size_t n) { return (n + 255) & ~(size_t)255; };
  auto chunk_bytes = [&](size_t CH) -> size_t {
    size_t s = 0;
    s += pad(CH * 1024 * 512 * 2);        // xn_bf (reused as h_bf)
    s += pad(CH * kNT * 256 * 2);         // xfn_bf
    s += pad(CH * 1024 * 1024 * 2);       // rfk_bf (reused as yb f32)
    s += pad(CH * 1024 * 512 * 2);        // rfv_bf
    s += pad(CH * 1024 * 512 * 2);        // qb_bf
    s += pad((size_t)CH * kN * 512 * 2);  // kc_bf (E)
    s += pad((size_t)CH * kN * 512 * 2);  // vb_bf
    s += pad(CH * 8 * 4096 * 4);          // attb
    s += pad(CH * 8 * (size_t)kNS * 4096 * 4);  // attp partials
    s += pad(CH * kNS * 512 * 4) + pad(CH * 512 * 4);     // partE, sinv
    return s;
  };
  int CH = 32;
  while (CH > 1 && fixed_off + chunk_bytes(CH) > ws_size) CH >>= 1;

  // ---- once-per-call work (full batch) ----
  auto cl = [&](const float* s, unsigned short* d, int n) {
    castw<<<dim3((n / 4 + 255) / 256), 256, 0, stream>>>(s, d, n);
  };
  cl(Wq,  wq_bf,  512 * 512);
  cl(Wkt, wkt_bf, 512 * 256);
  cl(Wvt, wvt_bf, 512 * 256);
  cl(Wkm, wkm_bf, 512 * 512);
  cl(Wvm, wvm_bf, 512 * 512);
  cl(Wkr, wkr_bf, 512 * 1024);
  cl(Wvr, wvr_bf, 512 * 512);
  cl(out_W, wout_bf, 512 * 512);

  rowmask_kernel<<<dim3(kB * 4), 256, 0, stream>>>(cond, src_mask, re_mask,
      kaT_full, kaR_full, kaM_full, vmT_full, vmR_full, vmM_full, kB);
  silu_emb<<<dim3(kB * 2048 / 1024), 256, 0, stream>>>(emb, semb_f);
  emb_gemv<<<dim3(256), 256, 0, stream>>>(semb_f, emb_W, emb_b, ssb_full);

  for (int b0 = 0; b0 < kB; b0 += CH) {
    off = fixed_off;
    const int MRc = CH * 1024;
    const int MTc = CH * kNT;

    unsigned short* xn_bf  = (unsigned short*)ab((size_t)MRc * 512 * 2);
    unsigned short* xfn_bf = (unsigned short*)ab((size_t)MTc * 256 * 2);
    unsigned short* rfk_bf = (unsigned short*)ab((size_t)MRc * 1024 * 2);
    unsigned short* rfv_bf = (unsigned short*)ab((size_t)MRc * 512 * 2);
    unsigned short* qb_bf  = (unsigned short*)ab((size_t)MRc * 512 * 2);
    unsigned short* kc_bf  = (unsigned short*)ab((size_t)CH * kN * 512 * 2);
    unsigned short* vb_bf  = (unsigned short*)ab((size_t)CH * kN * 512 * 2);
    float* attb = (float*)ab((size_t)CH * 8 * 4096 * 4);
    float* attp = (float*)ab((size_t)CH * 8 * kNS * 4096 * 4);
    float* partE = (float*)ab((size_t)CH * kNS * 512 * 4);
    float* sinv = (float*)ab((size_t)CH * 512 * 4);
    float* yb = (float*)rfk_bf;              // rfk dead after Wkr GEMM
    unsigned short* h_bf = xn_bf;            // xn dead after Wvm GEMM

    const float* x_c   = x + (size_t)b0 * kT * 512;
    const float* xf_c  = xf + (size_t)b0 * kNT * 256;
    const float* rm_c  = re_motion + (size_t)b0 * kRL * 512;
    const float* rt_c  = re_text + (size_t)b0 * kR * 512;
    float* out_c = out + (size_t)b0 * kT * 512;

    // --- preprocessing ---
    ln_bf16<512><<<dim3(MRc), 256, 0, stream>>>(x_c, norm_g, norm_b, xn_bf);
    ln_bf16<256><<<dim3(MTc), 256, 0, stream>>>(xf_c, tnorm_g, tnorm_b, xfn_bf);
    rfk_norm<<<dim3(MRc), 256, 0, stream>>>(rm_c, rt_c, rn1_g, rn1_b, rn2_g, rn2_b,
                                            rfk_bf, rfv_bf);

    // --- projections (bf16 MFMA); k-GEMMs and q-GEMM write exp() ---
    gemm_mfma<2><<<dim3(4, CH * 8), 256, 0, stream>>>(xn_bf, wq_bf, bq, qb_bf,
        MRc, 512, MRc, 0, 0, nullptr, nullptr, nullptr);
    gemm_mfma<2><<<dim3(4, (MTc + 127) / 128), 256, 0, stream>>>(xfn_bf, wkt_bf, bkt, kc_bf,
        MTc, 256, kNT, kN, 0, kaT_full + (size_t)b0 * kNT, nullptr, nullptr);
    gemm_mfma<2><<<dim3(4, CH * 8), 256, 0, stream>>>(rfk_bf, wkr_bf, bkr, kc_bf,
        MRc, 1024, kRL, kN, kNT, kaR_full + (size_t)b0 * kRL, nullptr, nullptr);
    gemm_mfma<2><<<dim3(4, CH * 8), 256, 0, stream>>>(xn_bf, wkm_bf, bkm, kc_bf,
        MRc, 512, kT, kN, kNT + kRL, kaM_full + (size_t)b0 * kT, nullptr, nullptr);
    gemm_mfma<1><<<dim3(4, (MTc + 127) / 128), 256, 0, stream>>>(xfn_bf, wvt_bf, bvt, vb_bf,
        MTc, 256, kNT, kN, 0, nullptr, vmT_full + (size_t)b0 * kNT, nullptr);
    gemm_mfma<1><<<dim3(4, CH * 8), 256, 0, stream>>>(rfv_bf, wvr_bf, bvr, vb_bf,
        MRc, 512, kRL, kN, kNT, nullptr, vmR_full + (size_t)b0 * kRL, nullptr);
    gemm_mfma<1><<<dim3(4, CH * 8), 256, 0, stream>>>(xn_bf, wvm_bf, bvm, vb_bf,
        MRc, 512, kT, kN, kNT + kRL, nullptr, vmM_full + (size_t)b0 * kT, nullptr);

    // --- attention (E = exp(k) already materialized) ---
    colsumE<<<dim3(CH, kNS), 256, 0, stream>>>(kc_bf, partE);
    colsum_fin<<<dim3(CH * 2), 256, 0, stream>>>(partE, sinv);
    attp_kernel<<<dim3(CH * 8, kNS), 256, 0, stream>>>(kc_bf, vb_bf, attp);
    attc_kernel<<<dim3(CH * 8), 256, 0, stream>>>(attp, sinv, attb);
    y_einsum<<<dim3(CH * 8, 16), 256, 0, stream>>>(qb_bf, attb, yb);

    // --- modulation + output projection + residual ---
    mod_kernel<<<dim3(MRc), 256, 0, stream>>>(yb, ssb_full + (size_t)b0 * 1024,
                                              snorm_g, snorm_b, h_bf);
    gemm_mfma<0><<<dim3(4, CH * 8), 256, 0, stream>>>(h_bf, wout_bf, out_b, out_c,
        MRc, 512, MRc, 0, 0, nullptr, nullptr, x_c);
  }
}

// Round 7
// 717.200 us; speedup vs baseline: 4.1192x; 1.0807x over previous
//
#include <hip/hip_runtime.h>
#include <cstddef>
#include <cstdint>

#define DEV __device__ __forceinline__

namespace {

constexpr int kH = 8;
constexpr int kB = 32, kT = 1024, kNT = 77, kR = 4, kLR = 256;
constexpr int kRL = kR * kLR;            // 1024
constexpr int kN = kNT + kRL + kT;       // 2125
constexpr float kNEG = -1000000.0f;
constexpr int kNS = 8;                   // N-slices for attention reduction
constexpr int kSL = 266;                 // ceil(2125/8)
constexpr int kLDSW = 136;               // padded epilogue stage width

typedef __bf16 bf16x8 __attribute__((ext_vector_type(8)));
typedef float f32x4 __attribute__((ext_vector_type(4)));

DEV unsigned short f2bf(float f) {
  unsigned int u = __float_as_uint(f);
  u += 0x7fffu + ((u >> 16) & 1u);
  return (unsigned short)(u >> 16);
}
DEV float bf2f(unsigned short h) { return __uint_as_float(((unsigned int)h) << 16); }

DEV float wave_sum(float v) {
  #pragma unroll
  for (int s = 32; s; s >>= 1) v += __shfl_xor(v, s);
  return v;
}

// ---------------- LayerNorm -> bf16 ----------------
template<int COLS>
__global__ __launch_bounds__(256) void ln_bf16(const float* __restrict__ in,
    const float* __restrict__ g, const float* __restrict__ be,
    unsigned short* __restrict__ out) {
  constexpr int PT = COLS / 256;
  int row = blockIdx.x;
  const float* p = in + (size_t)row * COLS;
  unsigned short* o = out + (size_t)row * COLS;
  float v[PT]; float s = 0.f, s2 = 0.f;
  #pragma unroll
  for (int i = 0; i < PT; i++) {
    v[i] = p[threadIdx.x + i * 256];
    s += v[i]; s2 += v[i] * v[i];
  }
  __shared__ float red[2][4];
  int lane = threadIdx.x & 63, w = threadIdx.x >> 6;
  s = wave_sum(s); s2 = wave_sum(s2);
  if (!lane) { red[0][w] = s; red[1][w] = s2; }
  __syncthreads();
  s = red[0][0] + red[0][1] + red[0][2] + red[0][3];
  s2 = red[1][0] + red[1][1] + red[1][2] + red[1][3];
  float mean = s / COLS;
  float var = s2 / COLS - mean * mean;
  float rstd = rsqrtf(var + 1e-5f);
  #pragma unroll
  for (int i = 0; i < PT; i++) {
    int c = threadIdx.x + i * 256;
    o[c] = f2bf((v[i] - mean) * rstd * g[c] + be[c]);
  }
}

// ---------------- retrieval LNs fused: stats + normalize -> bf16 ----------------
__global__ __launch_bounds__(256) void rfk_norm(const float* __restrict__ mot,
    const float* __restrict__ txt,
    const float* __restrict__ g1, const float* __restrict__ b1,
    const float* __restrict__ g2, const float* __restrict__ b2,
    unsigned short* __restrict__ rfk, unsigned short* __restrict__ rfv) {
  int m = blockIdx.x;                       // chunk-local retrieval row
  const float* pm = mot + (size_t)m * 512;
  const float* pt = txt + (size_t)(m >> 8) * 512;   // (b*4+r) = m/256
  float v[2], t[2];
  float sv = 0.f, sv2 = 0.f, st = 0.f, st2 = 0.f;
  #pragma unroll
  for (int i = 0; i < 2; i++) {
    v[i] = pm[threadIdx.x + i * 256]; sv += v[i]; sv2 += v[i] * v[i];
    t[i] = pt[threadIdx.x + i * 256]; st += t[i]; st2 += t[i] * t[i];
  }
  __shared__ float red[4][4];
  int lane = threadIdx.x & 63, w = threadIdx.x >> 6;
  sv = wave_sum(sv); sv2 = wave_sum(sv2); st = wave_sum(st); st2 = wave_sum(st2);
  if (!lane) { red[0][w] = sv; red[1][w] = sv2; red[2][w] = st; red[3][w] = st2; }
  __syncthreads();
  float SV = red[0][0] + red[0][1] + red[0][2] + red[0][3];
  float SV2 = red[1][0] + red[1][1] + red[1][2] + red[1][3];
  float ST = red[2][0] + red[2][1] + red[2][2] + red[2][3];
  float ST2 = red[3][0] + red[3][1] + red[3][2] + red[3][3];
  float SA = SV + ST, SA2 = SV2 + ST2;
  float ma = SA / 1024.f, va = SA2 / 1024.f - ma * ma;
  float ra_ = rsqrtf(va + 1e-5f);
  float mv = SV / 512.f, vv = SV2 / 512.f - mv * mv;
  float rv_ = rsqrtf(vv + 1e-5f);
  #pragma unroll
  for (int i = 0; i < 2; i++) {
    int c = threadIdx.x + i * 256;
    rfk[(size_t)m * 1024 + c]       = f2bf((v[i] - ma) * ra_ * g1[c] + b1[c]);
    rfk[(size_t)m * 1024 + 512 + c] = f2bf((t[i] - ma) * ra_ * g1[512 + c] + b1[512 + c]);
    rfv[(size_t)m * 512 + c]        = f2bf((v[i] - mv) * rv_ * g2[c] + b2[c]);
  }
}

// ---------------- per-row mask arrays (full batch) ----------------
__global__ __launch_bounds__(256) void rowmask_kernel(const int* __restrict__ ct,
    const float* __restrict__ src_mask, const float* __restrict__ re_mask,
    float* __restrict__ kaT, float* __restrict__ kaR, float* __restrict__ kaM,
    float* __restrict__ vmT, float* __restrict__ vmR, float* __restrict__ vmM,
    int nB) {
  int i = blockIdx.x * 256 + threadIdx.x;
  if (i < nB * kRL) {
    int b = i >> 10;
    int c = ct[b];
    float retr = (c / 10 > 0) ? 1.f : 0.f;
    float rm = re_mask[i];
    kaR[i] = (1.f - retr) * kNEG + (1.f - rm) * kNEG;
    vmR[i] = retr * rm;
    float sm = src_mask[i];
    kaM[i] = (1.f - sm) * kNEG;
    vmM[i] = sm;
  }
  if (i < nB * kNT) {
    int b = i / kNT;
    int c = ct[b];
    float text = (c % 10 > 0) ? 1.f : 0.f;
    kaT[i] = (1.f - text) * kNEG;
    vmT[i] = text;
  }
}

// ---------------- weight cast f32 -> bf16 ----------------
__global__ __launch_bounds__(256) void castw(const float* __restrict__ s,
    unsigned short* __restrict__ d, int n) {
  int i = (blockIdx.x * 256 + threadIdx.x) * 4;
  if (i < n) {
    float4 v = *reinterpret_cast<const float4*>(s + i);
    ushort4 o;
    o.x = f2bf(v.x); o.y = f2bf(v.y); o.z = f2bf(v.z); o.w = f2bf(v.w);
    *reinterpret_cast<ushort4*>(d + i) = o;
  }
}

// ---------------- silu(emb) precompute (f32) ----------------
__global__ __launch_bounds__(256) void silu_emb(const float* __restrict__ emb,
    float* __restrict__ semb) {
  int i = (blockIdx.x * 256 + threadIdx.x) * 4;
  float4 v = *reinterpret_cast<const float4*>(emb + i);
  float4 o;
  o.x = v.x / (1.f + __expf(-v.x));
  o.y = v.y / (1.f + __expf(-v.y));
  o.z = v.z / (1.f + __expf(-v.z));
  o.w = v.w / (1.f + __expf(-v.w));
  *reinterpret_cast<float4*>(semb + i) = o;
}

// ---------------- emb GEMV split-K: part[s][m][n] partials ----------------
__global__ __launch_bounds__(256) void emb_gemv2(const float* __restrict__ semb,
    const float* __restrict__ W, float* __restrict__ part) {
  int n = blockIdx.x * 4 + (threadIdx.x >> 6);   // 1024 cols
  int s = blockIdx.y;                            // 8 k-slices of 256
  int lane = threadIdx.x & 63;
  int k = s * 256 + lane * 4;
  float4 wv = *reinterpret_cast<const float4*>(&W[(size_t)n * 2048 + k]);
  float acc[32];
  #pragma unroll
  for (int m = 0; m < 32; m++) {
    float4 sv = *reinterpret_cast<const float4*>(&semb[(size_t)m * 2048 + k]);
    acc[m] = fmaf(sv.x, wv.x, fmaf(sv.y, wv.y, fmaf(sv.z, wv.z, sv.w * wv.w)));
  }
  #pragma unroll
  for (int m = 0; m < 32; m++) {
    float t = wave_sum(acc[m]);
    if (lane == 0) part[((size_t)s * 32 + m) * 1024 + n] = t;
  }
}
__global__ __launch_bounds__(256) void emb_fin(const float* __restrict__ part,
    const float* __restrict__ bias, float* __restrict__ ss) {
  int i = blockIdx.x * 256 + threadIdx.x;   // 32768 = 32*1024
  float s = 0.f;
  #pragma unroll
  for (int c = 0; c < 8; c++) s += part[(size_t)c * 32768 + i];
  ss[i] = s + bias[i & 1023];
}

// ---------------- MFMA GEMM: C = A @ W^T (+bias, masks, residual) ----------------
// OUTMODE: 0 = f32 (+optional addX residual), 1 = bf16, 2 = bf16(exp(.))
// 2-phase pipeline: stage(next) issued before compute(cur); one barrier/iter.
template<int OUTMODE>
__global__ __launch_bounds__(256) void gemm_mfma(
    const unsigned short* __restrict__ A, const unsigned short* __restrict__ W,
    const float* __restrict__ bias, void* __restrict__ Cout,
    int M, int K, int m_per_b, int n_total, int out_off,
    const float* __restrict__ rowAdd, const float* __restrict__ rowMul,
    const float* __restrict__ addX) {
  __shared__ __align__(16) char smem[34816];   // 2x16KB staging | 34KB epilogue
  unsigned short* lds = (unsigned short*)smem;
  const int tid = threadIdx.x;
  const int lane = tid & 63;
  const int wv = tid >> 6;
  const int wr = (wv >> 1) * 64;
  const int wc = (wv & 1) * 64;
  const int m0 = blockIdx.y * 128;
  const int n0 = blockIdx.x * 128;

  const unsigned short* srcA[2]; const unsigned short* srcB[2];
  int dstOff[2];
  #pragma unroll
  for (int i = 0; i < 2; i++) {
    int lin = i * 256 + tid;
    int r = lin >> 2, cl = lin & 3;
    int cs = cl ^ ((r >> 1) & 3);
    int ra = m0 + r; if (ra > M - 1) ra = M - 1;
    srcA[i] = A + (size_t)ra * K + cs * 8;
    srcB[i] = W + (size_t)(n0 + r) * K + cs * 8;
    dstOff[i] = lin * 8;
  }
  int offA[4], offB[4];
  #pragma unroll
  for (int i = 0; i < 4; i++) {
    int r = wr + i * 16 + (lane & 15);
    int c = (lane >> 4) ^ ((r >> 1) & 3);
    offA[i] = r * 32 + c * 8;
    int rb = wc + i * 16 + (lane & 15);
    int cb = (lane >> 4) ^ ((rb >> 1) & 3);
    offB[i] = rb * 32 + cb * 8;
  }

  f32x4 acc[4][4] = {};

  // prologue: stage tile 0 into buffer 0
  #pragma unroll
  for (int i = 0; i < 2; i++) {
    __builtin_amdgcn_global_load_lds(
        (const __attribute__((address_space(1))) void*)(srcA[i]),
        (__attribute__((address_space(3))) void*)&lds[dstOff[i]], 16, 0, 0);
    __builtin_amdgcn_global_load_lds(
        (const __attribute__((address_space(1))) void*)(srcB[i]),
        (__attribute__((address_space(3))) void*)&lds[4096 + dstOff[i]], 16, 0, 0);
  }
  __syncthreads();

  int c = 0;
  for (int k0 = 0; k0 < K; k0 += 32) {
    int nc = c ^ 1;
    if (k0 + 32 < K) {
      #pragma unroll
      for (int i = 0; i < 2; i++) {
        __builtin_amdgcn_global_load_lds(
            (const __attribute__((address_space(1))) void*)(srcA[i] + k0 + 32),
            (__attribute__((address_space(3))) void*)&lds[nc * 8192 + dstOff[i]], 16, 0, 0);
        __builtin_amdgcn_global_load_lds(
            (const __attribute__((address_space(1))) void*)(srcB[i] + k0 + 32),
            (__attribute__((address_space(3))) void*)&lds[nc * 8192 + 4096 + dstOff[i]], 16, 0, 0);
      }
    }
    bf16x8 af[4], bf[4];
    #pragma unroll
    for (int i = 0; i < 4; i++) {
      af[i] = *reinterpret_cast<const bf16x8*>(&lds[c * 8192 + offA[i]]);
      bf[i] = *reinterpret_cast<const bf16x8*>(&lds[c * 8192 + 4096 + offB[i]]);
    }
    #pragma unroll
    for (int i = 0; i < 4; i++)
      #pragma unroll
      for (int j = 0; j < 4; j++)
        acc[i][j] = __builtin_amdgcn_mfma_f32_16x16x32_bf16(af[i], bf[j], acc[i][j], 0, 0, 0);
    __syncthreads();   // implicit vmcnt(0): next tile landed while MFMA ran
    c = nc;
  }

  const int r4 = (lane >> 4) << 2;
  if (OUTMODE != 0) {
    // ---- bf16 epilogue: stage full 128x128 tile in LDS, coalesced 16B writes ----
    unsigned short* S = (unsigned short*)smem;        // [128][kLDSW]
    #pragma unroll
    for (int i = 0; i < 4; i++) {
      #pragma unroll
      for (int r = 0; r < 4; r++) {
        int row_t = wr + i * 16 + r4 + r;
        int rowg = m0 + row_t; if (rowg > M - 1) rowg = M - 1;
        float ra = rowAdd ? rowAdd[rowg] : 0.f;
        float rm = rowMul ? rowMul[rowg] : 1.f;
        #pragma unroll
        for (int j = 0; j < 4; j++) {
          int col_t = wc + j * 16 + (lane & 15);
          float v = (acc[i][j][r] + bias[n0 + col_t] + ra) * rm;
          if (OUTMODE == 2) v = __expf(v);
          S[row_t * kLDSW + col_t] = f2bf(v);
        }
      }
    }
    __syncthreads();
    #pragma unroll
    for (int it = 0; it < 8; it++) {
      int slot = it * 256 + tid;        // 2048 slots = 128 rows x 16 chunks
      int row_t = slot >> 4;
      int cs = (slot & 15) * 8;
      int row = m0 + row_t;
      if (row < M) {
        size_t orow = (size_t)(row / m_per_b) * n_total + out_off + (row % m_per_b);
        ulonglong2 d = *reinterpret_cast<const ulonglong2*>(&S[row_t * kLDSW + cs]);
        *reinterpret_cast<ulonglong2*>((unsigned short*)Cout + orow * 512 + n0 + cs) = d;
      }
    }
  } else {
    // ---- f32 epilogue: two 64-row passes, coalesced float4 writes (+residual) ----
    float* Sf = (float*)smem;                         // [64][kLDSW]
    #pragma unroll
    for (int p = 0; p < 2; p++) {
      __syncthreads();
      #pragma unroll
      for (int i2 = 0; i2 < 2; i2++) {
        int i = p * 2 + i2;
        #pragma unroll
        for (int r = 0; r < 4; r++) {
          int row_t = wr + i * 16 + r4 + r;
          int srow = (row_t & 31) + ((row_t >> 6) << 5);
          int rowg = m0 + row_t; if (rowg > M - 1) rowg = M - 1;
          float ra = rowAdd ? rowAdd[rowg] : 0.f;
          float rm = rowMul ? rowMul[rowg] : 1.f;
          #pragma unroll
          for (int j = 0; j < 4; j++) {
            int col_t = wc + j * 16 + (lane & 15);
            Sf[srow * kLDSW + col_t] = (acc[i][j][r] + bias[n0 + col_t] + ra) * rm;
          }
        }
      }
      __syncthreads();
      #pragma unroll
      for (int it = 0; it < 8; it++) {
        int slot = it * 256 + tid;      // 2048 slots = 64 rows x 32 float4
        int srow = slot >> 5;
        int c4 = (slot & 31) * 4;
        int row_t = (srow & 31) + p * 32 + ((srow >> 5) << 6);
        int row = m0 + row_t;
        if (row < M) {
          size_t orow = (size_t)(row / m_per_b) * n_total + out_off + (row % m_per_b);
          float4 v = *reinterpret_cast<const float4*>(&Sf[srow * kLDSW + c4]);
          if (addX) {
            float4 xv = *reinterpret_cast<const float4*>(&addX[(size_t)row * 512 + n0 + c4]);
            v.x += xv.x; v.y += xv.y; v.z += xv.z; v.w += xv.w;
          }
          *reinterpret_cast<float4*>((float*)Cout + orow * 512 + n0 + c4) = v;
        }
      }
    }
  }
}

// ---------------- coalesced column-sum of E over N (partial per slice) ----------------
__global__ __launch_bounds__(256) void colsumE(const unsigned short* __restrict__ E,
    float* __restrict__ part) {
  int b = blockIdx.x, s = blockIdx.y;
  int nbeg = s * kSL, nend = min(kN, nbeg + kSL);
  int grp = threadIdx.x >> 6, lane = threadIdx.x & 63;
  const unsigned short* base = E + (size_t)b * kN * 512 + lane * 8;
  float acc[8] = {};
  for (int n = nbeg + grp; n < nend; n += 4) {
    const unsigned short* p = base + (size_t)n * 512;
    ushort4 u0 = *reinterpret_cast<const ushort4*>(p);
    ushort4 u1 = *reinterpret_cast<const ushort4*>(p + 4);
    acc[0] += bf2f(u0.x); acc[1] += bf2f(u0.y); acc[2] += bf2f(u0.z); acc[3] += bf2f(u0.w);
    acc[4] += bf2f(u1.x); acc[5] += bf2f(u1.y); acc[6] += bf2f(u1.z); acc[7] += bf2f(u1.w);
  }
  __shared__ float sacc[4][512];
  #pragma unroll
  for (int j = 0; j < 8; j++) sacc[grp][lane * 8 + j] = acc[j];
  __syncthreads();
  for (int c = threadIdx.x; c < 512; c += 256) {
    part[((size_t)b * kNS + s) * 512 + c] =
        sacc[0][c] + sacc[1][c] + sacc[2][c] + sacc[3][c];
  }
}
__global__ __launch_bounds__(256) void colsum_fin(const float* __restrict__ part,
    float* __restrict__ sinv) {
  int i = blockIdx.x * 256 + threadIdx.x;   // CH*512 total
  int b = i >> 9, d = i & 511;
  float s = 0.f;
  #pragma unroll
  for (int c = 0; c < kNS; c++) s += part[((size_t)b * kNS + c) * 512 + d];
  sinv[i] = 1.f / s;
}

// ---------------- attention partials: P[bh][s] = E_slice^T V_slice (64x64) ----------------
__global__ __launch_bounds__(256) void attp_kernel(const unsigned short* __restrict__ E,
    const unsigned short* __restrict__ V, float* __restrict__ part) {
  int bh = blockIdx.x; int b = bh >> 3, h = bh & 7;
  int s = blockIdx.y;
  int nbeg = s * kSL, nend = min(kN, nbeg + kSL);
  const unsigned short* kp = E + (size_t)b * kN * 512 + h * 64;
  const unsigned short* vp = V + (size_t)b * kN * 512 + h * 64;
  __shared__ float ks[32][68];
  __shared__ float vs[32][68];
  int tid = threadIdx.x;
  int td = tid >> 4, tl = tid & 15;
  int snn = tid >> 3, sc0 = (tid & 7) * 8;
  float acc[4][4] = {};
  for (int n0 = nbeg; n0 < nend; n0 += 32) {
    __syncthreads();
    int n = n0 + snn;
    float kv[8] = {}, vv[8] = {};
    if (n < nend) {
      const unsigned short* pk = kp + (size_t)n * 512 + sc0;
      const unsigned short* pv = vp + (size_t)n * 512 + sc0;
      ushort4 a0 = *reinterpret_cast<const ushort4*>(pk);
      ushort4 a1 = *reinterpret_cast<const ushort4*>(pk + 4);
      ushort4 b0 = *reinterpret_cast<const ushort4*>(pv);
      ushort4 b1 = *reinterpret_cast<const ushort4*>(pv + 4);
      kv[0] = bf2f(a0.x); kv[1] = bf2f(a0.y); kv[2] = bf2f(a0.z); kv[3] = bf2f(a0.w);
      kv[4] = bf2f(a1.x); kv[5] = bf2f(a1.y); kv[6] = bf2f(a1.z); kv[7] = bf2f(a1.w);
      vv[0] = bf2f(b0.x); vv[1] = bf2f(b0.y); vv[2] = bf2f(b0.z); vv[3] = bf2f(b0.w);
      vv[4] = bf2f(b1.x); vv[5] = bf2f(b1.y); vv[6] = bf2f(b1.z); vv[7] = bf2f(b1.w);
    }
    #pragma unroll
    for (int j = 0; j < 8; j++) { ks[snn][sc0 + j] = kv[j]; vs[snn][sc0 + j] = vv[j]; }
    __syncthreads();
    #pragma unroll
    for (int nn = 0; nn < 32; nn++) {
      float4 kq = *reinterpret_cast<const float4*>(&ks[nn][td * 4]);
      float4 vl = *reinterpret_cast<const float4*>(&vs[nn][tl * 4]);
      float a[4] = {kq.x, kq.y, kq.z, kq.w};
      float c[4] = {vl.x, vl.y, vl.z, vl.w};
      #pragma unroll
      for (int i = 0; i < 4; i++)
        #pragma unroll
        for (int j = 0; j < 4; j++)
          acc[i][j] = fmaf(a[i], c[j], acc[i][j]);
    }
  }
  float* op = part + ((size_t)bh * kNS + s) * 4096;
  #pragma unroll
  for (int i = 0; i < 4; i++)
    #pragma unroll
    for (int j = 0; j < 4; j++)
      op[(td * 4 + i) * 64 + tl * 4 + j] = acc[i][j];
}

// ---------------- combine attention partials * sinv ----------------
__global__ __launch_bounds__(256) void attc_kernel(const float* __restrict__ part,
    const float* __restrict__ sinv, float* __restrict__ att) {
  int bh = blockIdx.x; int b = bh >> 3, h = bh & 7;
  for (int i = threadIdx.x; i < 4096; i += 256) {
    float s = 0.f;
    #pragma unroll
    for (int c = 0; c < kNS; c++) s += part[((size_t)bh * kNS + c) * 4096 + i];
    att[(size_t)bh * 4096 + i] = s * sinv[b * 512 + h * 64 + (i >> 6)];
  }
}

// ---------------- y = (softmax_d expq) @ att  (expq pre-exponentiated) ----------------
__global__ __launch_bounds__(256) void y_einsum(const unsigned short* __restrict__ q,
    const float* __restrict__ att, float* __restrict__ y) {
  int bh = blockIdx.x; int b = bh >> 3, h = bh & 7;
  int t0 = blockIdx.y * 64;
  __shared__ float as_[64][64];
  __shared__ float qs[64][68];
  int tid = threadIdx.x;
  #pragma unroll
  for (int idx = tid; idx < 4096; idx += 256) {
    int l = idx & 63, dd = idx >> 6;
    as_[dd][l] = att[(size_t)bh * 4096 + idx];
  }
  #pragma unroll
  for (int idx = tid; idx < 4096; idx += 256) {
    int dd = idx & 63, tt = idx >> 6;
    qs[tt][dd] = bf2f(q[(size_t)(b * 1024 + t0 + tt) * 512 + h * 64 + dd]);
  }
  __syncthreads();
  int t = tid >> 2, lb = (tid & 3) << 4;
  float rsum = 0.f;
  for (int dd = 0; dd < 64; dd++) rsum += qs[t][dd];
  float rinv = 1.f / rsum;
  float acc[16] = {};
  for (int dd = 0; dd < 64; dd++) {
    float qv = qs[t][dd];
    #pragma unroll
    for (int j = 0; j < 16; j++) acc[j] = fmaf(qv, as_[dd][lb + j], acc[j]);
  }
  float* yp = y + (size_t)(b * 1024 + t0 + t) * 512 + h * 64 + lb;
  #pragma unroll
  for (int j = 0; j < 16; j++) yp[j] = acc[j] * rinv;
}

// ---------------- LN(y)*(1+scale)+shift then SiLU -> bf16 ----------------
__global__ __launch_bounds__(256) void mod_kernel(const float* __restrict__ y,
    const float* __restrict__ ss, const float* __restrict__ g, const float* __restrict__ be,
    unsigned short* __restrict__ h) {
  int row = blockIdx.x; int b = row >> 10;
  const float* p = y + (size_t)row * 512;
  unsigned short* o = h + (size_t)row * 512;
  float v[2]; float s = 0.f, s2 = 0.f;
  #pragma unroll
  for (int i = 0; i < 2; i++) {
    v[i] = p[threadIdx.x + i * 256];
    s += v[i]; s2 += v[i] * v[i];
  }
  __shared__ float red[2][4];
  int lane = threadIdx.x & 63, w = threadIdx.x >> 6;
  s = wave_sum(s); s2 = wave_sum(s2);
  if (!lane) { red[0][w] = s; red[1][w] = s2; }
  __syncthreads();
  s = red[0][0] + red[0][1] + red[0][2] + red[0][3];
  s2 = red[1][0] + red[1][1] + red[1][2] + red[1][3];
  float mean = s / 512.f, var = s2 / 512.f - mean * mean;
  float rstd = rsqrtf(var + 1e-5f);
  #pragma unroll
  for (int i = 0; i < 2; i++) {
    int c = threadIdx.x + i * 256;
    float val = (v[i] - mean) * rstd * g[c] + be[c];
    val = val * (1.f + ss[b * 1024 + c]) + ss[b * 1024 + 512 + c];
    o[c] = f2bf(val / (1.f + __expf(-val)));
  }
}

}  // namespace

extern "C" void kernel_launch(void* const* d_in, const int* in_sizes, int n_in,
                              void* d_out, int out_size, void* d_ws, size_t ws_size,
                              hipStream_t stream) {
  const float* x        = (const float*)d_in[0];
  const float* xf       = (const float*)d_in[1];
  const float* emb      = (const float*)d_in[2];
  const float* src_mask = (const float*)d_in[3];
  const int*   cond     = (const int*)d_in[4];
  const float* re_motion= (const float*)d_in[5];
  const float* re_text  = (const float*)d_in[6];
  const float* re_mask  = (const float*)d_in[7];
  const float* norm_g = (const float*)d_in[8],  * norm_b = (const float*)d_in[9];
  const float* tnorm_g= (const float*)d_in[10], * tnorm_b= (const float*)d_in[11];
  const float* rn1_g  = (const float*)d_in[12], * rn1_b  = (const float*)d_in[13];
  const float* rn2_g  = (const float*)d_in[14], * rn2_b  = (const float*)d_in[15];
  const float* Wq  = (const float*)d_in[16], * bq  = (const float*)d_in[17];
  const float* Wkt = (const float*)d_in[18], * bkt = (const float*)d_in[19];
  const float* Wvt = (const float*)d_in[20], * bvt = (const float*)d_in[21];
  const float* Wkm = (const float*)d_in[22], * bkm = (const float*)d_in[23];
  const float* Wvm = (const float*)d_in[24], * bvm = (const float*)d_in[25];
  const float* Wkr = (const float*)d_in[26], * bkr = (const float*)d_in[27];
  const float* Wvr = (const float*)d_in[28], * bvr = (const float*)d_in[29];
  const float* emb_W = (const float*)d_in[30], * emb_b = (const float*)d_in[31];
  const float* snorm_g = (const float*)d_in[32], * snorm_b = (const float*)d_in[33];
  const float* out_W = (const float*)d_in[34], * out_b = (const float*)d_in[35];
  float* out = (float*)d_out;

  char* base = (char*)d_ws;
  size_t off = 0;
  auto ab = [&](size_t nb) { char* p = base + off; off = (off + nb + 255) & ~(size_t)255; return p; };

  // ---- persistent region: bf16 weights + full-batch small buffers ----
  unsigned short* wq_bf  = (unsigned short*)ab(512 * 512 * 2);
  unsigned short* wkt_bf = (unsigned short*)ab(512 * 256 * 2);
  unsigned short* wvt_bf = (unsigned short*)ab(512 * 256 * 2);
  unsigned short* wkm_bf = (unsigned short*)ab(512 * 512 * 2);
  unsigned short* wvm_bf = (unsigned short*)ab(512 * 512 * 2);
  unsigned short* wkr_bf = (unsigned short*)ab(512 * 1024 * 2);
  unsigned short* wvr_bf = (unsigned short*)ab(512 * 512 * 2);
  unsigned short* wout_bf= (unsigned short*)ab(512 * 512 * 2);
  float* semb_f   = (float*)ab((size_t)kB * 2048 * 4);
  float* part_emb = (float*)ab((size_t)8 * kB * 1024 * 4);
  float* ssb_full = (float*)ab((size_t)kB * 1024 * 4);
  float* kaT_full = (float*)ab((size_t)kB * kNT * 4);
  float* vmT_full = (float*)ab((size_t)kB * kNT * 4);
  float* kaR_full = (float*)ab((size_t)kB * kRL * 4);
  float* kaM_full = (float*)ab((size_t)kB * kT * 4);
  float* vmR_full = (float*)ab((size_t)kB * kRL * 4);
  float* vmM_full = (float*)ab((size_t)kB * kT * 4);
  const size_t fixed_off = off;

  auto pad = [](size_t n) { return (n + 255) & ~(size_t)255; };
  auto chunk_bytes = [&](size_t CH) -> size_t {
    size_t s = 0;
    s += pad(CH * 1024 * 512 * 2);        // xn_bf (reused as h_bf)
    s += pad(CH * kNT * 256 * 2);         // xfn_bf
    s += pad(CH * 1024 * 1024 * 2);       // rfk_bf (reused as yb f32)
    s += pad(CH * 1024 * 512 * 2);        // rfv_bf
    s += pad(CH * 1024 * 512 * 2);        // qb_bf
    s += pad((size_t)CH * kN * 512 * 2);  // kc_bf (E)
    s += pad((size_t)CH * kN * 512 * 2);  // vb_bf
    s += pad(CH * 8 * 4096 * 4);          // attb
    s += pad(CH * 8 * (size_t)kNS * 4096 * 4);  // attp partials
    s += pad(CH * kNS * 512 * 4) + pad(CH * 512 * 4);     // partE, sinv
    return s;
  };
  int CH = 32;
  while (CH > 1 && fixed_off + chunk_bytes(CH) > ws_size) CH >>= 1;

  // ---- once-per-call work (full batch) ----
  auto cl = [&](const float* s, unsigned short* d, int n) {
    castw<<<dim3((n / 4 + 255) / 256), 256, 0, stream>>>(s, d, n);
  };
  cl(Wq,  wq_bf,  512 * 512);
  cl(Wkt, wkt_bf, 512 * 256);
  cl(Wvt, wvt_bf, 512 * 256);
  cl(Wkm, wkm_bf, 512 * 512);
  cl(Wvm, wvm_bf, 512 * 512);
  cl(Wkr, wkr_bf, 512 * 1024);
  cl(Wvr, wvr_bf, 512 * 512);
  cl(out_W, wout_bf, 512 * 512);

  rowmask_kernel<<<dim3(kB * 4), 256, 0, stream>>>(cond, src_mask, re_mask,
      kaT_full, kaR_full, kaM_full, vmT_full, vmR_full, vmM_full, kB);
  silu_emb<<<dim3(kB * 2048 / 1024), 256, 0, stream>>>(emb, semb_f);
  emb_gemv2<<<dim3(256, 8), 256, 0, stream>>>(semb_f, emb_W, part_emb);
  emb_fin<<<dim3(128), 256, 0, stream>>>(part_emb, emb_b, ssb_full);

  for (int b0 = 0; b0 < kB; b0 += CH) {
    off = fixed_off;
    const int MRc = CH * 1024;
    const int MTc = CH * kNT;

    unsigned short* xn_bf  = (unsigned short*)ab((size_t)MRc * 512 * 2);
    unsigned short* xfn_bf = (unsigned short*)ab((size_t)MTc * 256 * 2);
    unsigned short* rfk_bf = (unsigned short*)ab((size_t)MRc * 1024 * 2);
    unsigned short* rfv_bf = (unsigned short*)ab((size_t)MRc * 512 * 2);
    unsigned short* qb_bf  = (unsigned short*)ab((size_t)MRc * 512 * 2);
    unsigned short* kc_bf  = (unsigned short*)ab((size_t)CH * kN * 512 * 2);
    unsigned short* vb_bf  = (unsigned short*)ab((size_t)CH * kN * 512 * 2);
    float* attb = (float*)ab((size_t)CH * 8 * 4096 * 4);
    float* attp = (float*)ab((size_t)CH * 8 * kNS * 4096 * 4);
    float* partE = (float*)ab((size_t)CH * kNS * 512 * 4);
    float* sinv = (float*)ab((size_t)CH * 512 * 4);
    float* yb = (float*)rfk_bf;              // rfk dead after Wkr GEMM
    unsigned short* h_bf = xn_bf;            // xn dead after Wvm GEMM

    const float* x_c   = x + (size_t)b0 * kT * 512;
    const float* xf_c  = xf + (size_t)b0 * kNT * 256;
    const float* rm_c  = re_motion + (size_t)b0 * kRL * 512;
    const float* rt_c  = re_text + (size_t)b0 * kR * 512;
    float* out_c = out + (size_t)b0 * kT * 512;

    // --- preprocessing ---
    ln_bf16<512><<<dim3(MRc), 256, 0, stream>>>(x_c, norm_g, norm_b, xn_bf);
    ln_bf16<256><<<dim3(MTc), 256, 0, stream>>>(xf_c, tnorm_g, tnorm_b, xfn_bf);
    rfk_norm<<<dim3(MRc), 256, 0, stream>>>(rm_c, rt_c, rn1_g, rn1_b, rn2_g, rn2_b,
                                            rfk_bf, rfv_bf);

    // --- projections (bf16 MFMA); k-GEMMs and q-GEMM write exp() ---
    gemm_mfma<2><<<dim3(4, CH * 8), 256, 0, stream>>>(xn_bf, wq_bf, bq, qb_bf,
        MRc, 512, MRc, 0, 0, nullptr, nullptr, nullptr);
    gemm_mfma<2><<<dim3(4, (MTc + 127) / 128), 256, 0, stream>>>(xfn_bf, wkt_bf, bkt, kc_bf,
        MTc, 256, kNT, kN, 0, kaT_full + (size_t)b0 * kNT, nullptr, nullptr);
    gemm_mfma<2><<<dim3(4, CH * 8), 256, 0, stream>>>(rfk_bf, wkr_bf, bkr, kc_bf,
        MRc, 1024, kRL, kN, kNT, kaR_full + (size_t)b0 * kRL, nullptr, nullptr);
    gemm_mfma<2><<<dim3(4, CH * 8), 256, 0, stream>>>(xn_bf, wkm_bf, bkm, kc_bf,
        MRc, 512, kT, kN, kNT + kRL, kaM_full + (size_t)b0 * kT, nullptr, nullptr);
    gemm_mfma<1><<<dim3(4, (MTc + 127) / 128), 256, 0, stream>>>(xfn_bf, wvt_bf, bvt, vb_bf,
        MTc, 256, kNT, kN, 0, nullptr, vmT_full + (size_t)b0 * kNT, nullptr);
    gemm_mfma<1><<<dim3(4, CH * 8), 256, 0, stream>>>(rfv_bf, wvr_bf, bvr, vb_bf,
        MRc, 512, kRL, kN, kNT, nullptr, vmR_full + (size_t)b0 * kRL, nullptr);
    gemm_mfma<1><<<dim3(4, CH * 8), 256, 0, stream>>>(xn_bf, wvm_bf, bvm, vb_bf,
        MRc, 512, kT, kN, kNT + kRL, nullptr, vmM_full + (size_t)b0 * kT, nullptr);

    // --- attention (E = exp(k) already materialized) ---
    colsumE<<<dim3(CH, kNS), 256, 0, stream>>>(kc_bf, partE);
    colsum_fin<<<dim3(CH * 2), 256, 0, stream>>>(partE, sinv);
    attp_kernel<<<dim3(CH * 8, kNS), 256, 0, stream>>>(kc_bf, vb_bf, attp);
    attc_kernel<<<dim3(CH * 8), 256, 0, stream>>>(attp, sinv, attb);
    y_einsum<<<dim3(CH * 8, 16), 256, 0, stream>>>(qb_bf, attb, yb);

    // --- modulation + output projection + residual ---
    mod_kernel<<<dim3(MRc), 256, 0, stream>>>(yb, ssb_full + (size_t)b0 * 1024,
                                              snorm_g, snorm_b, h_bf);
    gemm_mfma<0><<<dim3(4, CH * 8), 256, 0, stream>>>(h_bf, wout_bf, out_b, out_c,
        MRc, 512, MRc, 0, 0, nullptr, nullptr, x_c);
  }
}

// Round 8
// 617.454 us; speedup vs baseline: 4.7846x; 1.1615x over previous
//
#include <hip/hip_runtime.h>
#include <cstddef>
#include <cstdint>

#define DEV __device__ __forceinline__

namespace {

constexpr int kH = 8;
constexpr int kB = 32, kT = 1024, kNT = 77, kR = 4, kLR = 256;
constexpr int kRL = kR * kLR;            // 1024
constexpr int kN = kNT + kRL + kT;       // 2125
constexpr float kNEG = -1000000.0f;
constexpr int kNS = 8;                   // N-slices for attention reduction
constexpr int kSL = 266;                 // ceil(2125/8)
constexpr int kLDSW = 136;               // padded epilogue stage width

typedef __bf16 bf16x8 __attribute__((ext_vector_type(8)));
typedef float f32x4 __attribute__((ext_vector_type(4)));

DEV unsigned short f2bf(float f) {
  unsigned int u = __float_as_uint(f);
  u += 0x7fffu + ((u >> 16) & 1u);
  return (unsigned short)(u >> 16);
}
DEV float bf2f(unsigned short h) { return __uint_as_float(((unsigned int)h) << 16); }

DEV float wave_sum(float v) {
  #pragma unroll
  for (int s = 32; s; s >>= 1) v += __shfl_xor(v, s);
  return v;
}

// ---------------- LayerNorm -> bf16 ----------------
template<int COLS>
__global__ __launch_bounds__(256) void ln_bf16(const float* __restrict__ in,
    const float* __restrict__ g, const float* __restrict__ be,
    unsigned short* __restrict__ out) {
  constexpr int PT = COLS / 256;
  int row = blockIdx.x;
  const float* p = in + (size_t)row * COLS;
  unsigned short* o = out + (size_t)row * COLS;
  float v[PT]; float s = 0.f, s2 = 0.f;
  #pragma unroll
  for (int i = 0; i < PT; i++) {
    v[i] = p[threadIdx.x + i * 256];
    s += v[i]; s2 += v[i] * v[i];
  }
  __shared__ float red[2][4];
  int lane = threadIdx.x & 63, w = threadIdx.x >> 6;
  s = wave_sum(s); s2 = wave_sum(s2);
  if (!lane) { red[0][w] = s; red[1][w] = s2; }
  __syncthreads();
  s = red[0][0] + red[0][1] + red[0][2] + red[0][3];
  s2 = red[1][0] + red[1][1] + red[1][2] + red[1][3];
  float mean = s / COLS;
  float var = s2 / COLS - mean * mean;
  float rstd = rsqrtf(var + 1e-5f);
  #pragma unroll
  for (int i = 0; i < PT; i++) {
    int c = threadIdx.x + i * 256;
    o[c] = f2bf((v[i] - mean) * rstd * g[c] + be[c]);
  }
}

// ---------------- retrieval LNs fused: stats + normalize -> bf16 ----------------
__global__ __launch_bounds__(256) void rfk_norm(const float* __restrict__ mot,
    const float* __restrict__ txt,
    const float* __restrict__ g1, const float* __restrict__ b1,
    const float* __restrict__ g2, const float* __restrict__ b2,
    unsigned short* __restrict__ rfk, unsigned short* __restrict__ rfv) {
  int m = blockIdx.x;                       // chunk-local retrieval row
  const float* pm = mot + (size_t)m * 512;
  const float* pt = txt + (size_t)(m >> 8) * 512;   // (b*4+r) = m/256
  float v[2], t[2];
  float sv = 0.f, sv2 = 0.f, st = 0.f, st2 = 0.f;
  #pragma unroll
  for (int i = 0; i < 2; i++) {
    v[i] = pm[threadIdx.x + i * 256]; sv += v[i]; sv2 += v[i] * v[i];
    t[i] = pt[threadIdx.x + i * 256]; st += t[i]; st2 += t[i] * t[i];
  }
  __shared__ float red[4][4];
  int lane = threadIdx.x & 63, w = threadIdx.x >> 6;
  sv = wave_sum(sv); sv2 = wave_sum(sv2); st = wave_sum(st); st2 = wave_sum(st2);
  if (!lane) { red[0][w] = sv; red[1][w] = sv2; red[2][w] = st; red[3][w] = st2; }
  __syncthreads();
  float SV = red[0][0] + red[0][1] + red[0][2] + red[0][3];
  float SV2 = red[1][0] + red[1][1] + red[1][2] + red[1][3];
  float ST = red[2][0] + red[2][1] + red[2][2] + red[2][3];
  float ST2 = red[3][0] + red[3][1] + red[3][2] + red[3][3];
  float SA = SV + ST, SA2 = SV2 + ST2;
  float ma = SA / 1024.f, va = SA2 / 1024.f - ma * ma;
  float ra_ = rsqrtf(va + 1e-5f);
  float mv = SV / 512.f, vv = SV2 / 512.f - mv * mv;
  float rv_ = rsqrtf(vv + 1e-5f);
  #pragma unroll
  for (int i = 0; i < 2; i++) {
    int c = threadIdx.x + i * 256;
    rfk[(size_t)m * 1024 + c]       = f2bf((v[i] - ma) * ra_ * g1[c] + b1[c]);
    rfk[(size_t)m * 1024 + 512 + c] = f2bf((t[i] - ma) * ra_ * g1[512 + c] + b1[512 + c]);
    rfv[(size_t)m * 512 + c]        = f2bf((v[i] - mv) * rv_ * g2[c] + b2[c]);
  }
}

// ---------------- per-row mask arrays (full batch) ----------------
__global__ __launch_bounds__(256) void rowmask_kernel(const int* __restrict__ ct,
    const float* __restrict__ src_mask, const float* __restrict__ re_mask,
    float* __restrict__ kaT, float* __restrict__ kaR, float* __restrict__ kaM,
    float* __restrict__ vmT, float* __restrict__ vmR, float* __restrict__ vmM,
    int nB) {
  int i = blockIdx.x * 256 + threadIdx.x;
  if (i < nB * kRL) {
    int b = i >> 10;
    int c = ct[b];
    float retr = (c / 10 > 0) ? 1.f : 0.f;
    float rm = re_mask[i];
    kaR[i] = (1.f - retr) * kNEG + (1.f - rm) * kNEG;
    vmR[i] = retr * rm;
    float sm = src_mask[i];
    kaM[i] = (1.f - sm) * kNEG;
    vmM[i] = sm;
  }
  if (i < nB * kNT) {
    int b = i / kNT;
    int c = ct[b];
    float text = (c % 10 > 0) ? 1.f : 0.f;
    kaT[i] = (1.f - text) * kNEG;
    vmT[i] = text;
  }
}

// ---------------- weight cast f32 -> bf16 ----------------
__global__ __launch_bounds__(256) void castw(const float* __restrict__ s,
    unsigned short* __restrict__ d, int n) {
  int i = (blockIdx.x * 256 + threadIdx.x) * 4;
  if (i < n) {
    float4 v = *reinterpret_cast<const float4*>(s + i);
    ushort4 o;
    o.x = f2bf(v.x); o.y = f2bf(v.y); o.z = f2bf(v.z); o.w = f2bf(v.w);
    *reinterpret_cast<ushort4*>(d + i) = o;
  }
}

// ---------------- silu(emb) precompute (f32) ----------------
__global__ __launch_bounds__(256) void silu_emb(const float* __restrict__ emb,
    float* __restrict__ semb) {
  int i = (blockIdx.x * 256 + threadIdx.x) * 4;
  float4 v = *reinterpret_cast<const float4*>(emb + i);
  float4 o;
  o.x = v.x / (1.f + __expf(-v.x));
  o.y = v.y / (1.f + __expf(-v.y));
  o.z = v.z / (1.f + __expf(-v.z));
  o.w = v.w / (1.f + __expf(-v.w));
  *reinterpret_cast<float4*>(semb + i) = o;
}

// ---------------- emb GEMV split-K: part[s][m][n] partials ----------------
__global__ __launch_bounds__(256) void emb_gemv2(const float* __restrict__ semb,
    const float* __restrict__ W, float* __restrict__ part) {
  int n = blockIdx.x * 4 + (threadIdx.x >> 6);   // 1024 cols
  int s = blockIdx.y;                            // 8 k-slices of 256
  int lane = threadIdx.x & 63;
  int k = s * 256 + lane * 4;
  float4 wv = *reinterpret_cast<const float4*>(&W[(size_t)n * 2048 + k]);
  float acc[32];
  #pragma unroll
  for (int m = 0; m < 32; m++) {
    float4 sv = *reinterpret_cast<const float4*>(&semb[(size_t)m * 2048 + k]);
    acc[m] = fmaf(sv.x, wv.x, fmaf(sv.y, wv.y, fmaf(sv.z, wv.z, sv.w * wv.w)));
  }
  #pragma unroll
  for (int m = 0; m < 32; m++) {
    float t = wave_sum(acc[m]);
    if (lane == 0) part[((size_t)s * 32 + m) * 1024 + n] = t;
  }
}
__global__ __launch_bounds__(256) void emb_fin(const float* __restrict__ part,
    const float* __restrict__ bias, float* __restrict__ ss) {
  int i = blockIdx.x * 256 + threadIdx.x;   // 32768 = 32*1024
  float s = 0.f;
  #pragma unroll
  for (int c = 0; c < 8; c++) s += part[(size_t)c * 32768 + i];
  ss[i] = s + bias[i & 1023];
}

// ---------------- MFMA GEMM: C = A @ W^T (+bias, masks, residual) ----------------
// OUTMODE: 0 = f32 (+optional addX residual), 1 = bf16, 2 = bf16(exp(.))
// 2-phase pipeline: stage(next) issued before compute(cur); one barrier/iter.
template<int OUTMODE>
__global__ __launch_bounds__(256) void gemm_mfma(
    const unsigned short* __restrict__ A, const unsigned short* __restrict__ W,
    const float* __restrict__ bias, void* __restrict__ Cout,
    int M, int K, int m_per_b, int n_total, int out_off,
    const float* __restrict__ rowAdd, const float* __restrict__ rowMul,
    const float* __restrict__ addX) {
  __shared__ __align__(16) char smem[34816];   // 2x16KB staging | 34KB epilogue
  unsigned short* lds = (unsigned short*)smem;
  const int tid = threadIdx.x;
  const int lane = tid & 63;
  const int wv = tid >> 6;
  const int wr = (wv >> 1) * 64;
  const int wc = (wv & 1) * 64;
  const int m0 = blockIdx.y * 128;
  const int n0 = blockIdx.x * 128;

  const unsigned short* srcA[2]; const unsigned short* srcB[2];
  int dstOff[2];
  #pragma unroll
  for (int i = 0; i < 2; i++) {
    int lin = i * 256 + tid;
    int r = lin >> 2, cl = lin & 3;
    int cs = cl ^ ((r >> 1) & 3);
    int ra = m0 + r; if (ra > M - 1) ra = M - 1;
    srcA[i] = A + (size_t)ra * K + cs * 8;
    srcB[i] = W + (size_t)(n0 + r) * K + cs * 8;
    dstOff[i] = lin * 8;
  }
  int offA[4], offB[4];
  #pragma unroll
  for (int i = 0; i < 4; i++) {
    int r = wr + i * 16 + (lane & 15);
    int c = (lane >> 4) ^ ((r >> 1) & 3);
    offA[i] = r * 32 + c * 8;
    int rb = wc + i * 16 + (lane & 15);
    int cb = (lane >> 4) ^ ((rb >> 1) & 3);
    offB[i] = rb * 32 + cb * 8;
  }

  f32x4 acc[4][4] = {};

  // prologue: stage tile 0 into buffer 0
  #pragma unroll
  for (int i = 0; i < 2; i++) {
    __builtin_amdgcn_global_load_lds(
        (const __attribute__((address_space(1))) void*)(srcA[i]),
        (__attribute__((address_space(3))) void*)&lds[dstOff[i]], 16, 0, 0);
    __builtin_amdgcn_global_load_lds(
        (const __attribute__((address_space(1))) void*)(srcB[i]),
        (__attribute__((address_space(3))) void*)&lds[4096 + dstOff[i]], 16, 0, 0);
  }
  __syncthreads();

  int c = 0;
  for (int k0 = 0; k0 < K; k0 += 32) {
    int nc = c ^ 1;
    if (k0 + 32 < K) {
      #pragma unroll
      for (int i = 0; i < 2; i++) {
        __builtin_amdgcn_global_load_lds(
            (const __attribute__((address_space(1))) void*)(srcA[i] + k0 + 32),
            (__attribute__((address_space(3))) void*)&lds[nc * 8192 + dstOff[i]], 16, 0, 0);
        __builtin_amdgcn_global_load_lds(
            (const __attribute__((address_space(1))) void*)(srcB[i] + k0 + 32),
            (__attribute__((address_space(3))) void*)&lds[nc * 8192 + 4096 + dstOff[i]], 16, 0, 0);
      }
    }
    bf16x8 af[4], bf[4];
    #pragma unroll
    for (int i = 0; i < 4; i++) {
      af[i] = *reinterpret_cast<const bf16x8*>(&lds[c * 8192 + offA[i]]);
      bf[i] = *reinterpret_cast<const bf16x8*>(&lds[c * 8192 + 4096 + offB[i]]);
    }
    #pragma unroll
    for (int i = 0; i < 4; i++)
      #pragma unroll
      for (int j = 0; j < 4; j++)
        acc[i][j] = __builtin_amdgcn_mfma_f32_16x16x32_bf16(af[i], bf[j], acc[i][j], 0, 0, 0);
    __syncthreads();   // implicit vmcnt(0): next tile landed while MFMA ran
    c = nc;
  }

  const int r4 = (lane >> 4) << 2;
  if (OUTMODE != 0) {
    // ---- bf16 epilogue: stage full 128x128 tile in LDS, coalesced 16B writes ----
    unsigned short* S = (unsigned short*)smem;        // [128][kLDSW]
    #pragma unroll
    for (int i = 0; i < 4; i++) {
      #pragma unroll
      for (int r = 0; r < 4; r++) {
        int row_t = wr + i * 16 + r4 + r;
        int rowg = m0 + row_t; if (rowg > M - 1) rowg = M - 1;
        float ra = rowAdd ? rowAdd[rowg] : 0.f;
        float rm = rowMul ? rowMul[rowg] : 1.f;
        #pragma unroll
        for (int j = 0; j < 4; j++) {
          int col_t = wc + j * 16 + (lane & 15);
          float v = (acc[i][j][r] + bias[n0 + col_t] + ra) * rm;
          if (OUTMODE == 2) v = __expf(v);
          S[row_t * kLDSW + col_t] = f2bf(v);
        }
      }
    }
    __syncthreads();
    #pragma unroll
    for (int it = 0; it < 8; it++) {
      int slot = it * 256 + tid;        // 2048 slots = 128 rows x 16 chunks
      int row_t = slot >> 4;
      int cs = (slot & 15) * 8;
      int row = m0 + row_t;
      if (row < M) {
        size_t orow = (size_t)(row / m_per_b) * n_total + out_off + (row % m_per_b);
        ulonglong2 d = *reinterpret_cast<const ulonglong2*>(&S[row_t * kLDSW + cs]);
        *reinterpret_cast<ulonglong2*>((unsigned short*)Cout + orow * 512 + n0 + cs) = d;
      }
    }
  } else {
    // ---- f32 epilogue: two 64-row passes, coalesced float4 writes (+residual) ----
    float* Sf = (float*)smem;                         // [64][kLDSW]
    #pragma unroll
    for (int p = 0; p < 2; p++) {
      __syncthreads();
      #pragma unroll
      for (int i2 = 0; i2 < 2; i2++) {
        int i = p * 2 + i2;
        #pragma unroll
        for (int r = 0; r < 4; r++) {
          int row_t = wr + i * 16 + r4 + r;
          int srow = (row_t & 31) + ((row_t >> 6) << 5);
          int rowg = m0 + row_t; if (rowg > M - 1) rowg = M - 1;
          float ra = rowAdd ? rowAdd[rowg] : 0.f;
          float rm = rowMul ? rowMul[rowg] : 1.f;
          #pragma unroll
          for (int j = 0; j < 4; j++) {
            int col_t = wc + j * 16 + (lane & 15);
            Sf[srow * kLDSW + col_t] = (acc[i][j][r] + bias[n0 + col_t] + ra) * rm;
          }
        }
      }
      __syncthreads();
      #pragma unroll
      for (int it = 0; it < 8; it++) {
        int slot = it * 256 + tid;      // 2048 slots = 64 rows x 32 float4
        int srow = slot >> 5;
        int c4 = (slot & 31) * 4;
        int row_t = (srow & 31) + p * 32 + ((srow >> 5) << 6);
        int row = m0 + row_t;
        if (row < M) {
          size_t orow = (size_t)(row / m_per_b) * n_total + out_off + (row % m_per_b);
          float4 v = *reinterpret_cast<const float4*>(&Sf[srow * kLDSW + c4]);
          if (addX) {
            float4 xv = *reinterpret_cast<const float4*>(&addX[(size_t)row * 512 + n0 + c4]);
            v.x += xv.x; v.y += xv.y; v.z += xv.z; v.w += xv.w;
          }
          *reinterpret_cast<float4*>((float*)Cout + orow * 512 + n0 + c4) = v;
        }
      }
    }
  }
}

// ---- attention partials: P[bh][s] = E_slice^T V_slice (64x64) + column-sum of E ----
__global__ __launch_bounds__(256) void attp_kernel(const unsigned short* __restrict__ E,
    const unsigned short* __restrict__ V, float* __restrict__ part,
    float* __restrict__ part_cs) {
  int bh = blockIdx.x; int b = bh >> 3, h = bh & 7;
  int s = blockIdx.y;
  int nbeg = s * kSL, nend = min(kN, nbeg + kSL);
  const unsigned short* kp = E + (size_t)b * kN * 512 + h * 64;
  const unsigned short* vp = V + (size_t)b * kN * 512 + h * 64;
  __shared__ float ks[32][68];
  __shared__ float vs[32][68];
  int tid = threadIdx.x;
  int td = tid >> 4, tl = tid & 15;
  int snn = tid >> 3, sc0 = (tid & 7) * 8;
  float acc[4][4] = {};
  float csum[4] = {};
  for (int n0 = nbeg; n0 < nend; n0 += 32) {
    __syncthreads();
    int n = n0 + snn;
    float kv[8] = {}, vv[8] = {};
    if (n < nend) {
      const unsigned short* pk = kp + (size_t)n * 512 + sc0;
      const unsigned short* pv = vp + (size_t)n * 512 + sc0;
      ushort4 a0 = *reinterpret_cast<const ushort4*>(pk);
      ushort4 a1 = *reinterpret_cast<const ushort4*>(pk + 4);
      ushort4 b0 = *reinterpret_cast<const ushort4*>(pv);
      ushort4 b1 = *reinterpret_cast<const ushort4*>(pv + 4);
      kv[0] = bf2f(a0.x); kv[1] = bf2f(a0.y); kv[2] = bf2f(a0.z); kv[3] = bf2f(a0.w);
      kv[4] = bf2f(a1.x); kv[5] = bf2f(a1.y); kv[6] = bf2f(a1.z); kv[7] = bf2f(a1.w);
      vv[0] = bf2f(b0.x); vv[1] = bf2f(b0.y); vv[2] = bf2f(b0.z); vv[3] = bf2f(b0.w);
      vv[4] = bf2f(b1.x); vv[5] = bf2f(b1.y); vv[6] = bf2f(b1.z); vv[7] = bf2f(b1.w);
    }
    #pragma unroll
    for (int j = 0; j < 8; j++) { ks[snn][sc0 + j] = kv[j]; vs[snn][sc0 + j] = vv[j]; }
    __syncthreads();
    #pragma unroll
    for (int nn = 0; nn < 32; nn++) {
      float4 kq = *reinterpret_cast<const float4*>(&ks[nn][td * 4]);
      float4 vl = *reinterpret_cast<const float4*>(&vs[nn][tl * 4]);
      float a[4] = {kq.x, kq.y, kq.z, kq.w};
      float c[4] = {vl.x, vl.y, vl.z, vl.w};
      #pragma unroll
      for (int i = 0; i < 4; i++) {
        csum[i] += a[i];
        #pragma unroll
        for (int j = 0; j < 4; j++)
          acc[i][j] = fmaf(a[i], c[j], acc[i][j]);
      }
    }
  }
  float* op = part + ((size_t)bh * kNS + s) * 4096;
  #pragma unroll
  for (int i = 0; i < 4; i++)
    #pragma unroll
    for (int j = 0; j < 4; j++)
      op[(td * 4 + i) * 64 + tl * 4 + j] = acc[i][j];
  if (tl == 0) {
    #pragma unroll
    for (int i = 0; i < 4; i++)
      part_cs[((size_t)bh * kNS + s) * 64 + td * 4 + i] = csum[i];
  }
}

// ---- combine partials, apply 1/colsum, write att^T bf16 [l][d] ----
__global__ __launch_bounds__(256) void attc_kernel(const float* __restrict__ part,
    const float* __restrict__ part_cs, unsigned short* __restrict__ attT) {
  int bh = blockIdx.x;
  __shared__ float at[64][65];
  __shared__ float sinv[64];
  int tid = threadIdx.x;
  if (tid < 64) {
    float s = 0.f;
    #pragma unroll
    for (int c = 0; c < kNS; c++) s += part_cs[((size_t)bh * kNS + c) * 64 + tid];
    sinv[tid] = 1.f / s;
  }
  for (int i = tid; i < 4096; i += 256) {
    float s = 0.f;
    #pragma unroll
    for (int c = 0; c < kNS; c++) s += part[((size_t)bh * kNS + c) * 4096 + i];
    at[i >> 6][i & 63] = s;
  }
  __syncthreads();
  for (int j = tid; j < 4096; j += 256) {
    int l = j >> 6, d = j & 63;
    attT[(size_t)bh * 4096 + j] = f2bf(at[d][l] * sinv[d]);
  }
}

// ---- y = (expq/rowsum) @ att via MFMA; y bf16 ----
__global__ __launch_bounds__(256) void y_mfma(const unsigned short* __restrict__ q,
    const unsigned short* __restrict__ attT, unsigned short* __restrict__ y) {
  int bh = blockIdx.x; int b = bh >> 3, h = bh & 7;
  int t0 = blockIdx.y * 128;
  __shared__ unsigned short bt[64][72];
  __shared__ float rs[128];
  __shared__ unsigned short ob[128][72];
  int tid = threadIdx.x, lane = tid & 63, wv = tid >> 6;
  int wr = wv * 32;
  // stage attT tile (64x64 bf16)
  for (int i = tid; i < 512; i += 256) {
    int row = i >> 3, c8 = (i & 7) * 8;
    *reinterpret_cast<ulonglong2*>(&bt[row][c8]) =
        *reinterpret_cast<const ulonglong2*>(attT + (size_t)bh * 4096 + row * 64 + c8);
  }
  // A fragments straight from global expq
  const unsigned short* qp = q + ((size_t)(b * 1024 + t0 + wr)) * 512 + h * 64;
  bf16x8 af[2][2];
  #pragma unroll
  for (int i = 0; i < 2; i++) {
    int row = i * 16 + (lane & 15);
    #pragma unroll
    for (int s = 0; s < 2; s++)
      af[i][s] = *reinterpret_cast<const bf16x8*>(qp + (size_t)row * 512 + s * 32 + (lane >> 4) * 8);
  }
  // row sums of expq (softmax denominator), per 64-d head slice
  #pragma unroll
  for (int i = 0; i < 2; i++) {
    float r = 0.f;
    #pragma unroll
    for (int s = 0; s < 2; s++) {
      const unsigned short* pu = reinterpret_cast<const unsigned short*>(&af[i][s]);
      #pragma unroll
      for (int e = 0; e < 8; e++) r += bf2f(pu[e]);
    }
    r += __shfl_xor(r, 16); r += __shfl_xor(r, 32);
    if (lane < 16) rs[wr + i * 16 + lane] = r;
  }
  __syncthreads();
  f32x4 acc[2][4] = {};
  #pragma unroll
  for (int s = 0; s < 2; s++) {
    #pragma unroll
    for (int j = 0; j < 4; j++) {
      bf16x8 bf = *reinterpret_cast<const bf16x8*>(&bt[j * 16 + (lane & 15)][s * 32 + (lane >> 4) * 8]);
      #pragma unroll
      for (int i = 0; i < 2; i++)
        acc[i][j] = __builtin_amdgcn_mfma_f32_16x16x32_bf16(af[i][s], bf, acc[i][j], 0, 0, 0);
    }
  }
  int r4 = (lane >> 4) << 2;
  #pragma unroll
  for (int i = 0; i < 2; i++) {
    #pragma unroll
    for (int r = 0; r < 4; r++) {
      int row = wr + i * 16 + r4 + r;
      float rinv = 1.f / rs[row];
      #pragma unroll
      for (int j = 0; j < 4; j++)
        ob[row][j * 16 + (lane & 15)] = f2bf(acc[i][j][r] * rinv);
    }
  }
  __syncthreads();
  for (int i = tid; i < 1024; i += 256) {
    int row = i >> 3, c8 = (i & 7) * 8;
    *reinterpret_cast<ulonglong2*>(y + ((size_t)(b * 1024 + t0 + row)) * 512 + h * 64 + c8) =
        *reinterpret_cast<const ulonglong2*>(&ob[row][c8]);
  }
}

// ---------------- LN(y)*(1+scale)+shift then SiLU -> bf16 (y is bf16) ----------------
__global__ __launch_bounds__(256) void mod_kernel(const unsigned short* __restrict__ y,
    const float* __restrict__ ss, const float* __restrict__ g, const float* __restrict__ be,
    unsigned short* __restrict__ h) {
  int row = blockIdx.x; int b = row >> 10;
  const unsigned short* p = y + (size_t)row * 512;
  unsigned short* o = h + (size_t)row * 512;
  float v[2]; float s = 0.f, s2 = 0.f;
  #pragma unroll
  for (int i = 0; i < 2; i++) {
    v[i] = bf2f(p[threadIdx.x + i * 256]);
    s += v[i]; s2 += v[i] * v[i];
  }
  __shared__ float red[2][4];
  int lane = threadIdx.x & 63, w = threadIdx.x >> 6;
  s = wave_sum(s); s2 = wave_sum(s2);
  if (!lane) { red[0][w] = s; red[1][w] = s2; }
  __syncthreads();
  s = red[0][0] + red[0][1] + red[0][2] + red[0][3];
  s2 = red[1][0] + red[1][1] + red[1][2] + red[1][3];
  float mean = s / 512.f, var = s2 / 512.f - mean * mean;
  float rstd = rsqrtf(var + 1e-5f);
  #pragma unroll
  for (int i = 0; i < 2; i++) {
    int c = threadIdx.x + i * 256;
    float val = (v[i] - mean) * rstd * g[c] + be[c];
    val = val * (1.f + ss[b * 1024 + c]) + ss[b * 1024 + 512 + c];
    o[c] = f2bf(val / (1.f + __expf(-val)));
  }
}

}  // namespace

extern "C" void kernel_launch(void* const* d_in, const int* in_sizes, int n_in,
                              void* d_out, int out_size, void* d_ws, size_t ws_size,
                              hipStream_t stream) {
  const float* x        = (const float*)d_in[0];
  const float* xf       = (const float*)d_in[1];
  const float* emb      = (const float*)d_in[2];
  const float* src_mask = (const float*)d_in[3];
  const int*   cond     = (const int*)d_in[4];
  const float* re_motion= (const float*)d_in[5];
  const float* re_text  = (const float*)d_in[6];
  const float* re_mask  = (const float*)d_in[7];
  const float* norm_g = (const float*)d_in[8],  * norm_b = (const float*)d_in[9];
  const float* tnorm_g= (const float*)d_in[10], * tnorm_b= (const float*)d_in[11];
  const float* rn1_g  = (const float*)d_in[12], * rn1_b  = (const float*)d_in[13];
  const float* rn2_g  = (const float*)d_in[14], * rn2_b  = (const float*)d_in[15];
  const float* Wq  = (const float*)d_in[16], * bq  = (const float*)d_in[17];
  const float* Wkt = (const float*)d_in[18], * bkt = (const float*)d_in[19];
  const float* Wvt = (const float*)d_in[20], * bvt = (const float*)d_in[21];
  const float* Wkm = (const float*)d_in[22], * bkm = (const float*)d_in[23];
  const float* Wvm = (const float*)d_in[24], * bvm = (const float*)d_in[25];
  const float* Wkr = (const float*)d_in[26], * bkr = (const float*)d_in[27];
  const float* Wvr = (const float*)d_in[28], * bvr = (const float*)d_in[29];
  const float* emb_W = (const float*)d_in[30], * emb_b = (const float*)d_in[31];
  const float* snorm_g = (const float*)d_in[32], * snorm_b = (const float*)d_in[33];
  const float* out_W = (const float*)d_in[34], * out_b = (const float*)d_in[35];
  float* out = (float*)d_out;

  char* base = (char*)d_ws;
  size_t off = 0;
  auto ab = [&](size_t nb) { char* p = base + off; off = (off + nb + 255) & ~(size_t)255; return p; };

  // ---- persistent region: bf16 weights + full-batch small buffers ----
  unsigned short* wq_bf  = (unsigned short*)ab(512 * 512 * 2);
  unsigned short* wkt_bf = (unsigned short*)ab(512 * 256 * 2);
  unsigned short* wvt_bf = (unsigned short*)ab(512 * 256 * 2);
  unsigned short* wkm_bf = (unsigned short*)ab(512 * 512 * 2);
  unsigned short* wvm_bf = (unsigned short*)ab(512 * 512 * 2);
  unsigned short* wkr_bf = (unsigned short*)ab(512 * 1024 * 2);
  unsigned short* wvr_bf = (unsigned short*)ab(512 * 512 * 2);
  unsigned short* wout_bf= (unsigned short*)ab(512 * 512 * 2);
  float* semb_f   = (float*)ab((size_t)kB * 2048 * 4);
  float* part_emb = (float*)ab((size_t)8 * kB * 1024 * 4);
  float* ssb_full = (float*)ab((size_t)kB * 1024 * 4);
  float* kaT_full = (float*)ab((size_t)kB * kNT * 4);
  float* vmT_full = (float*)ab((size_t)kB * kNT * 4);
  float* kaR_full = (float*)ab((size_t)kB * kRL * 4);
  float* kaM_full = (float*)ab((size_t)kB * kT * 4);
  float* vmR_full = (float*)ab((size_t)kB * kRL * 4);
  float* vmM_full = (float*)ab((size_t)kB * kT * 4);
  const size_t fixed_off = off;

  auto pad = [](size_t n) { return (n + 255) & ~(size_t)255; };
  auto chunk_bytes = [&](size_t CH) -> size_t {
    size_t s = 0;
    s += pad(CH * 1024 * 512 * 2);        // xn_bf (reused as h_bf)
    s += pad(CH * kNT * 256 * 2);         // xfn_bf
    s += pad(CH * 1024 * 1024 * 2);       // rfk_bf (reused as y bf16)
    s += pad(CH * 1024 * 512 * 2);        // rfv_bf
    s += pad(CH * 1024 * 512 * 2);        // qb_bf
    s += pad((size_t)CH * kN * 512 * 2);  // kc_bf (E)
    s += pad((size_t)CH * kN * 512 * 2);  // vb_bf
    s += pad(CH * 8 * 4096 * 2);          // attT bf16
    s += pad(CH * 8 * (size_t)kNS * 4096 * 4);  // attp partials
    s += pad(CH * 8 * (size_t)kNS * 64 * 4);    // colsum partials
    return s;
  };
  int CH = 32;
  while (CH > 1 && fixed_off + chunk_bytes(CH) > ws_size) CH >>= 1;

  // ---- once-per-call work (full batch) ----
  auto cl = [&](const float* s, unsigned short* d, int n) {
    castw<<<dim3((n / 4 + 255) / 256), 256, 0, stream>>>(s, d, n);
  };
  cl(Wq,  wq_bf,  512 * 512);
  cl(Wkt, wkt_bf, 512 * 256);
  cl(Wvt, wvt_bf, 512 * 256);
  cl(Wkm, wkm_bf, 512 * 512);
  cl(Wvm, wvm_bf, 512 * 512);
  cl(Wkr, wkr_bf, 512 * 1024);
  cl(Wvr, wvr_bf, 512 * 512);
  cl(out_W, wout_bf, 512 * 512);

  rowmask_kernel<<<dim3(kB * 4), 256, 0, stream>>>(cond, src_mask, re_mask,
      kaT_full, kaR_full, kaM_full, vmT_full, vmR_full, vmM_full, kB);
  silu_emb<<<dim3(kB * 2048 / 1024), 256, 0, stream>>>(emb, semb_f);
  emb_gemv2<<<dim3(256, 8), 256, 0, stream>>>(semb_f, emb_W, part_emb);
  emb_fin<<<dim3(128), 256, 0, stream>>>(part_emb, emb_b, ssb_full);

  for (int b0 = 0; b0 < kB; b0 += CH) {
    off = fixed_off;
    const int MRc = CH * 1024;
    const int MTc = CH * kNT;

    unsigned short* xn_bf  = (unsigned short*)ab((size_t)MRc * 512 * 2);
    unsigned short* xfn_bf = (unsigned short*)ab((size_t)MTc * 256 * 2);
    unsigned short* rfk_bf = (unsigned short*)ab((size_t)MRc * 1024 * 2);
    unsigned short* rfv_bf = (unsigned short*)ab((size_t)MRc * 512 * 2);
    unsigned short* qb_bf  = (unsigned short*)ab((size_t)MRc * 512 * 2);
    unsigned short* kc_bf  = (unsigned short*)ab((size_t)CH * kN * 512 * 2);
    unsigned short* vb_bf  = (unsigned short*)ab((size_t)CH * kN * 512 * 2);
    unsigned short* attT = (unsigned short*)ab((size_t)CH * 8 * 4096 * 2);
    float* attp = (float*)ab((size_t)CH * 8 * kNS * 4096 * 4);
    float* part_cs = (float*)ab((size_t)CH * 8 * kNS * 64 * 4);
    unsigned short* yb16 = rfk_bf;           // rfk dead after Wkr GEMM
    unsigned short* h_bf = xn_bf;            // xn dead after Wvm GEMM

    const float* x_c   = x + (size_t)b0 * kT * 512;
    const float* xf_c  = xf + (size_t)b0 * kNT * 256;
    const float* rm_c  = re_motion + (size_t)b0 * kRL * 512;
    const float* rt_c  = re_text + (size_t)b0 * kR * 512;
    float* out_c = out + (size_t)b0 * kT * 512;

    // --- preprocessing ---
    ln_bf16<512><<<dim3(MRc), 256, 0, stream>>>(x_c, norm_g, norm_b, xn_bf);
    ln_bf16<256><<<dim3(MTc), 256, 0, stream>>>(xf_c, tnorm_g, tnorm_b, xfn_bf);
    rfk_norm<<<dim3(MRc), 256, 0, stream>>>(rm_c, rt_c, rn1_g, rn1_b, rn2_g, rn2_b,
                                            rfk_bf, rfv_bf);

    // --- projections (bf16 MFMA); k-GEMMs and q-GEMM write exp() ---
    gemm_mfma<2><<<dim3(4, CH * 8), 256, 0, stream>>>(xn_bf, wq_bf, bq, qb_bf,
        MRc, 512, MRc, 0, 0, nullptr, nullptr, nullptr);
    gemm_mfma<2><<<dim3(4, (MTc + 127) / 128), 256, 0, stream>>>(xfn_bf, wkt_bf, bkt, kc_bf,
        MTc, 256, kNT, kN, 0, kaT_full + (size_t)b0 * kNT, nullptr, nullptr);
    gemm_mfma<2><<<dim3(4, CH * 8), 256, 0, stream>>>(rfk_bf, wkr_bf, bkr, kc_bf,
        MRc, 1024, kRL, kN, kNT, kaR_full + (size_t)b0 * kRL, nullptr, nullptr);
    gemm_mfma<2><<<dim3(4, CH * 8), 256, 0, stream>>>(xn_bf, wkm_bf, bkm, kc_bf,
        MRc, 512, kT, kN, kNT + kRL, kaM_full + (size_t)b0 * kT, nullptr, nullptr);
    gemm_mfma<1><<<dim3(4, (MTc + 127) / 128), 256, 0, stream>>>(xfn_bf, wvt_bf, bvt, vb_bf,
        MTc, 256, kNT, kN, 0, nullptr, vmT_full + (size_t)b0 * kNT, nullptr);
    gemm_mfma<1><<<dim3(4, CH * 8), 256, 0, stream>>>(rfv_bf, wvr_bf, bvr, vb_bf,
        MRc, 512, kRL, kN, kNT, nullptr, vmR_full + (size_t)b0 * kRL, nullptr);
    gemm_mfma<1><<<dim3(4, CH * 8), 256, 0, stream>>>(xn_bf, wvm_bf, bvm, vb_bf,
        MRc, 512, kT, kN, kNT + kRL, nullptr, vmM_full + (size_t)b0 * kT, nullptr);

    // --- attention: partials + fused column-sum, combine, MFMA y ---
    attp_kernel<<<dim3(CH * 8, kNS), 256, 0, stream>>>(kc_bf, vb_bf, attp, part_cs);
    attc_kernel<<<dim3(CH * 8), 256, 0, stream>>>(attp, part_cs, attT);
    y_mfma<<<dim3(CH * 8, 8), 256, 0, stream>>>(qb_bf, attT, yb16);

    // --- modulation + output projection + residual ---
    mod_kernel<<<dim3(MRc), 256, 0, stream>>>(yb16, ssb_full + (size_t)b0 * 1024,
                                              snorm_g, snorm_b, h_bf);
    gemm_mfma<0><<<dim3(4, CH * 8), 256, 0, stream>>>(h_bf, wout_bf, out_b, out_c,
        MRc, 512, MRc, 0, 0, nullptr, nullptr, x_c);
  }
}